// Round 1
// baseline (755.263 us; speedup 1.0000x reference)
//
#include <hip/hip_runtime.h>
#include <cstddef>

// ---------------------------------------------------------------------------
// Problem shapes (fixed by setup_inputs):
//   x_p (4,16,3,64,64) -> x (64,3,64,64)
//   conv1 5x5 s2 p2: (64,128,32,32) ; GDN1
//   conv2 5x5 s2 p2: (64,128,16,16) ; GDN2
//   conv3 3x3 s1 p1: (64,192,16,16) -> q (64,256,192)
//   kv from y_g (64,192,32) -> (64,32,192)
//   Bahdanau attention D=128, out proj 192x192, final LN, out (64,192,16,16)
// ---------------------------------------------------------------------------

#define BPn 64

// ---- workspace layout (float offsets); peak = 16,777,216 floats = 64 MB ----
static constexpr size_t OFF_T1   = 0;          // (64,128,32,32) conv1 out
static constexpr size_t OFF_T1B  = 8388608;    // gdn1 out
static constexpr size_t OFF_T2   = 0;          // (64,128,16,16) conv2 out (t1 dead)
static constexpr size_t OFF_T2B  = 2097152;    // gdn2 out
static constexpr size_t OFF_QRAW = 4194304;    // (64,256,192) conv3 out, (b,t,m)
static constexpr size_t OFF_QLN  = 8388608;    // (64,256,192) LN(q)  (t1b dead)
static constexpr size_t OFF_KVLN = 11534336;   // (64,32,192)
static constexpr size_t OFF_QP   = 11927552;   // (64,256,128)
static constexpr size_t OFF_KP   = 14024704;   // (64,32,128)
static constexpr size_t OFF_VP   = 14286848;   // (64,32,192)
static constexpr size_t OFF_CTX  = 0;          // (64,256,192) attention out
static constexpr size_t OFF_CTX2 = 3145728;    // (64,256,192) out-proj out

// ---------------------------------------------------------------------------
// conv1: (64,3,64,64) -> (64,128,32,32), 5x5 s2 p2.
// block: one b, 8 output channels; input image staged in LDS (padded rows).
// ---------------------------------------------------------------------------
__global__ __launch_bounds__(256) void conv1_kernel(
    const float* __restrict__ x, const float* __restrict__ w,
    const float* __restrict__ bias, float* __restrict__ out) {
  int b  = blockIdx.x >> 4;
  int og = blockIdx.x & 15;
  int o0 = og * 8;
  __shared__ float sx[3][64][72];   // cols -4..67 stored at +4
  __shared__ float sw[8 * 75];
  int tid = threadIdx.x;
  const float* xb = x + (size_t)b * 3 * 4096;
  for (int j = tid; j < 3 * 64 * 16; j += 256) {
    int c = j / 1024, rem = j % 1024;
    int row = rem >> 4, col4 = rem & 15;
    float4 v = *(const float4*)&xb[c * 4096 + row * 64 + col4 * 4];
    *(float4*)&sx[c][row][4 + col4 * 4] = v;
  }
  for (int j = tid; j < 3 * 64; j += 256) {
    int c = j / 64, row = j % 64;
    sx[c][row][0] = sx[c][row][1] = sx[c][row][2] = sx[c][row][3] = 0.f;
    sx[c][row][68] = sx[c][row][69] = sx[c][row][70] = sx[c][row][71] = 0.f;
  }
  for (int j = tid; j < 600; j += 256) sw[j] = w[o0 * 75 + j];
  __syncthreads();

  int oh = tid >> 3, ow0 = (tid & 7) * 4;
  float acc[8][4];
  #pragma unroll
  for (int oo = 0; oo < 8; ++oo)
    #pragma unroll
    for (int j = 0; j < 4; ++j) acc[oo][j] = 0.f;

  for (int c = 0; c < 3; ++c) {
    #pragma unroll
    for (int kh = 0; kh < 5; ++kh) {
      int ih = oh * 2 - 2 + kh;
      if (ih < 0 || ih >= 64) continue;
      float rv[16];
      *(float4*)&rv[0]  = *(const float4*)&sx[c][ih][ow0 * 2];
      *(float4*)&rv[4]  = *(const float4*)&sx[c][ih][ow0 * 2 + 4];
      *(float4*)&rv[8]  = *(const float4*)&sx[c][ih][ow0 * 2 + 8];
      *(float4*)&rv[12] = *(const float4*)&sx[c][ih][ow0 * 2 + 12];
      #pragma unroll
      for (int kw = 0; kw < 5; ++kw) {
        float wv[8];
        #pragma unroll
        for (int oo = 0; oo < 8; ++oo) wv[oo] = sw[oo * 75 + c * 25 + kh * 5 + kw];
        #pragma unroll
        for (int oo = 0; oo < 8; ++oo)
          #pragma unroll
          for (int j = 0; j < 4; ++j)
            acc[oo][j] += wv[oo] * rv[2 + kw + 2 * j];
      }
    }
  }
  #pragma unroll
  for (int oo = 0; oo < 8; ++oo) {
    float bv = bias[o0 + oo];
    float4 o4 = {acc[oo][0] + bv, acc[oo][1] + bv, acc[oo][2] + bv, acc[oo][3] + bv};
    *(float4*)&out[((size_t)(b * 128 + o0 + oo)) * 1024 + oh * 32 + ow0] = o4;
  }
}

// ---------------------------------------------------------------------------
// GDN as GEMM: norm[d,p] = beta[d] + sum_c gamma[d,c]*x[c,p]^2 ; y = x*rsqrt
// tile 64 d x 64 pix, K=128 in 2 chunks. Out-of-place (y != x).
// ---------------------------------------------------------------------------
__global__ __launch_bounds__(256) void gdn_kernel(
    const float* __restrict__ x, const float* __restrict__ gamma,
    const float* __restrict__ beta, float* __restrict__ y,
    int HW, int nPixTiles) {
  int dt = blockIdx.x & 1;
  int pt = (blockIdx.x >> 1) % nPixTiles;
  int b  = blockIdx.x / (2 * nPixTiles);
  int d0 = dt * 64, p0 = pt * 64;
  const float* xb = x + (size_t)b * 128 * HW;
  float* yb = y + (size_t)b * 128 * HW;
  __shared__ float sA[64 * 68];   // [kk][dd] gamma
  __shared__ float sB[64 * 68];   // [kk][nn] x^2
  int tid = threadIdx.x;
  int rg = tid >> 4, ng = tid & 15;
  float acc[4][4];
  #pragma unroll
  for (int i = 0; i < 4; ++i)
    #pragma unroll
    for (int j = 0; j < 4; ++j) acc[i][j] = 0.f;

  for (int c0 = 0; c0 < 128; c0 += 64) {
    __syncthreads();
    for (int j = tid; j < 1024; j += 256) {
      int dd = j >> 4, k4 = j & 15;
      float4 v = *(const float4*)&gamma[(size_t)(d0 + dd) * 128 + c0 + k4 * 4];
      int kb = k4 * 4;
      sA[(kb + 0) * 68 + dd] = v.x; sA[(kb + 1) * 68 + dd] = v.y;
      sA[(kb + 2) * 68 + dd] = v.z; sA[(kb + 3) * 68 + dd] = v.w;
    }
    for (int j = tid; j < 1024; j += 256) {
      int kk = j >> 4, n4 = j & 15;
      float4 v = *(const float4*)&xb[(size_t)(c0 + kk) * HW + p0 + n4 * 4];
      v.x *= v.x; v.y *= v.y; v.z *= v.z; v.w *= v.w;
      *(float4*)&sB[kk * 68 + n4 * 4] = v;
    }
    __syncthreads();
    #pragma unroll 8
    for (int kk = 0; kk < 64; ++kk) {
      float4 a = *(const float4*)&sA[kk * 68 + rg * 4];
      float4 bb4 = *(const float4*)&sB[kk * 68 + ng * 4];
      acc[0][0] += a.x * bb4.x; acc[0][1] += a.x * bb4.y; acc[0][2] += a.x * bb4.z; acc[0][3] += a.x * bb4.w;
      acc[1][0] += a.y * bb4.x; acc[1][1] += a.y * bb4.y; acc[1][2] += a.y * bb4.z; acc[1][3] += a.y * bb4.w;
      acc[2][0] += a.z * bb4.x; acc[2][1] += a.z * bb4.y; acc[2][2] += a.z * bb4.z; acc[2][3] += a.z * bb4.w;
      acc[3][0] += a.w * bb4.x; acc[3][1] += a.w * bb4.y; acc[3][2] += a.w * bb4.z; acc[3][3] += a.w * bb4.w;
    }
  }
  #pragma unroll
  for (int i = 0; i < 4; ++i) {
    int d = d0 + rg * 4 + i;
    float bt = beta[d];
    float4 xv = *(const float4*)&xb[(size_t)d * HW + p0 + ng * 4];
    float4 o4;
    o4.x = xv.x * rsqrtf(acc[i][0] + bt);
    o4.y = xv.y * rsqrtf(acc[i][1] + bt);
    o4.z = xv.z * rsqrtf(acc[i][2] + bt);
    o4.w = xv.w * rsqrtf(acc[i][3] + bt);
    *(float4*)&yb[(size_t)d * HW + p0 + ng * 4] = o4;
  }
}

// ---------------------------------------------------------------------------
// conv2: (64,128,32,32) -> (64,128,16,16), 5x5 s2 p2. tile 64 o x 64 pix.
// ---------------------------------------------------------------------------
__global__ __launch_bounds__(256) void conv2_kernel(
    const float* __restrict__ x, const float* __restrict__ w,
    const float* __restrict__ bias, float* __restrict__ out) {
  int blk = blockIdx.x;
  int b = blk >> 3;
  int ot = (blk >> 2) & 1;
  int pt = blk & 3;
  int o0 = ot * 64;
  int oh0 = (pt >> 1) * 8, ow0 = (pt & 1) * 8;
  int ih0 = oh0 * 2 - 2, iw0 = ow0 * 2 - 2;
  const float* xb = x + (size_t)b * 128 * 1024;

  __shared__ float sA[100 * 68];       // [r=c*25+k][o]
  __shared__ float sB[4 * 19 * 20];    // [c][row][col]
  int tid = threadIdx.x;
  int og = tid >> 4, pg = tid & 15;
  int ph = pg >> 1, pw0 = (pg & 1) * 4;

  float acc[4][4];
  #pragma unroll
  for (int i = 0; i < 4; ++i)
    #pragma unroll
    for (int j = 0; j < 4; ++j) acc[i][j] = 0.f;

  for (int ck = 0; ck < 128; ck += 4) {
    __syncthreads();
    for (int jj = tid; jj < 6400; jj += 256) {
      int o = jj / 100, r = jj % 100;
      sA[r * 68 + o] = w[(size_t)(o0 + o) * 3200 + ck * 25 + r];
    }
    for (int jj = tid; jj < 4 * 380; jj += 256) {
      int c = jj / 380, rr = jj % 380;
      int r = rr / 20, cc = rr % 20;
      int ih = ih0 + r, iw = iw0 + cc;
      float v = 0.f;
      if (r < 19 && ih >= 0 && ih < 32 && iw >= 0 && iw < 32)
        v = xb[(size_t)(ck + c) * 1024 + ih * 32 + iw];
      sB[(c * 19 + (r < 19 ? r : 18)) * 20 + cc] = (r < 19) ? v : sB[(c * 19 + 18) * 20 + cc];
      if (r < 19) sB[(c * 19 + r) * 20 + cc] = v;
    }
    __syncthreads();
    for (int c = 0; c < 4; ++c) {
      #pragma unroll
      for (int kh = 0; kh < 5; ++kh) {
        const float* rowp = &sB[(c * 19 + ph * 2 + kh) * 20 + pw0 * 2];
        float rv[12];
        *(float4*)&rv[0] = *(const float4*)&rowp[0];
        *(float4*)&rv[4] = *(const float4*)&rowp[4];
        *(float4*)&rv[8] = *(const float4*)&rowp[8];
        #pragma unroll
        for (int kw = 0; kw < 5; ++kw) {
          float4 a = *(const float4*)&sA[(c * 25 + kh * 5 + kw) * 68 + og * 4];
          float av[4] = {a.x, a.y, a.z, a.w};
          #pragma unroll
          for (int i = 0; i < 4; ++i)
            #pragma unroll
            for (int j = 0; j < 4; ++j)
              acc[i][j] += av[i] * rv[j * 2 + kw];
        }
      }
    }
  }
  #pragma unroll
  for (int i = 0; i < 4; ++i) {
    int o = o0 + og * 4 + i;
    float bv = bias[o];
    float4 o4 = {acc[i][0] + bv, acc[i][1] + bv, acc[i][2] + bv, acc[i][3] + bv};
    *(float4*)&out[((size_t)(b * 128 + o)) * 256 + (oh0 + ph) * 16 + ow0 + pw0] = o4;
  }
}

// ---------------------------------------------------------------------------
// conv3: (64,128,16,16) -> q_raw (64,256,192) [(b,t,m) layout], 3x3 s1 p1.
// ---------------------------------------------------------------------------
__global__ __launch_bounds__(256) void conv3_kernel(
    const float* __restrict__ x, const float* __restrict__ w,
    const float* __restrict__ bias, float* __restrict__ qraw) {
  int ot = blockIdx.x % 3;
  int pt = (blockIdx.x / 3) & 3;
  int b  = blockIdx.x / 12;
  int o0 = ot * 64;
  int oh0 = (pt >> 1) * 8, ow0 = (pt & 1) * 8;
  const float* xb = x + (size_t)b * 128 * 256;

  __shared__ float sA[72 * 68];     // [r=c*9+k][o]
  __shared__ float sB[8 * 10 * 12]; // [c][row][col]
  __shared__ float sOut[64 * 68];   // [p][o]
  int tid = threadIdx.x;
  int og = tid >> 4, pg = tid & 15;
  int ph = pg >> 1, pw0 = (pg & 1) * 4;

  float acc[4][4];
  #pragma unroll
  for (int i = 0; i < 4; ++i)
    #pragma unroll
    for (int j = 0; j < 4; ++j) acc[i][j] = 0.f;

  for (int c0 = 0; c0 < 128; c0 += 8) {
    __syncthreads();
    for (int jj = tid; jj < 4608; jj += 256) {
      int o = jj / 72, r = jj % 72;
      sA[r * 68 + o] = w[(size_t)(o0 + o) * 1152 + c0 * 9 + r];
    }
    for (int jj = tid; jj < 960; jj += 256) {
      int c = jj / 120, rr = jj % 120;
      int r = rr / 12, cc = rr % 12;
      int ih = oh0 + r - 1, iw = ow0 + cc - 1;
      float v = 0.f;
      if (ih >= 0 && ih < 16 && iw >= 0 && iw < 16)
        v = xb[(size_t)(c0 + c) * 256 + ih * 16 + iw];
      sB[(c * 10 + r) * 12 + cc] = v;
    }
    __syncthreads();
    for (int c = 0; c < 8; ++c) {
      #pragma unroll
      for (int kh = 0; kh < 3; ++kh) {
        const float* rowp = &sB[(c * 10 + ph + kh) * 12 + pw0];
        float rv[8];
        *(float4*)&rv[0] = *(const float4*)&rowp[0];
        *(float4*)&rv[4] = *(const float4*)&rowp[4];
        #pragma unroll
        for (int kw = 0; kw < 3; ++kw) {
          float4 a = *(const float4*)&sA[(c * 9 + kh * 3 + kw) * 68 + og * 4];
          float av[4] = {a.x, a.y, a.z, a.w};
          #pragma unroll
          for (int i = 0; i < 4; ++i)
            #pragma unroll
            for (int j = 0; j < 4; ++j)
              acc[i][j] += av[i] * rv[j + kw];
        }
      }
    }
  }
  #pragma unroll
  for (int j = 0; j < 4; ++j) {
    float4 o4 = {acc[0][j], acc[1][j], acc[2][j], acc[3][j]};
    *(float4*)&sOut[(pg * 4 + j) * 68 + og * 4] = o4;
  }
  __syncthreads();
  for (int jj = tid; jj < 4096; jj += 256) {
    int p = jj >> 6, oo = jj & 63;
    int t = (oh0 + (p >> 3)) * 16 + ow0 + (p & 7);
    qraw[(size_t)b * 49152 + (size_t)t * 192 + o0 + oo] = sOut[p * 68 + oo] + bias[o0 + oo];
  }
}

// ---------------------------------------------------------------------------
// LayerNorm over contiguous rows of length 192. One wave per row.
// ---------------------------------------------------------------------------
__global__ __launch_bounds__(256) void ln_rows_kernel(
    const float* __restrict__ X, const float* __restrict__ w,
    const float* __restrict__ bb, float* __restrict__ Y, int R) {
  int row = blockIdx.x * 4 + (threadIdx.x >> 6);
  int lane = threadIdx.x & 63;
  if (row >= R) return;
  const float* xr = X + (size_t)row * 192;
  float v0 = xr[lane], v1 = xr[lane + 64], v2 = xr[lane + 128];
  float s = v0 + v1 + v2;
  float s2 = v0 * v0 + v1 * v1 + v2 * v2;
  #pragma unroll
  for (int off = 32; off; off >>= 1) { s += __shfl_xor(s, off); s2 += __shfl_xor(s2, off); }
  float mean = s * (1.f / 192.f);
  float var = s2 * (1.f / 192.f) - mean * mean;
  float inv = rsqrtf(var + 1e-5f);
  float* yr = Y + (size_t)row * 192;
  yr[lane]       = (v0 - mean) * inv * w[lane]       + bb[lane];
  yr[lane + 64]  = (v1 - mean) * inv * w[lane + 64]  + bb[lane + 64];
  yr[lane + 128] = (v2 - mean) * inv * w[lane + 128] + bb[lane + 128];
}

// ---------------------------------------------------------------------------
// kv LN: gather y_g (64,192,32) -> kv_ln (64,32,192) with LN over 192.
// ---------------------------------------------------------------------------
__global__ __launch_bounds__(256) void ln_kv_kernel(
    const float* __restrict__ yg, const float* __restrict__ w,
    const float* __restrict__ bb, float* __restrict__ Y) {
  int row = blockIdx.x * 4 + (threadIdx.x >> 6);   // row = b*32 + t
  int lane = threadIdx.x & 63;
  int b = row >> 5, t = row & 31;
  const float* src = yg + (size_t)b * 6144 + t;
  float v0 = src[(size_t)lane * 32];
  float v1 = src[(size_t)(lane + 64) * 32];
  float v2 = src[(size_t)(lane + 128) * 32];
  float s = v0 + v1 + v2;
  float s2 = v0 * v0 + v1 * v1 + v2 * v2;
  #pragma unroll
  for (int off = 32; off; off >>= 1) { s += __shfl_xor(s, off); s2 += __shfl_xor(s2, off); }
  float mean = s * (1.f / 192.f);
  float var = s2 * (1.f / 192.f) - mean * mean;
  float inv = rsqrtf(var + 1e-5f);
  float* yr = Y + (size_t)row * 192;
  yr[lane]       = (v0 - mean) * inv * w[lane]       + bb[lane];
  yr[lane + 64]  = (v1 - mean) * inv * w[lane + 64]  + bb[lane + 64];
  yr[lane + 128] = (v2 - mean) * inv * w[lane + 128] + bb[lane + 128];
}

// ---------------------------------------------------------------------------
// Generic GEMM: C[r][n] = sum_k A[r][k] * B[n][k] (+bias[n]); K=192 fixed.
// tile 64x64, 4x4 register block.
// ---------------------------------------------------------------------------
__global__ __launch_bounds__(256) void gemm_kernel(
    const float* __restrict__ A, const float* __restrict__ Bm,
    const float* __restrict__ bias, float* __restrict__ C,
    int N, int nTilesN) {
  int rt = blockIdx.x / nTilesN, nt = blockIdx.x % nTilesN;
  int r0 = rt * 64, n0 = nt * 64;
  __shared__ float sA[64 * 68];
  __shared__ float sB[64 * 68];
  int tid = threadIdx.x;
  int rg = tid >> 4, ng = tid & 15;
  float acc[4][4];
  #pragma unroll
  for (int i = 0; i < 4; ++i)
    #pragma unroll
    for (int j = 0; j < 4; ++j) acc[i][j] = 0.f;

  for (int k0 = 0; k0 < 192; k0 += 64) {
    __syncthreads();
    for (int j = tid; j < 1024; j += 256) {
      int rr = j >> 4, k4 = j & 15;
      float4 v = *(const float4*)&A[(size_t)(r0 + rr) * 192 + k0 + k4 * 4];
      int kb = k4 * 4;
      sA[(kb + 0) * 68 + rr] = v.x; sA[(kb + 1) * 68 + rr] = v.y;
      sA[(kb + 2) * 68 + rr] = v.z; sA[(kb + 3) * 68 + rr] = v.w;
    }
    for (int j = tid; j < 1024; j += 256) {
      int nn = j >> 4, k4 = j & 15;
      float4 v = *(const float4*)&Bm[(size_t)(n0 + nn) * 192 + k0 + k4 * 4];
      int kb = k4 * 4;
      sB[(kb + 0) * 68 + nn] = v.x; sB[(kb + 1) * 68 + nn] = v.y;
      sB[(kb + 2) * 68 + nn] = v.z; sB[(kb + 3) * 68 + nn] = v.w;
    }
    __syncthreads();
    #pragma unroll 8
    for (int kk = 0; kk < 64; ++kk) {
      float4 a = *(const float4*)&sA[kk * 68 + rg * 4];
      float4 b4 = *(const float4*)&sB[kk * 68 + ng * 4];
      acc[0][0] += a.x * b4.x; acc[0][1] += a.x * b4.y; acc[0][2] += a.x * b4.z; acc[0][3] += a.x * b4.w;
      acc[1][0] += a.y * b4.x; acc[1][1] += a.y * b4.y; acc[1][2] += a.y * b4.z; acc[1][3] += a.y * b4.w;
      acc[2][0] += a.z * b4.x; acc[2][1] += a.z * b4.y; acc[2][2] += a.z * b4.z; acc[2][3] += a.z * b4.w;
      acc[3][0] += a.w * b4.x; acc[3][1] += a.w * b4.y; acc[3][2] += a.w * b4.z; acc[3][3] += a.w * b4.w;
    }
  }
  float bv[4] = {0.f, 0.f, 0.f, 0.f};
  if (bias) {
    bv[0] = bias[n0 + ng * 4 + 0]; bv[1] = bias[n0 + ng * 4 + 1];
    bv[2] = bias[n0 + ng * 4 + 2]; bv[3] = bias[n0 + ng * 4 + 3];
  }
  #pragma unroll
  for (int i = 0; i < 4; ++i) {
    float4 o4 = {acc[i][0] + bv[0], acc[i][1] + bv[1], acc[i][2] + bv[2], acc[i][3] + bv[3]};
    *(float4*)&C[(size_t)(r0 + rg * 4 + i) * N + n0 + ng * 4] = o4;
  }
}

// ---------------------------------------------------------------------------
// Fused Bahdanau attention per (b, 16 q-rows): energy (tanh) + softmax + a@V
// ---------------------------------------------------------------------------
__global__ __launch_bounds__(256) void attn_kernel(
    const float* __restrict__ qp, const float* __restrict__ kp,
    const float* __restrict__ vp, const float* __restrict__ vw,
    float* __restrict__ ctxp) {
  int b = blockIdx.x >> 4;
  int q0 = (blockIdx.x & 15) * 16;
  __shared__ float skp[32 * 132];
  __shared__ float sqp[16 * 132];
  __shared__ float svp[32 * 192];
  __shared__ float se[16][33];
  __shared__ float svw[128];
  int tid = threadIdx.x;

  const float4* kp4 = (const float4*)(kp + (size_t)b * 32 * 128);
  for (int j = tid; j < 32 * 32; j += 256) {
    int k = j >> 5, d4 = j & 31;
    float4 v = kp4[k * 32 + d4];
    int base = k * 132 + d4 * 4;
    skp[base] = v.x; skp[base + 1] = v.y; skp[base + 2] = v.z; skp[base + 3] = v.w;
  }
  const float4* qp4 = (const float4*)(qp + (size_t)(b * 256 + q0) * 128);
  for (int j = tid; j < 16 * 32; j += 256) {
    int qq = j >> 5, d4 = j & 31;
    float4 v = qp4[qq * 32 + d4];
    int base = qq * 132 + d4 * 4;
    sqp[base] = v.x; sqp[base + 1] = v.y; sqp[base + 2] = v.z; sqp[base + 3] = v.w;
  }
  const float4* vp4 = (const float4*)(vp + (size_t)b * 32 * 192);
  for (int j = tid; j < 32 * 48; j += 256) {
    int k = j / 48, m4 = j % 48;
    *(float4*)&svp[k * 192 + m4 * 4] = vp4[k * 48 + m4];
  }
  if (tid < 128) svw[tid] = vw[tid];
  __syncthreads();

  for (int idx = tid; idx < 512; idx += 256) {
    int kk = idx >> 4, qq = idx & 15;
    const float* qrow = sqp + qq * 132;
    const float* krow = skp + kk * 132;
    float e = 0.f;
    #pragma unroll 4
    for (int d = 0; d < 128; ++d) {
      float t = qrow[d] + krow[d];
      float ex = __expf(2.f * t);
      e += svw[d] * (1.f - 2.f / (ex + 1.f));   // tanh(t)
    }
    se[qq][kk] = e;
  }
  __syncthreads();
  if (tid < 16) {
    float mx = -1e30f;
    for (int k = 0; k < 32; ++k) mx = fmaxf(mx, se[tid][k]);
    float s = 0.f;
    for (int k = 0; k < 32; ++k) { float a = __expf(se[tid][k] - mx); se[tid][k] = a; s += a; }
    float invs = 1.f / s;
    for (int k = 0; k < 32; ++k) se[tid][k] *= invs;
  }
  __syncthreads();
  for (int j = tid; j < 768; j += 256) {
    int qq = j / 48, m4 = j % 48;
    const float* al = se[qq];
    float4 a = {0.f, 0.f, 0.f, 0.f};
    #pragma unroll 8
    for (int k = 0; k < 32; ++k) {
      float wk = al[k];
      float4 v = *(const float4*)&svp[k * 192 + m4 * 4];
      a.x += wk * v.x; a.y += wk * v.y; a.z += wk * v.z; a.w += wk * v.w;
    }
    *(float4*)&ctxp[((size_t)(b * 256 + q0 + qq)) * 192 + m4 * 4] = a;
  }
}

// ---------------------------------------------------------------------------
// Final LN(q_ln + ctx2) + transpose (b,t,m) -> (b,m,t)
// ---------------------------------------------------------------------------
__global__ __launch_bounds__(256) void lnout_kernel(
    const float* __restrict__ qln, const float* __restrict__ ctx2,
    const float* __restrict__ w, const float* __restrict__ bb,
    float* __restrict__ out) {
  int b = blockIdx.x >> 2;
  int t0 = (blockIdx.x & 3) * 64;
  __shared__ float sf[64 * 193];
  int wid = threadIdx.x >> 6, lane = threadIdx.x & 63;
  for (int rr = wid; rr < 64; rr += 4) {
    size_t base = ((size_t)(b * 256 + t0 + rr)) * 192;
    float v0 = qln[base + lane]       + ctx2[base + lane];
    float v1 = qln[base + lane + 64]  + ctx2[base + lane + 64];
    float v2 = qln[base + lane + 128] + ctx2[base + lane + 128];
    float s = v0 + v1 + v2;
    float s2 = v0 * v0 + v1 * v1 + v2 * v2;
    #pragma unroll
    for (int off = 32; off; off >>= 1) { s += __shfl_xor(s, off); s2 += __shfl_xor(s2, off); }
    float mean = s * (1.f / 192.f);
    float var = s2 * (1.f / 192.f) - mean * mean;
    float inv = rsqrtf(var + 1e-5f);
    sf[rr * 193 + lane]       = (v0 - mean) * inv * w[lane]       + bb[lane];
    sf[rr * 193 + lane + 64]  = (v1 - mean) * inv * w[lane + 64]  + bb[lane + 64];
    sf[rr * 193 + lane + 128] = (v2 - mean) * inv * w[lane + 128] + bb[lane + 128];
  }
  __syncthreads();
  for (int j = threadIdx.x; j < 192 * 16; j += 256) {
    int m = j >> 4, t4 = j & 15;
    float4 o4;
    o4.x = sf[(t4 * 4 + 0) * 193 + m];
    o4.y = sf[(t4 * 4 + 1) * 193 + m];
    o4.z = sf[(t4 * 4 + 2) * 193 + m];
    o4.w = sf[(t4 * 4 + 3) * 193 + m];
    *(float4*)&out[((size_t)(b * 192 + m)) * 256 + t0 + t4 * 4] = o4;
  }
}

// ---------------------------------------------------------------------------
extern "C" void kernel_launch(void* const* d_in, const int* in_sizes, int n_in,
                              void* d_out, int out_size, void* d_ws, size_t ws_size,
                              hipStream_t stream) {
  (void)in_sizes; (void)n_in; (void)out_size; (void)ws_size;
  const float* x_p     = (const float*)d_in[0];
  const float* y_g     = (const float*)d_in[1];
  const float* conv1_w = (const float*)d_in[2];
  const float* conv1_b = (const float*)d_in[3];
  const float* gamma1  = (const float*)d_in[4];
  const float* beta1   = (const float*)d_in[5];
  const float* conv2_w = (const float*)d_in[6];
  const float* conv2_b = (const float*)d_in[7];
  const float* gamma2  = (const float*)d_in[8];
  const float* beta2   = (const float*)d_in[9];
  const float* conv3_w = (const float*)d_in[10];
  const float* conv3_b = (const float*)d_in[11];
  const float* ln_q_w  = (const float*)d_in[12];
  const float* ln_q_b  = (const float*)d_in[13];
  const float* ln_kv_w = (const float*)d_in[14];
  const float* ln_kv_b = (const float*)d_in[15];
  const float* ln_out_w= (const float*)d_in[16];
  const float* ln_out_b= (const float*)d_in[17];
  const float* Wq      = (const float*)d_in[18];
  const float* Wk      = (const float*)d_in[19];
  const float* v_w     = (const float*)d_in[20];
  const float* Wv      = (const float*)d_in[21];
  const float* out_w   = (const float*)d_in[22];
  const float* out_b   = (const float*)d_in[23];
  float* out = (float*)d_out;
  float* ws  = (float*)d_ws;

  float* t1    = ws + OFF_T1;
  float* t1b   = ws + OFF_T1B;
  float* t2    = ws + OFF_T2;
  float* t2b   = ws + OFF_T2B;
  float* qraw  = ws + OFF_QRAW;
  float* qln   = ws + OFF_QLN;
  float* kvln  = ws + OFF_KVLN;
  float* qproj = ws + OFF_QP;
  float* kproj = ws + OFF_KP;
  float* vproj = ws + OFF_VP;
  float* ctx   = ws + OFF_CTX;
  float* ctx2  = ws + OFF_CTX2;

  conv1_kernel<<<1024, 256, 0, stream>>>(x_p, conv1_w, conv1_b, t1);
  gdn_kernel<<<2048, 256, 0, stream>>>(t1, gamma1, beta1, t1b, 1024, 16);
  conv2_kernel<<<512, 256, 0, stream>>>(t1b, conv2_w, conv2_b, t2);
  gdn_kernel<<<512, 256, 0, stream>>>(t2, gamma2, beta2, t2b, 256, 4);
  conv3_kernel<<<768, 256, 0, stream>>>(t2b, conv3_w, conv3_b, qraw);
  ln_rows_kernel<<<4096, 256, 0, stream>>>(qraw, ln_q_w, ln_q_b, qln, 16384);
  ln_kv_kernel<<<512, 256, 0, stream>>>(y_g, ln_kv_w, ln_kv_b, kvln);
  gemm_kernel<<<512, 256, 0, stream>>>(qln, Wq, nullptr, qproj, 128, 2);   // q_proj (16384x128)
  gemm_kernel<<<64, 256, 0, stream>>>(kvln, Wk, nullptr, kproj, 128, 2);   // k_proj (2048x128)
  gemm_kernel<<<96, 256, 0, stream>>>(kvln, Wv, nullptr, vproj, 192, 3);   // v_proj (2048x192)
  attn_kernel<<<1024, 256, 0, stream>>>(qproj, kproj, vproj, v_w, ctx);
  gemm_kernel<<<768, 256, 0, stream>>>(ctx, out_w, out_b, ctx2, 192, 3);   // out proj
  lnout_kernel<<<256, 256, 0, stream>>>(qln, ctx2, ln_out_w, ln_out_b, out);
}

// Round 2
// 429.197 us; speedup vs baseline: 1.7597x; 1.7597x over previous
//
#include <hip/hip_runtime.h>
#include <cstddef>
#include <cstdint>

// ---------------------------------------------------------------------------
// Shapes: x (64,3,64,64) -> conv1 5x5s2 -> (64,128,32,32) -> GDN1
//   -> conv2 5x5s2 -> (64,128,16,16) -> GDN2 -> conv3 3x3s1 -> (64,192,16,16)
//   -> LN -> Bahdanau attention (D=128, Tk=32) -> out proj -> LN -> out.
// conv2/conv3 run as bf16 MFMA implicit GEMM (polyphase decomposition for the
// stride-2 conv2: 4 stride-1 phase convs with 9/6/6/4 taps).
// ---------------------------------------------------------------------------

typedef __bf16 bf16x8 __attribute__((ext_vector_type(8)));
typedef float floatx4 __attribute__((ext_vector_type(4)));
typedef unsigned short ushortT;
typedef unsigned short ushort8v __attribute__((ext_vector_type(8)));

__device__ __forceinline__ ushortT f2bf(float f) {
  unsigned u = __builtin_bit_cast(unsigned, f);
  unsigned r = (u + 0x7FFFu + ((u >> 16) & 1u)) >> 16;
  return (ushortT)r;
}

// ---- workspace layout (float-slot offsets); peak use 51.6 MB ----
static constexpr size_t OFF_T1   = 0;          // conv1 out fp32 (64,128,1024)
static constexpr size_t OFF_X2BF = 8388608;    // gdn1 out bf16 [b][4][16][16][128]
static constexpr size_t OFF_T2   = 0;          // conv2 out fp32 (64,128,256)
static constexpr size_t OFF_X3BF = 2097152;    // gdn2 out bf16 [b][1][16][16][128]
static constexpr size_t OFF_QRAW = 3145728;    // conv3 out fp32 (64,256,192)
static constexpr size_t OFF_QLN  = 6291456;    // (64,256,192)
static constexpr size_t OFF_KVLN = 9437184;    // (64,32,192)
static constexpr size_t OFF_QP   = 9830400;    // (64,256,128)
static constexpr size_t OFF_KP   = 11927552;   // (64,32,128)
static constexpr size_t OFF_VP   = 12189696;   // (64,32,192)
static constexpr size_t OFF_CTX  = 0;          // (64,256,192)
static constexpr size_t OFF_CTX2 = 3145728;    // (64,256,192)
static constexpr size_t OFF_WT2  = 12582912;   // bf16 [25][128][128]
static constexpr size_t OFF_WT3  = 12787712;   // bf16 [9][192][128]

// ---------------------------------------------------------------------------
// weight transpose+convert: w (O,C,T) fp32 -> wt (T,O,C) bf16
// ---------------------------------------------------------------------------
__global__ __launch_bounds__(256) void convw_kernel(
    const float* __restrict__ w, ushortT* __restrict__ wt,
    int OC, int T, int C, int total) {
  int idx = blockIdx.x * 256 + threadIdx.x;
  if (idx >= total) return;
  int t = idx / (OC * C);
  int rem = idx - t * OC * C;
  int o = rem / C, c = rem - o * C;
  wt[idx] = f2bf(w[(size_t)(o * C + c) * T + t]);
}

// ---------------------------------------------------------------------------
// conv1: (64,3,64,64) -> (64,128,32,32), 5x5 s2 p2. (fp32, unchanged)
// ---------------------------------------------------------------------------
__global__ __launch_bounds__(256) void conv1_kernel(
    const float* __restrict__ x, const float* __restrict__ w,
    const float* __restrict__ bias, float* __restrict__ out) {
  int b  = blockIdx.x >> 4;
  int og = blockIdx.x & 15;
  int o0 = og * 8;
  __shared__ float sx[3][64][72];
  __shared__ float sw[8 * 75];
  int tid = threadIdx.x;
  const float* xb = x + (size_t)b * 3 * 4096;
  for (int j = tid; j < 3 * 64 * 16; j += 256) {
    int c = j / 1024, rem = j % 1024;
    int row = rem >> 4, col4 = rem & 15;
    float4 v = *(const float4*)&xb[c * 4096 + row * 64 + col4 * 4];
    *(float4*)&sx[c][row][4 + col4 * 4] = v;
  }
  for (int j = tid; j < 3 * 64; j += 256) {
    int c = j / 64, row = j % 64;
    sx[c][row][0] = sx[c][row][1] = sx[c][row][2] = sx[c][row][3] = 0.f;
    sx[c][row][68] = sx[c][row][69] = sx[c][row][70] = sx[c][row][71] = 0.f;
  }
  for (int j = tid; j < 600; j += 256) sw[j] = w[o0 * 75 + j];
  __syncthreads();

  int oh = tid >> 3, ow0 = (tid & 7) * 4;
  float acc[8][4];
  #pragma unroll
  for (int oo = 0; oo < 8; ++oo)
    #pragma unroll
    for (int j = 0; j < 4; ++j) acc[oo][j] = 0.f;

  for (int c = 0; c < 3; ++c) {
    #pragma unroll
    for (int kh = 0; kh < 5; ++kh) {
      int ih = oh * 2 - 2 + kh;
      if (ih < 0 || ih >= 64) continue;
      float rv[16];
      *(float4*)&rv[0]  = *(const float4*)&sx[c][ih][ow0 * 2];
      *(float4*)&rv[4]  = *(const float4*)&sx[c][ih][ow0 * 2 + 4];
      *(float4*)&rv[8]  = *(const float4*)&sx[c][ih][ow0 * 2 + 8];
      *(float4*)&rv[12] = *(const float4*)&sx[c][ih][ow0 * 2 + 12];
      #pragma unroll
      for (int kw = 0; kw < 5; ++kw) {
        float wv[8];
        #pragma unroll
        for (int oo = 0; oo < 8; ++oo) wv[oo] = sw[oo * 75 + c * 25 + kh * 5 + kw];
        #pragma unroll
        for (int oo = 0; oo < 8; ++oo)
          #pragma unroll
          for (int j = 0; j < 4; ++j)
            acc[oo][j] += wv[oo] * rv[2 + kw + 2 * j];
      }
    }
  }
  #pragma unroll
  for (int oo = 0; oo < 8; ++oo) {
    float bv = bias[o0 + oo];
    float4 o4 = {acc[oo][0] + bv, acc[oo][1] + bv, acc[oo][2] + bv, acc[oo][3] + bv};
    *(float4*)&out[((size_t)(b * 128 + o0 + oo)) * 1024 + oh * 32 + ow0] = o4;
  }
}

// ---------------------------------------------------------------------------
// GDN (fp32 GEMM math) -> bf16 output in [b][phase][i][j][c] layout.
// isSplit=1: 32x32 image, 4 phases (for conv2). isSplit=0: 16x16, 1 phase.
// ---------------------------------------------------------------------------
__global__ __launch_bounds__(256) void gdn_kernel(
    const float* __restrict__ x, const float* __restrict__ gamma,
    const float* __restrict__ beta, ushortT* __restrict__ ybf,
    int HW, int nPixTiles, int isSplit) {
  int dt = blockIdx.x & 1;
  int pt = (blockIdx.x >> 1) % nPixTiles;
  int b  = blockIdx.x / (2 * nPixTiles);
  int d0 = dt * 64, p0 = pt * 64;
  const float* xb = x + (size_t)b * 128 * HW;
  __shared__ float sA[64 * 68];   // [kk][dd] gamma; reused for output transpose
  __shared__ float sB[64 * 68];   // [kk][nn] x^2
  int tid = threadIdx.x;
  int rg = tid >> 4, ng = tid & 15;
  float acc[4][4];
  #pragma unroll
  for (int i = 0; i < 4; ++i)
    #pragma unroll
    for (int j = 0; j < 4; ++j) acc[i][j] = 0.f;

  for (int c0 = 0; c0 < 128; c0 += 64) {
    __syncthreads();
    for (int j = tid; j < 1024; j += 256) {
      int dd = j >> 4, k4 = j & 15;
      float4 v = *(const float4*)&gamma[(size_t)(d0 + dd) * 128 + c0 + k4 * 4];
      int kb = k4 * 4;
      sA[(kb + 0) * 68 + dd] = v.x; sA[(kb + 1) * 68 + dd] = v.y;
      sA[(kb + 2) * 68 + dd] = v.z; sA[(kb + 3) * 68 + dd] = v.w;
    }
    for (int j = tid; j < 1024; j += 256) {
      int kk = j >> 4, n4 = j & 15;
      float4 v = *(const float4*)&xb[(size_t)(c0 + kk) * HW + p0 + n4 * 4];
      v.x *= v.x; v.y *= v.y; v.z *= v.z; v.w *= v.w;
      *(float4*)&sB[kk * 68 + n4 * 4] = v;
    }
    __syncthreads();
    #pragma unroll 8
    for (int kk = 0; kk < 64; ++kk) {
      float4 a = *(const float4*)&sA[kk * 68 + rg * 4];
      float4 bb4 = *(const float4*)&sB[kk * 68 + ng * 4];
      acc[0][0] += a.x * bb4.x; acc[0][1] += a.x * bb4.y; acc[0][2] += a.x * bb4.z; acc[0][3] += a.x * bb4.w;
      acc[1][0] += a.y * bb4.x; acc[1][1] += a.y * bb4.y; acc[1][2] += a.y * bb4.z; acc[1][3] += a.y * bb4.w;
      acc[2][0] += a.z * bb4.x; acc[2][1] += a.z * bb4.y; acc[2][2] += a.z * bb4.z; acc[2][3] += a.z * bb4.w;
      acc[3][0] += a.w * bb4.x; acc[3][1] += a.w * bb4.y; acc[3][2] += a.w * bb4.z; acc[3][3] += a.w * bb4.w;
    }
  }
  // y values
  float yv[4][4];
  #pragma unroll
  for (int i = 0; i < 4; ++i) {
    int d = d0 + rg * 4 + i;
    float bt = beta[d];
    float4 xv = *(const float4*)&xb[(size_t)d * HW + p0 + ng * 4];
    yv[i][0] = xv.x * rsqrtf(acc[i][0] + bt);
    yv[i][1] = xv.y * rsqrtf(acc[i][1] + bt);
    yv[i][2] = xv.z * rsqrtf(acc[i][2] + bt);
    yv[i][3] = xv.w * rsqrtf(acc[i][3] + bt);
  }
  // transpose to [pixel][channel] in sA, then emit bf16 channel-contiguous
  __syncthreads();
  #pragma unroll
  for (int j = 0; j < 4; ++j) {
    float4 col = {yv[0][j], yv[1][j], yv[2][j], yv[3][j]};
    *(float4*)&sA[(ng * 4 + j) * 68 + rg * 4] = col;
  }
  __syncthreads();
  for (int idx = tid; idx < 512; idx += 256) {
    int px = idx >> 3, c8 = idx & 7;
    const float* src = &sA[px * 68 + c8 * 8];
    ushort8v uv;
    #pragma unroll
    for (int k = 0; k < 8; ++k) uv[k] = f2bf(src[k]);
    int p = p0 + px;
    size_t base;
    if (isSplit) {            // 32x32 -> phase split
      int h = p >> 5, w5 = p & 31;
      int ph = ((h & 1) << 1) | (w5 & 1);
      base = (((size_t)b * 4 + ph) * 256 + (h >> 1) * 16 + (w5 >> 1));
    } else {                  // 16x16 direct
      base = ((size_t)b * 256 + p);
    }
    *(ushort8v*)&ybf[base * 128 + d0 + c8 * 8] = uv;
  }
}

// ---------------------------------------------------------------------------
// bf16 MFMA implicit-GEMM conv over 16x16 images with small taps.
// MODE 0: conv2 (4 phases, 25 taps total, OC=128, out fp32 (b,m,16,16))
// MODE 1: conv3 (1 phase, 9 taps, OC=192, out fp32 (b,t,192))
// Block: one b, one M-tile, one row-half (8 output rows). 4 waves;
// wave w owns rows r0+2w, r0+2w+1. A-frags straight from global (L2-resident
// transposed weights), B-frags from LDS phase image [row][col][c pad 136].
// ---------------------------------------------------------------------------
template<int MODE>
__global__ __launch_bounds__(256) void conv_mfma_kernel(
    const ushortT* __restrict__ X,   // [b][NPH][16][16][128] bf16
    const ushortT* __restrict__ Wt,  // [widx][OC][128] bf16
    const float* __restrict__ bias,
    float* __restrict__ out) {
  constexpr int OC    = (MODE == 0) ? 128 : 192;
  constexpr int MTILE = (MODE == 0) ? 64 : 48;
  constexpr int MB    = MTILE / 16;
  constexpr int NPH   = (MODE == 0) ? 4 : 1;
  constexpr int NMT   = OC / MTILE;

  int b   = blockIdx.x / (NMT * 2);
  int rem = blockIdx.x % (NMT * 2);
  int mt  = rem >> 1;
  int rs  = rem & 1;
  int r0  = rs * 8;

  int wave = threadIdx.x >> 6;
  int lane = threadIdx.x & 63;
  int ln15 = lane & 15;
  int kg   = lane >> 4;

  __shared__ ushortT simg[10 * 18 * 136];   // 48.96 KB

  floatx4 acc[MB][2];
  #pragma unroll
  for (int m = 0; m < MB; ++m) { acc[m][0] = (floatx4)0.f; acc[m][1] = (floatx4)0.f; }

  // tap tables
  constexpr int PH_NT_2[4] = {9, 6, 6, 4};
  constexpr int TDR_2[4][9] = {{-1,-1,-1, 0, 0, 0, 1, 1, 1},
                               {-1,-1, 0, 0, 1, 1, 0, 0, 0},
                               {-1,-1,-1, 0, 0, 0, 0, 0, 0},
                               {-1,-1, 0, 0, 0, 0, 0, 0, 0}};
  constexpr int TDC_2[4][9] = {{-1, 0, 1,-1, 0, 1,-1, 0, 1},
                               {-1, 0,-1, 0,-1, 0, 0, 0, 0},
                               {-1, 0, 1,-1, 0, 1, 0, 0, 0},
                               {-1, 0,-1, 0, 0, 0, 0, 0, 0}};
  constexpr int TWI_2[4][9] = {{ 0, 2, 4,10,12,14,20,22,24},
                               { 1, 3,11,13,21,23, 0, 0, 0},
                               { 5, 7, 9,15,17,19, 0, 0, 0},
                               { 6, 8,16,18, 0, 0, 0, 0, 0}};
  constexpr int TDR_3[9] = {-1,-1,-1, 0, 0, 0, 1, 1, 1};
  constexpr int TDC_3[9] = {-1, 0, 1,-1, 0, 1,-1, 0, 1};

  #pragma unroll
  for (int ph = 0; ph < NPH; ++ph) {
    __syncthreads();
    // stage phase image: rows r0-1..r0+8, cols -1..16, all 128 ch
    const ushortT* Xb = X + (((size_t)b * NPH + ph) * 256) * 128;
    for (int idx = threadIdx.x; idx < 2880; idx += 256) {
      int chunk = idx & 15;
      int pix = idx >> 4;
      int row = pix / 18, colm = pix - row * 18;
      int i = r0 - 1 + row, j = colm - 1;
      uint4 v = {0u, 0u, 0u, 0u};
      if (i >= 0 && i < 16 && j >= 0 && j < 16)
        v = *(const uint4*)(Xb + ((size_t)(i * 16 + j)) * 128 + chunk * 8);
      *(uint4*)&simg[(row * 18 + colm) * 136 + chunk * 8] = v;
    }
    __syncthreads();

    const int NT = (MODE == 0) ? PH_NT_2[ph] : 9;
    for (int c0 = 0; c0 < 128; c0 += 32) {
      const ushortT* wbase = Wt + ((size_t)(mt * MTILE + ln15)) * 128 + c0 + kg * 8;
      #pragma unroll
      for (int t = 0; t < 9; ++t) {
        if (t >= NT) break;
        int dr = (MODE == 0) ? TDR_2[ph][t] : TDR_3[t];
        int dc = (MODE == 0) ? TDC_2[ph][t] : TDC_3[t];
        int wi = (MODE == 0) ? TWI_2[ph][t] : t;
        // A fragments (global, L2-hit)
        bf16x8 afr[MB];
        const ushortT* wp = wbase + (size_t)wi * OC * 128;
        #pragma unroll
        for (int m = 0; m < MB; ++m) afr[m] = *(const bf16x8*)(wp + m * 16 * 128);
        // B fragments + MFMA
        #pragma unroll
        for (int rw = 0; rw < 2; ++rw) {
          int lrow = wave * 2 + rw + dr + 1;
          int lcol = ln15 + dc + 1;
          bf16x8 bfr = *(const bf16x8*)&simg[(lrow * 18 + lcol) * 136 + c0 + kg * 8];
          #pragma unroll
          for (int m = 0; m < MB; ++m)
            acc[m][rw] = __builtin_amdgcn_mfma_f32_16x16x32_bf16(afr[m], bfr, acc[m][rw], 0, 0, 0);
        }
      }
    }
  }

  // epilogue
  #pragma unroll
  for (int m = 0; m < MB; ++m) {
    int mg = mt * MTILE + m * 16 + kg * 4;
    float4 bv = *(const float4*)&bias[mg];
    #pragma unroll
    for (int rw = 0; rw < 2; ++rw) {
      int r = r0 + wave * 2 + rw;
      if (MODE == 0) {
        int p = r * 16 + ln15;
        float* op = out + ((size_t)b * 128 + mg) * 256 + p;
        op[0]   = acc[m][rw][0] + bv.x;
        op[256] = acc[m][rw][1] + bv.y;
        op[512] = acc[m][rw][2] + bv.z;
        op[768] = acc[m][rw][3] + bv.w;
      } else {
        int t = r * 16 + ln15;
        float4 o4 = {acc[m][rw][0] + bv.x, acc[m][rw][1] + bv.y,
                     acc[m][rw][2] + bv.z, acc[m][rw][3] + bv.w};
        *(float4*)&out[((size_t)b * 256 + t) * 192 + mg] = o4;
      }
    }
  }
}

// ---------------------------------------------------------------------------
// LayerNorm over contiguous rows of length 192.
// ---------------------------------------------------------------------------
__global__ __launch_bounds__(256) void ln_rows_kernel(
    const float* __restrict__ X, const float* __restrict__ w,
    const float* __restrict__ bb, float* __restrict__ Y, int R) {
  int row = blockIdx.x * 4 + (threadIdx.x >> 6);
  int lane = threadIdx.x & 63;
  if (row >= R) return;
  const float* xr = X + (size_t)row * 192;
  float v0 = xr[lane], v1 = xr[lane + 64], v2 = xr[lane + 128];
  float s = v0 + v1 + v2;
  float s2 = v0 * v0 + v1 * v1 + v2 * v2;
  #pragma unroll
  for (int off = 32; off; off >>= 1) { s += __shfl_xor(s, off); s2 += __shfl_xor(s2, off); }
  float mean = s * (1.f / 192.f);
  float var = s2 * (1.f / 192.f) - mean * mean;
  float inv = rsqrtf(var + 1e-5f);
  float* yr = Y + (size_t)row * 192;
  yr[lane]       = (v0 - mean) * inv * w[lane]       + bb[lane];
  yr[lane + 64]  = (v1 - mean) * inv * w[lane + 64]  + bb[lane + 64];
  yr[lane + 128] = (v2 - mean) * inv * w[lane + 128] + bb[lane + 128];
}

// ---------------------------------------------------------------------------
// kv LN: gather y_g (64,192,32) -> kv_ln (64,32,192) with LN over 192.
// ---------------------------------------------------------------------------
__global__ __launch_bounds__(256) void ln_kv_kernel(
    const float* __restrict__ yg, const float* __restrict__ w,
    const float* __restrict__ bb, float* __restrict__ Y) {
  int row = blockIdx.x * 4 + (threadIdx.x >> 6);
  int lane = threadIdx.x & 63;
  int b = row >> 5, t = row & 31;
  const float* src = yg + (size_t)b * 6144 + t;
  float v0 = src[(size_t)lane * 32];
  float v1 = src[(size_t)(lane + 64) * 32];
  float v2 = src[(size_t)(lane + 128) * 32];
  float s = v0 + v1 + v2;
  float s2 = v0 * v0 + v1 * v1 + v2 * v2;
  #pragma unroll
  for (int off = 32; off; off >>= 1) { s += __shfl_xor(s, off); s2 += __shfl_xor(s2, off); }
  float mean = s * (1.f / 192.f);
  float var = s2 * (1.f / 192.f) - mean * mean;
  float inv = rsqrtf(var + 1e-5f);
  float* yr = Y + (size_t)row * 192;
  yr[lane]       = (v0 - mean) * inv * w[lane]       + bb[lane];
  yr[lane + 64]  = (v1 - mean) * inv * w[lane + 64]  + bb[lane + 64];
  yr[lane + 128] = (v2 - mean) * inv * w[lane + 128] + bb[lane + 128];
}

// ---------------------------------------------------------------------------
// Generic fp32 GEMM: C[r][n] = sum_k A[r][k]*B[n][k] (+bias[n]); K=192.
// ---------------------------------------------------------------------------
__global__ __launch_bounds__(256) void gemm_kernel(
    const float* __restrict__ A, const float* __restrict__ Bm,
    const float* __restrict__ bias, float* __restrict__ C,
    int N, int nTilesN) {
  int rt = blockIdx.x / nTilesN, nt = blockIdx.x % nTilesN;
  int r0 = rt * 64, n0 = nt * 64;
  __shared__ float sA[64 * 68];
  __shared__ float sB[64 * 68];
  int tid = threadIdx.x;
  int rg = tid >> 4, ng = tid & 15;
  float acc[4][4];
  #pragma unroll
  for (int i = 0; i < 4; ++i)
    #pragma unroll
    for (int j = 0; j < 4; ++j) acc[i][j] = 0.f;

  for (int k0 = 0; k0 < 192; k0 += 64) {
    __syncthreads();
    for (int j = tid; j < 1024; j += 256) {
      int rr = j >> 4, k4 = j & 15;
      float4 v = *(const float4*)&A[(size_t)(r0 + rr) * 192 + k0 + k4 * 4];
      int kb = k4 * 4;
      sA[(kb + 0) * 68 + rr] = v.x; sA[(kb + 1) * 68 + rr] = v.y;
      sA[(kb + 2) * 68 + rr] = v.z; sA[(kb + 3) * 68 + rr] = v.w;
    }
    for (int j = tid; j < 1024; j += 256) {
      int nn = j >> 4, k4 = j & 15;
      float4 v = *(const float4*)&Bm[(size_t)(n0 + nn) * 192 + k0 + k4 * 4];
      int kb = k4 * 4;
      sB[(kb + 0) * 68 + nn] = v.x; sB[(kb + 1) * 68 + nn] = v.y;
      sB[(kb + 2) * 68 + nn] = v.z; sB[(kb + 3) * 68 + nn] = v.w;
    }
    __syncthreads();
    #pragma unroll 8
    for (int kk = 0; kk < 64; ++kk) {
      float4 a = *(const float4*)&sA[kk * 68 + rg * 4];
      float4 b4 = *(const float4*)&sB[kk * 68 + ng * 4];
      acc[0][0] += a.x * b4.x; acc[0][1] += a.x * b4.y; acc[0][2] += a.x * b4.z; acc[0][3] += a.x * b4.w;
      acc[1][0] += a.y * b4.x; acc[1][1] += a.y * b4.y; acc[1][2] += a.y * b4.z; acc[1][3] += a.y * b4.w;
      acc[2][0] += a.z * b4.x; acc[2][1] += a.z * b4.y; acc[2][2] += a.z * b4.z; acc[2][3] += a.z * b4.w;
      acc[3][0] += a.w * b4.x; acc[3][1] += a.w * b4.y; acc[3][2] += a.w * b4.z; acc[3][3] += a.w * b4.w;
    }
  }
  float bv[4] = {0.f, 0.f, 0.f, 0.f};
  if (bias) {
    bv[0] = bias[n0 + ng * 4 + 0]; bv[1] = bias[n0 + ng * 4 + 1];
    bv[2] = bias[n0 + ng * 4 + 2]; bv[3] = bias[n0 + ng * 4 + 3];
  }
  #pragma unroll
  for (int i = 0; i < 4; ++i) {
    float4 o4 = {acc[i][0] + bv[0], acc[i][1] + bv[1], acc[i][2] + bv[2], acc[i][3] + bv[3]};
    *(float4*)&C[(size_t)(r0 + rg * 4 + i) * N + n0 + ng * 4] = o4;
  }
}

// ---------------------------------------------------------------------------
// Fused Bahdanau attention per (b, 16 q-rows): energy (tanh) + softmax + a@V
// ---------------------------------------------------------------------------
__global__ __launch_bounds__(256) void attn_kernel(
    const float* __restrict__ qp, const float* __restrict__ kp,
    const float* __restrict__ vp, const float* __restrict__ vw,
    float* __restrict__ ctxp) {
  int b = blockIdx.x >> 4;
  int q0 = (blockIdx.x & 15) * 16;
  __shared__ float skp[32 * 132];
  __shared__ float sqp[16 * 132];
  __shared__ float svp[32 * 192];
  __shared__ float se[16][33];
  __shared__ float svw[128];
  int tid = threadIdx.x;

  const float4* kp4 = (const float4*)(kp + (size_t)b * 32 * 128);
  for (int j = tid; j < 32 * 32; j += 256) {
    int k = j >> 5, d4 = j & 31;
    float4 v = kp4[k * 32 + d4];
    int base = k * 132 + d4 * 4;
    skp[base] = v.x; skp[base + 1] = v.y; skp[base + 2] = v.z; skp[base + 3] = v.w;
  }
  const float4* qp4 = (const float4*)(qp + (size_t)(b * 256 + q0) * 128);
  for (int j = tid; j < 16 * 32; j += 256) {
    int qq = j >> 5, d4 = j & 31;
    float4 v = qp4[qq * 32 + d4];
    int base = qq * 132 + d4 * 4;
    sqp[base] = v.x; sqp[base + 1] = v.y; sqp[base + 2] = v.z; sqp[base + 3] = v.w;
  }
  const float4* vp4 = (const float4*)(vp + (size_t)b * 32 * 192);
  for (int j = tid; j < 32 * 48; j += 256) {
    int k = j / 48, m4 = j % 48;
    *(float4*)&svp[k * 192 + m4 * 4] = vp4[k * 48 + m4];
  }
  if (tid < 128) svw[tid] = vw[tid];
  __syncthreads();

  for (int idx = tid; idx < 512; idx += 256) {
    int kk = idx >> 4, qq = idx & 15;
    const float* qrow = sqp + qq * 132;
    const float* krow = skp + kk * 132;
    float e = 0.f;
    #pragma unroll 4
    for (int d = 0; d < 128; ++d) {
      float t = qrow[d] + krow[d];
      float ex = __expf(2.f * t);
      e += svw[d] * (1.f - 2.f / (ex + 1.f));   // tanh(t)
    }
    se[qq][kk] = e;
  }
  __syncthreads();
  if (tid < 16) {
    float mx = -1e30f;
    for (int k = 0; k < 32; ++k) mx = fmaxf(mx, se[tid][k]);
    float s = 0.f;
    for (int k = 0; k < 32; ++k) { float a = __expf(se[tid][k] - mx); se[tid][k] = a; s += a; }
    float invs = 1.f / s;
    for (int k = 0; k < 32; ++k) se[tid][k] *= invs;
  }
  __syncthreads();
  for (int j = tid; j < 768; j += 256) {
    int qq = j / 48, m4 = j % 48;
    const float* al = se[qq];
    float4 a = {0.f, 0.f, 0.f, 0.f};
    #pragma unroll 8
    for (int k = 0; k < 32; ++k) {
      float wk = al[k];
      float4 v = *(const float4*)&svp[k * 192 + m4 * 4];
      a.x += wk * v.x; a.y += wk * v.y; a.z += wk * v.z; a.w += wk * v.w;
    }
    *(float4*)&ctxp[((size_t)(b * 256 + q0 + qq)) * 192 + m4 * 4] = a;
  }
}

// ---------------------------------------------------------------------------
// Final LN(q_ln + ctx2) + transpose (b,t,m) -> (b,m,t)
// ---------------------------------------------------------------------------
__global__ __launch_bounds__(256) void lnout_kernel(
    const float* __restrict__ qln, const float* __restrict__ ctx2,
    const float* __restrict__ w, const float* __restrict__ bb,
    float* __restrict__ out) {
  int b = blockIdx.x >> 2;
  int t0 = (blockIdx.x & 3) * 64;
  __shared__ float sf[64 * 193];
  int wid = threadIdx.x >> 6, lane = threadIdx.x & 63;
  for (int rr = wid; rr < 64; rr += 4) {
    size_t base = ((size_t)(b * 256 + t0 + rr)) * 192;
    float v0 = qln[base + lane]       + ctx2[base + lane];
    float v1 = qln[base + lane + 64]  + ctx2[base + lane + 64];
    float v2 = qln[base + lane + 128] + ctx2[base + lane + 128];
    float s = v0 + v1 + v2;
    float s2 = v0 * v0 + v1 * v1 + v2 * v2;
    #pragma unroll
    for (int off = 32; off; off >>= 1) { s += __shfl_xor(s, off); s2 += __shfl_xor(s2, off); }
    float mean = s * (1.f / 192.f);
    float var = s2 * (1.f / 192.f) - mean * mean;
    float inv = rsqrtf(var + 1e-5f);
    sf[rr * 193 + lane]       = (v0 - mean) * inv * w[lane]       + bb[lane];
    sf[rr * 193 + lane + 64]  = (v1 - mean) * inv * w[lane + 64]  + bb[lane + 64];
    sf[rr * 193 + lane + 128] = (v2 - mean) * inv * w[lane + 128] + bb[lane + 128];
  }
  __syncthreads();
  for (int j = threadIdx.x; j < 192 * 16; j += 256) {
    int m = j >> 4, t4 = j & 15;
    float4 o4;
    o4.x = sf[(t4 * 4 + 0) * 193 + m];
    o4.y = sf[(t4 * 4 + 1) * 193 + m];
    o4.z = sf[(t4 * 4 + 2) * 193 + m];
    o4.w = sf[(t4 * 4 + 3) * 193 + m];
    *(float4*)&out[((size_t)(b * 192 + m)) * 256 + t0 + t4 * 4] = o4;
  }
}

// ---------------------------------------------------------------------------
extern "C" void kernel_launch(void* const* d_in, const int* in_sizes, int n_in,
                              void* d_out, int out_size, void* d_ws, size_t ws_size,
                              hipStream_t stream) {
  (void)in_sizes; (void)n_in; (void)out_size; (void)ws_size;
  const float* x_p     = (const float*)d_in[0];
  const float* y_g     = (const float*)d_in[1];
  const float* conv1_w = (const float*)d_in[2];
  const float* conv1_b = (const float*)d_in[3];
  const float* gamma1  = (const float*)d_in[4];
  const float* beta1   = (const float*)d_in[5];
  const float* conv2_w = (const float*)d_in[6];
  const float* conv2_b = (const float*)d_in[7];
  const float* gamma2  = (const float*)d_in[8];
  const float* beta2   = (const float*)d_in[9];
  const float* conv3_w = (const float*)d_in[10];
  const float* conv3_b = (const float*)d_in[11];
  const float* ln_q_w  = (const float*)d_in[12];
  const float* ln_q_b  = (const float*)d_in[13];
  const float* ln_kv_w = (const float*)d_in[14];
  const float* ln_kv_b = (const float*)d_in[15];
  const float* ln_out_w= (const float*)d_in[16];
  const float* ln_out_b= (const float*)d_in[17];
  const float* Wq      = (const float*)d_in[18];
  const float* Wk      = (const float*)d_in[19];
  const float* v_w     = (const float*)d_in[20];
  const float* Wv      = (const float*)d_in[21];
  const float* out_w   = (const float*)d_in[22];
  const float* out_b   = (const float*)d_in[23];
  float* out = (float*)d_out;
  float* ws  = (float*)d_ws;

  float*   t1    = ws + OFF_T1;
  ushortT* x2bf  = (ushortT*)(ws + OFF_X2BF);
  float*   t2    = ws + OFF_T2;
  ushortT* x3bf  = (ushortT*)(ws + OFF_X3BF);
  float*   qraw  = ws + OFF_QRAW;
  float*   qln   = ws + OFF_QLN;
  float*   kvln  = ws + OFF_KVLN;
  float*   qproj = ws + OFF_QP;
  float*   kproj = ws + OFF_KP;
  float*   vproj = ws + OFF_VP;
  float*   ctx   = ws + OFF_CTX;
  float*   ctx2  = ws + OFF_CTX2;
  ushortT* wt2   = (ushortT*)(ws + OFF_WT2);
  ushortT* wt3   = (ushortT*)(ws + OFF_WT3);

  convw_kernel<<<1600, 256, 0, stream>>>(conv2_w, wt2, 128, 25, 128, 409600);
  convw_kernel<<<864, 256, 0, stream>>>(conv3_w, wt3, 192, 9, 128, 221184);
  conv1_kernel<<<1024, 256, 0, stream>>>(x_p, conv1_w, conv1_b, t1);
  gdn_kernel<<<2048, 256, 0, stream>>>(t1, gamma1, beta1, x2bf, 1024, 16, 1);
  conv_mfma_kernel<0><<<256, 256, 0, stream>>>(x2bf, wt2, conv2_b, t2);
  gdn_kernel<<<512, 256, 0, stream>>>(t2, gamma2, beta2, x3bf, 256, 4, 0);
  conv_mfma_kernel<1><<<512, 256, 0, stream>>>(x3bf, wt3, conv3_b, qraw);
  ln_rows_kernel<<<4096, 256, 0, stream>>>(qraw, ln_q_w, ln_q_b, qln, 16384);
  ln_kv_kernel<<<512, 256, 0, stream>>>(y_g, ln_kv_w, ln_kv_b, kvln);
  gemm_kernel<<<512, 256, 0, stream>>>(qln, Wq, nullptr, qproj, 128, 2);
  gemm_kernel<<<64, 256, 0, stream>>>(kvln, Wk, nullptr, kproj, 128, 2);
  gemm_kernel<<<96, 256, 0, stream>>>(kvln, Wv, nullptr, vproj, 192, 3);
  attn_kernel<<<1024, 256, 0, stream>>>(qproj, kproj, vproj, v_w, ctx);
  gemm_kernel<<<768, 256, 0, stream>>>(ctx, out_w, out_b, ctx2, 192, 3);
  lnout_kernel<<<256, 256, 0, stream>>>(qln, ctx2, ln_out_w, ln_out_b, out);
}

// Round 3
// 372.627 us; speedup vs baseline: 2.0269x; 1.1518x over previous
//
#include <hip/hip_runtime.h>
#include <cstddef>
#include <cstdint>

// ---------------------------------------------------------------------------
// Shapes: x (64,3,64,64) -> conv1 5x5s2 -> (64,128,32,32) -> GDN1
//   -> conv2 5x5s2 -> (64,128,16,16) -> GDN2 -> conv3 3x3s1 -> (64,192,16,16)
//   -> LN -> Bahdanau attention (D=128, Tk=32) -> out proj -> LN -> out.
// conv2/conv3: bf16 MFMA implicit GEMM (polyphase for stride-2), register-
// prefetched weight slabs. Projections: bf16 MFMA GEMM, K=192 in LDS.
// ---------------------------------------------------------------------------

typedef __bf16 bf16x8 __attribute__((ext_vector_type(8)));
typedef float floatx4 __attribute__((ext_vector_type(4)));
typedef unsigned short ushortT;
typedef unsigned short ushort8v __attribute__((ext_vector_type(8)));

__device__ __forceinline__ ushortT f2bf(float f) {
  unsigned u = __builtin_bit_cast(unsigned, f);
  unsigned r = (u + 0x7FFFu + ((u >> 16) & 1u)) >> 16;
  return (ushortT)r;
}

// ---- workspace layout (float-slot offsets); peak ~56 MB ----
static constexpr size_t OFF_T1   = 0;          // conv1 out fp32 (64,128,1024)
static constexpr size_t OFF_X2BF = 8388608;    // gdn1 out bf16 [b][4][256][128]
static constexpr size_t OFF_T2   = 0;          // conv2 out fp32 (64,128,256)
static constexpr size_t OFF_X3BF = 2097152;    // gdn2 out bf16 [b][256][128]
static constexpr size_t OFF_QRAW = 3145728;    // conv3 out fp32 (64,256,192)
static constexpr size_t OFF_QLN  = 6291456;    // fp32 (64,256,192)
static constexpr size_t OFF_QLNB = 9437184;    // bf16 (64,256,192)
static constexpr size_t OFF_KVB  = 11010048;   // bf16 (64,32,192)
static constexpr size_t OFF_QP   = 11206656;   // fp32 (64,256,128)
static constexpr size_t OFF_KP   = 13303808;   // fp32 (64,32,128)
static constexpr size_t OFF_VP   = 13565952;   // fp32 (64,32,192)
static constexpr size_t OFF_WBQ  = 13959168;   // bf16 128x192
static constexpr size_t OFF_WBK  = 13971456;   // bf16 128x192
static constexpr size_t OFF_WBV  = 13983744;   // bf16 192x192
static constexpr size_t OFF_WBO  = 14002176;   // bf16 192x192
static constexpr size_t OFF_CTXB = 0;          // bf16 (64,256,192)
static constexpr size_t OFF_CTX2 = 3145728;    // fp32 (64,256,192)
static constexpr size_t OFF_WT2  = 12582912;   // bf16 conv2 slabs [25][4][2][2048]
static constexpr size_t OFF_WT3  = 12787712;   // bf16 conv3 slabs [9][4][3][2048]

// ---------------------------------------------------------------------------
// conv weight repack: w (O,C=128,T) fp32 OIHW -> slabs:
// wt[((tap*4+cc)*NMT+mt)*2048 + kg*512 + om*8 + j], oc=mt*64+om, c=cc*32+kg*8+j
// ---------------------------------------------------------------------------
__global__ __launch_bounds__(256) void convw2_kernel(
    const float* __restrict__ w, ushortT* __restrict__ wt,
    int NMT, int T, int total) {
  int idx = blockIdx.x * 256 + threadIdx.x;
  if (idx >= total) return;
  int j  = idx & 7;
  int om = (idx >> 3) & 63;
  int kg = (idx >> 9) & 3;
  int r  = idx >> 11;
  int mt = r % NMT;
  int r2 = r / NMT;
  int cc = r2 & 3;
  int tap = r2 >> 2;
  int c  = cc * 32 + kg * 8 + j;
  int oc = mt * 64 + om;
  wt[idx] = f2bf(w[(size_t)(oc * 128 + c) * T + tap]);
}

// plain fp32 -> bf16 cast
__global__ __launch_bounds__(256) void wcast_kernel(
    const float* __restrict__ w, ushortT* __restrict__ wb, int total) {
  int idx = blockIdx.x * 256 + threadIdx.x;
  if (idx < total) wb[idx] = f2bf(w[idx]);
}

// ---------------------------------------------------------------------------
// conv1: (64,3,64,64) -> (64,128,32,32), 5x5 s2 p2. (fp32)
// ---------------------------------------------------------------------------
__global__ __launch_bounds__(256) void conv1_kernel(
    const float* __restrict__ x, const float* __restrict__ w,
    const float* __restrict__ bias, float* __restrict__ out) {
  int b  = blockIdx.x >> 4;
  int og = blockIdx.x & 15;
  int o0 = og * 8;
  __shared__ float sx[3][64][72];
  __shared__ float sw[8 * 75];
  int tid = threadIdx.x;
  const float* xb = x + (size_t)b * 3 * 4096;
  for (int j = tid; j < 3 * 64 * 16; j += 256) {
    int c = j / 1024, rem = j % 1024;
    int row = rem >> 4, col4 = rem & 15;
    float4 v = *(const float4*)&xb[c * 4096 + row * 64 + col4 * 4];
    *(float4*)&sx[c][row][4 + col4 * 4] = v;
  }
  for (int j = tid; j < 3 * 64; j += 256) {
    int c = j / 64, row = j % 64;
    sx[c][row][0] = sx[c][row][1] = sx[c][row][2] = sx[c][row][3] = 0.f;
    sx[c][row][68] = sx[c][row][69] = sx[c][row][70] = sx[c][row][71] = 0.f;
  }
  for (int j = tid; j < 600; j += 256) sw[j] = w[o0 * 75 + j];
  __syncthreads();

  int oh = tid >> 3, ow0 = (tid & 7) * 4;
  float acc[8][4];
  #pragma unroll
  for (int oo = 0; oo < 8; ++oo)
    #pragma unroll
    for (int j = 0; j < 4; ++j) acc[oo][j] = 0.f;

  for (int c = 0; c < 3; ++c) {
    #pragma unroll
    for (int kh = 0; kh < 5; ++kh) {
      int ih = oh * 2 - 2 + kh;
      if (ih < 0 || ih >= 64) continue;
      float rv[16];
      *(float4*)&rv[0]  = *(const float4*)&sx[c][ih][ow0 * 2];
      *(float4*)&rv[4]  = *(const float4*)&sx[c][ih][ow0 * 2 + 4];
      *(float4*)&rv[8]  = *(const float4*)&sx[c][ih][ow0 * 2 + 8];
      *(float4*)&rv[12] = *(const float4*)&sx[c][ih][ow0 * 2 + 12];
      #pragma unroll
      for (int kw = 0; kw < 5; ++kw) {
        float wv[8];
        #pragma unroll
        for (int oo = 0; oo < 8; ++oo) wv[oo] = sw[oo * 75 + c * 25 + kh * 5 + kw];
        #pragma unroll
        for (int oo = 0; oo < 8; ++oo)
          #pragma unroll
          for (int j = 0; j < 4; ++j)
            acc[oo][j] += wv[oo] * rv[2 + kw + 2 * j];
      }
    }
  }
  #pragma unroll
  for (int oo = 0; oo < 8; ++oo) {
    float bv = bias[o0 + oo];
    float4 o4 = {acc[oo][0] + bv, acc[oo][1] + bv, acc[oo][2] + bv, acc[oo][3] + bv};
    *(float4*)&out[((size_t)(b * 128 + o0 + oo)) * 1024 + oh * 32 + ow0] = o4;
  }
}

// ---------------------------------------------------------------------------
// GDN (fp32 GEMM math) -> bf16 output in [b][phase][pix][c] layout.
// ---------------------------------------------------------------------------
__global__ __launch_bounds__(256) void gdn_kernel(
    const float* __restrict__ x, const float* __restrict__ gamma,
    const float* __restrict__ beta, ushortT* __restrict__ ybf,
    int HW, int nPixTiles, int isSplit) {
  int dt = blockIdx.x & 1;
  int pt = (blockIdx.x >> 1) % nPixTiles;
  int b  = blockIdx.x / (2 * nPixTiles);
  int d0 = dt * 64, p0 = pt * 64;
  const float* xb = x + (size_t)b * 128 * HW;
  __shared__ float sA[64 * 68];
  __shared__ float sB[64 * 68];
  int tid = threadIdx.x;
  int rg = tid >> 4, ng = tid & 15;
  float acc[4][4];
  #pragma unroll
  for (int i = 0; i < 4; ++i)
    #pragma unroll
    for (int j = 0; j < 4; ++j) acc[i][j] = 0.f;

  for (int c0 = 0; c0 < 128; c0 += 64) {
    __syncthreads();
    for (int j = tid; j < 1024; j += 256) {
      int dd = j >> 4, k4 = j & 15;
      float4 v = *(const float4*)&gamma[(size_t)(d0 + dd) * 128 + c0 + k4 * 4];
      int kb = k4 * 4;
      sA[(kb + 0) * 68 + dd] = v.x; sA[(kb + 1) * 68 + dd] = v.y;
      sA[(kb + 2) * 68 + dd] = v.z; sA[(kb + 3) * 68 + dd] = v.w;
    }
    for (int j = tid; j < 1024; j += 256) {
      int kk = j >> 4, n4 = j & 15;
      float4 v = *(const float4*)&xb[(size_t)(c0 + kk) * HW + p0 + n4 * 4];
      v.x *= v.x; v.y *= v.y; v.z *= v.z; v.w *= v.w;
      *(float4*)&sB[kk * 68 + n4 * 4] = v;
    }
    __syncthreads();
    #pragma unroll 8
    for (int kk = 0; kk < 64; ++kk) {
      float4 a = *(const float4*)&sA[kk * 68 + rg * 4];
      float4 bb4 = *(const float4*)&sB[kk * 68 + ng * 4];
      acc[0][0] += a.x * bb4.x; acc[0][1] += a.x * bb4.y; acc[0][2] += a.x * bb4.z; acc[0][3] += a.x * bb4.w;
      acc[1][0] += a.y * bb4.x; acc[1][1] += a.y * bb4.y; acc[1][2] += a.y * bb4.z; acc[1][3] += a.y * bb4.w;
      acc[2][0] += a.z * bb4.x; acc[2][1] += a.z * bb4.y; acc[2][2] += a.z * bb4.z; acc[2][3] += a.z * bb4.w;
      acc[3][0] += a.w * bb4.x; acc[3][1] += a.w * bb4.y; acc[3][2] += a.w * bb4.z; acc[3][3] += a.w * bb4.w;
    }
  }
  float yv[4][4];
  #pragma unroll
  for (int i = 0; i < 4; ++i) {
    int d = d0 + rg * 4 + i;
    float bt = beta[d];
    float4 xv = *(const float4*)&xb[(size_t)d * HW + p0 + ng * 4];
    yv[i][0] = xv.x * rsqrtf(acc[i][0] + bt);
    yv[i][1] = xv.y * rsqrtf(acc[i][1] + bt);
    yv[i][2] = xv.z * rsqrtf(acc[i][2] + bt);
    yv[i][3] = xv.w * rsqrtf(acc[i][3] + bt);
  }
  __syncthreads();
  #pragma unroll
  for (int j = 0; j < 4; ++j) {
    float4 col = {yv[0][j], yv[1][j], yv[2][j], yv[3][j]};
    *(float4*)&sA[(ng * 4 + j) * 68 + rg * 4] = col;
  }
  __syncthreads();
  for (int idx = tid; idx < 512; idx += 256) {
    int px = idx >> 3, c8 = idx & 7;
    const float* src = &sA[px * 68 + c8 * 8];
    ushort8v uv;
    #pragma unroll
    for (int k = 0; k < 8; ++k) uv[k] = f2bf(src[k]);
    int p = p0 + px;
    size_t base;
    if (isSplit) {
      int h = p >> 5, w5 = p & 31;
      int ph = ((h & 1) << 1) | (w5 & 1);
      base = (((size_t)b * 4 + ph) * 256 + (h >> 1) * 16 + (w5 >> 1));
    } else {
      base = ((size_t)b * 256 + p);
    }
    *(ushort8v*)&ybf[base * 128 + d0 + c8 * 8] = uv;
  }
}

// ---------------------------------------------------------------------------
// bf16 MFMA implicit-GEMM conv, register-prefetched weight slabs.
// MODE 0: conv2 (4 phases, 25 taps, OC=128, out fp32 (b,m,16,16))
// MODE 1: conv3 (1 phase, 9 taps, OC=192, out fp32 (b,t,OC))
// Block: (b, mt 64-oc tile, 8-row half). Wave w owns rows r0+2w, r0+2w+1.
// ---------------------------------------------------------------------------
template<int MODE>
__global__ __launch_bounds__(256) void conv_mfma_kernel(
    const ushortT* __restrict__ X,   // [b][NPH][256][128] bf16
    const ushortT* __restrict__ Wt,  // slabs [(tap*4+cc)*NMT+mt][2048] bf16
    const float* __restrict__ bias,
    float* __restrict__ out) {
  constexpr int OC  = (MODE == 0) ? 128 : 192;
  constexpr int NMT = OC / 64;
  constexpr int NPH = (MODE == 0) ? 4 : 1;

  int b   = blockIdx.x / (NMT * 2);
  int rem = blockIdx.x % (NMT * 2);
  int mt  = rem >> 1;
  int rs  = rem & 1;
  int r0  = rs * 8;

  int wave = threadIdx.x >> 6;
  int lane = threadIdx.x & 63;
  int ln15 = lane & 15;
  int kg   = lane >> 4;

  __shared__ ushortT simg[10 * 18 * 136];   // 49 KB

  floatx4 acc[4][2];
  #pragma unroll
  for (int m = 0; m < 4; ++m) { acc[m][0] = (floatx4)0.f; acc[m][1] = (floatx4)0.f; }

  constexpr int PH_NT_2[4] = {9, 6, 6, 4};
  constexpr int TDR_2[4][9] = {{-1,-1,-1, 0, 0, 0, 1, 1, 1},
                               {-1,-1, 0, 0, 1, 1, 0, 0, 0},
                               {-1,-1,-1, 0, 0, 0, 0, 0, 0},
                               {-1,-1, 0, 0, 0, 0, 0, 0, 0}};
  constexpr int TDC_2[4][9] = {{-1, 0, 1,-1, 0, 1,-1, 0, 1},
                               {-1, 0,-1, 0,-1, 0, 0, 0, 0},
                               {-1, 0, 1,-1, 0, 1, 0, 0, 0},
                               {-1, 0,-1, 0, 0, 0, 0, 0, 0}};
  constexpr int TWI_2[4][9] = {{ 0, 2, 4,10,12,14,20,22,24},
                               { 1, 3,11,13,21,23, 0, 0, 0},
                               { 5, 7, 9,15,17,19, 0, 0, 0},
                               { 6, 8,16,18, 0, 0, 0, 0, 0}};
  constexpr int TDR_3[9] = {-1,-1,-1, 0, 0, 0, 1, 1, 1};
  constexpr int TDC_3[9] = {-1, 0, 1,-1, 0, 1,-1, 0, 1};

  int aoff = kg * 512 + ln15 * 8;   // + m*128 per m-tile

  #pragma unroll
  for (int ph = 0; ph < NPH; ++ph) {
    __syncthreads();
    const ushortT* Xb = X + (((size_t)b * NPH + ph) * 256) * 128;
    for (int idx = threadIdx.x; idx < 2880; idx += 256) {
      int chunk = idx & 15;
      int pix = idx >> 4;
      int row = pix / 18, colm = pix - row * 18;
      int i = r0 - 1 + row, j = colm - 1;
      uint4 v = {0u, 0u, 0u, 0u};
      if (i >= 0 && i < 16 && j >= 0 && j < 16)
        v = *(const uint4*)(Xb + ((size_t)(i * 16 + j)) * 128 + chunk * 8);
      *(uint4*)&simg[(row * 18 + colm) * 136 + chunk * 8] = v;
    }
    __syncthreads();

    const int NT = (MODE == 0) ? PH_NT_2[ph] : 9;
    const int NS = NT * 4;

    // prefetch stage 0
    uint4 apf[4];
    {
      int wi0 = (MODE == 0) ? TWI_2[ph][0] : 0;
      const ushortT* s0 = Wt + ((size_t)((wi0 * 4 + 0) * NMT + mt)) * 2048 + aoff;
      #pragma unroll
      for (int m = 0; m < 4; ++m) apf[m] = *(const uint4*)(s0 + m * 128);
    }

    for (int s = 0; s < NS; ++s) {
      int t  = s >> 2;
      int cc = s & 3;
      bf16x8 acur[4];
      #pragma unroll
      for (int m = 0; m < 4; ++m) acur[m] = __builtin_bit_cast(bf16x8, apf[m]);
      if (s + 1 < NS) {
        int sn = s + 1;
        int tn = sn >> 2, ccn = sn & 3;
        int win = (MODE == 0) ? TWI_2[ph][tn] : tn;
        const ushortT* sp = Wt + ((size_t)((win * 4 + ccn) * NMT + mt)) * 2048 + aoff;
        #pragma unroll
        for (int m = 0; m < 4; ++m) apf[m] = *(const uint4*)(sp + m * 128);
      }
      int dr = (MODE == 0) ? TDR_2[ph][t] : TDR_3[t];
      int dc = (MODE == 0) ? TDC_2[ph][t] : TDC_3[t];
      int c0 = cc * 32;
      #pragma unroll
      for (int rw = 0; rw < 2; ++rw) {
        int lrow = wave * 2 + rw + dr + 1;
        int lcol = ln15 + dc + 1;
        bf16x8 bfr = *(const bf16x8*)&simg[(lrow * 18 + lcol) * 136 + c0 + kg * 8];
        #pragma unroll
        for (int m = 0; m < 4; ++m)
          acc[m][rw] = __builtin_amdgcn_mfma_f32_16x16x32_bf16(acur[m], bfr, acc[m][rw], 0, 0, 0);
      }
    }
  }

  // epilogue
  #pragma unroll
  for (int m = 0; m < 4; ++m) {
    int mg = mt * 64 + m * 16 + kg * 4;
    float4 bv = *(const float4*)&bias[mg];
    #pragma unroll
    for (int rw = 0; rw < 2; ++rw) {
      int r = r0 + wave * 2 + rw;
      if (MODE == 0) {
        int p = r * 16 + ln15;
        float* op = out + ((size_t)b * 128 + mg) * 256 + p;
        op[0]   = acc[m][rw][0] + bv.x;
        op[256] = acc[m][rw][1] + bv.y;
        op[512] = acc[m][rw][2] + bv.z;
        op[768] = acc[m][rw][3] + bv.w;
      } else {
        int t = r * 16 + ln15;
        float4 o4 = {acc[m][rw][0] + bv.x, acc[m][rw][1] + bv.y,
                     acc[m][rw][2] + bv.z, acc[m][rw][3] + bv.w};
        *(float4*)&out[((size_t)b * 256 + t) * OC + mg] = o4;
      }
    }
  }
}

// ---------------------------------------------------------------------------
// bf16 MFMA GEMM: C[r][n] = sum_k A[r][k]*B[n][k] (+bias[n]); K=192.
// Tile 128 R x 64 N; wave owns 32 rows. A,B bf16 row-major stride 192.
// ---------------------------------------------------------------------------
__global__ __launch_bounds__(256) void gemm_bf16_kernel(
    const ushortT* __restrict__ A, const ushortT* __restrict__ Bm,
    const float* __restrict__ bias, float* __restrict__ C,
    int N, int nTilesN) {
  int rt = blockIdx.x / nTilesN, nt = blockIdx.x % nTilesN;
  int r0 = rt * 128, n0 = nt * 64;
  __shared__ ushortT sA[128 * 196];
  __shared__ ushortT sB[64 * 196];
  int tid = threadIdx.x;
  for (int j = tid; j < 3072; j += 256) {
    int row = j / 24, ch = j % 24;
    *(ushort8v*)&sA[row * 196 + ch * 8] = *(const ushort8v*)&A[(size_t)(r0 + row) * 192 + ch * 8];
  }
  for (int j = tid; j < 1536; j += 256) {
    int row = j / 24, ch = j % 24;
    *(ushort8v*)&sB[row * 196 + ch * 8] = *(const ushort8v*)&Bm[(size_t)(n0 + row) * 192 + ch * 8];
  }
  __syncthreads();
  int wave = tid >> 6, lane = tid & 63, ln15 = lane & 15, kg = lane >> 4;
  floatx4 acc[2][4];
  #pragma unroll
  for (int m = 0; m < 2; ++m)
    #pragma unroll
    for (int n = 0; n < 4; ++n) acc[m][n] = (floatx4)0.f;

  #pragma unroll
  for (int k0 = 0; k0 < 192; k0 += 32) {
    bf16x8 afr[2];
    #pragma unroll
    for (int m = 0; m < 2; ++m)
      afr[m] = *(const bf16x8*)&sA[(wave * 32 + m * 16 + ln15) * 196 + k0 + kg * 8];
    #pragma unroll
    for (int n = 0; n < 4; ++n) {
      bf16x8 bfr = *(const bf16x8*)&sB[(n * 16 + ln15) * 196 + k0 + kg * 8];
      acc[0][n] = __builtin_amdgcn_mfma_f32_16x16x32_bf16(afr[0], bfr, acc[0][n], 0, 0, 0);
      acc[1][n] = __builtin_amdgcn_mfma_f32_16x16x32_bf16(afr[1], bfr, acc[1][n], 0, 0, 0);
    }
  }
  #pragma unroll
  for (int n = 0; n < 4; ++n) {
    int col = n0 + n * 16 + ln15;
    float bv = bias ? bias[col] : 0.f;
    #pragma unroll
    for (int m = 0; m < 2; ++m) {
      int rowb = r0 + wave * 32 + m * 16 + kg * 4;
      #pragma unroll
      for (int r = 0; r < 4; ++r)
        C[(size_t)(rowb + r) * N + col] = acc[m][n][r] + bv;
    }
  }
}

// ---------------------------------------------------------------------------
// LayerNorm rows of 192: fp32 out + bf16 out.
// ---------------------------------------------------------------------------
__global__ __launch_bounds__(256) void ln_rows_kernel(
    const float* __restrict__ X, const float* __restrict__ w,
    const float* __restrict__ bb, float* __restrict__ Y,
    ushortT* __restrict__ Yb, int R) {
  int row = blockIdx.x * 4 + (threadIdx.x >> 6);
  int lane = threadIdx.x & 63;
  if (row >= R) return;
  const float* xr = X + (size_t)row * 192;
  float v0 = xr[lane], v1 = xr[lane + 64], v2 = xr[lane + 128];
  float s = v0 + v1 + v2;
  float s2 = v0 * v0 + v1 * v1 + v2 * v2;
  #pragma unroll
  for (int off = 32; off; off >>= 1) { s += __shfl_xor(s, off); s2 += __shfl_xor(s2, off); }
  float mean = s * (1.f / 192.f);
  float var = s2 * (1.f / 192.f) - mean * mean;
  float inv = rsqrtf(var + 1e-5f);
  float o0 = (v0 - mean) * inv * w[lane]       + bb[lane];
  float o1 = (v1 - mean) * inv * w[lane + 64]  + bb[lane + 64];
  float o2 = (v2 - mean) * inv * w[lane + 128] + bb[lane + 128];
  float* yr = Y + (size_t)row * 192;
  yr[lane] = o0; yr[lane + 64] = o1; yr[lane + 128] = o2;
  ushortT* ybr = Yb + (size_t)row * 192;
  ybr[lane] = f2bf(o0); ybr[lane + 64] = f2bf(o1); ybr[lane + 128] = f2bf(o2);
}

// ---------------------------------------------------------------------------
// kv LN: y_g (64,192,32) -> bf16 (64,32,192) with LN over 192.
// ---------------------------------------------------------------------------
__global__ __launch_bounds__(256) void ln_kv_kernel(
    const float* __restrict__ yg, const float* __restrict__ w,
    const float* __restrict__ bb, ushortT* __restrict__ Yb) {
  int row = blockIdx.x * 4 + (threadIdx.x >> 6);
  int lane = threadIdx.x & 63;
  int b = row >> 5, t = row & 31;
  const float* src = yg + (size_t)b * 6144 + t;
  float v0 = src[(size_t)lane * 32];
  float v1 = src[(size_t)(lane + 64) * 32];
  float v2 = src[(size_t)(lane + 128) * 32];
  float s = v0 + v1 + v2;
  float s2 = v0 * v0 + v1 * v1 + v2 * v2;
  #pragma unroll
  for (int off = 32; off; off >>= 1) { s += __shfl_xor(s, off); s2 += __shfl_xor(s2, off); }
  float mean = s * (1.f / 192.f);
  float var = s2 * (1.f / 192.f) - mean * mean;
  float inv = rsqrtf(var + 1e-5f);
  ushortT* yr = Yb + (size_t)row * 192;
  yr[lane]       = f2bf((v0 - mean) * inv * w[lane]       + bb[lane]);
  yr[lane + 64]  = f2bf((v1 - mean) * inv * w[lane + 64]  + bb[lane + 64]);
  yr[lane + 128] = f2bf((v2 - mean) * inv * w[lane + 128] + bb[lane + 128]);
}

// ---------------------------------------------------------------------------
// Fused Bahdanau attention; ctx out is bf16.
// ---------------------------------------------------------------------------
__global__ __launch_bounds__(256) void attn_kernel(
    const float* __restrict__ qp, const float* __restrict__ kp,
    const float* __restrict__ vp, const float* __restrict__ vw,
    ushortT* __restrict__ ctxb) {
  int b = blockIdx.x >> 4;
  int q0 = (blockIdx.x & 15) * 16;
  __shared__ float skp[32 * 132];
  __shared__ float sqp[16 * 132];
  __shared__ float svp[32 * 192];
  __shared__ float se[16][33];
  __shared__ float svw[128];
  int tid = threadIdx.x;

  const float4* kp4 = (const float4*)(kp + (size_t)b * 32 * 128);
  for (int j = tid; j < 32 * 32; j += 256) {
    int k = j >> 5, d4 = j & 31;
    float4 v = kp4[k * 32 + d4];
    int base = k * 132 + d4 * 4;
    skp[base] = v.x; skp[base + 1] = v.y; skp[base + 2] = v.z; skp[base + 3] = v.w;
  }
  const float4* qp4 = (const float4*)(qp + (size_t)(b * 256 + q0) * 128);
  for (int j = tid; j < 16 * 32; j += 256) {
    int qq = j >> 5, d4 = j & 31;
    float4 v = qp4[qq * 32 + d4];
    int base = qq * 132 + d4 * 4;
    sqp[base] = v.x; sqp[base + 1] = v.y; sqp[base + 2] = v.z; sqp[base + 3] = v.w;
  }
  const float4* vp4 = (const float4*)(vp + (size_t)b * 32 * 192);
  for (int j = tid; j < 32 * 48; j += 256) {
    int k = j / 48, m4 = j % 48;
    *(float4*)&svp[k * 192 + m4 * 4] = vp4[k * 48 + m4];
  }
  if (tid < 128) svw[tid] = vw[tid];
  __syncthreads();

  for (int idx = tid; idx < 512; idx += 256) {
    int kk = idx >> 4, qq = idx & 15;
    const float* qrow = sqp + qq * 132;
    const float* krow = skp + kk * 132;
    float e = 0.f;
    #pragma unroll 4
    for (int d = 0; d < 128; ++d) {
      float t = qrow[d] + krow[d];
      float ex = __expf(2.f * t);
      e += svw[d] * (1.f - 2.f / (ex + 1.f));
    }
    se[qq][kk] = e;
  }
  __syncthreads();
  if (tid < 16) {
    float mx = -1e30f;
    for (int k = 0; k < 32; ++k) mx = fmaxf(mx, se[tid][k]);
    float s = 0.f;
    for (int k = 0; k < 32; ++k) { float a = __expf(se[tid][k] - mx); se[tid][k] = a; s += a; }
    float invs = 1.f / s;
    for (int k = 0; k < 32; ++k) se[tid][k] *= invs;
  }
  __syncthreads();
  for (int j = tid; j < 768; j += 256) {
    int qq = j / 48, m4 = j % 48;
    const float* al = se[qq];
    float4 a = {0.f, 0.f, 0.f, 0.f};
    #pragma unroll 8
    for (int k = 0; k < 32; ++k) {
      float wk = al[k];
      float4 v = *(const float4*)&svp[k * 192 + m4 * 4];
      a.x += wk * v.x; a.y += wk * v.y; a.z += wk * v.z; a.w += wk * v.w;
    }
    ushort4 o4 = {f2bf(a.x), f2bf(a.y), f2bf(a.z), f2bf(a.w)};
    *(ushort4*)&ctxb[((size_t)(b * 256 + q0 + qq)) * 192 + m4 * 4] = o4;
  }
}

// ---------------------------------------------------------------------------
// Final LN(q_ln + ctx2) + transpose (b,t,m) -> (b,m,t)
// ---------------------------------------------------------------------------
__global__ __launch_bounds__(256) void lnout_kernel(
    const float* __restrict__ qln, const float* __restrict__ ctx2,
    const float* __restrict__ w, const float* __restrict__ bb,
    float* __restrict__ out) {
  int b = blockIdx.x >> 2;
  int t0 = (blockIdx.x & 3) * 64;
  __shared__ float sf[64 * 193];
  int wid = threadIdx.x >> 6, lane = threadIdx.x & 63;
  for (int rr = wid; rr < 64; rr += 4) {
    size_t base = ((size_t)(b * 256 + t0 + rr)) * 192;
    float v0 = qln[base + lane]       + ctx2[base + lane];
    float v1 = qln[base + lane + 64]  + ctx2[base + lane + 64];
    float v2 = qln[base + lane + 128] + ctx2[base + lane + 128];
    float s = v0 + v1 + v2;
    float s2 = v0 * v0 + v1 * v1 + v2 * v2;
    #pragma unroll
    for (int off = 32; off; off >>= 1) { s += __shfl_xor(s, off); s2 += __shfl_xor(s2, off); }
    float mean = s * (1.f / 192.f);
    float var = s2 * (1.f / 192.f) - mean * mean;
    float inv = rsqrtf(var + 1e-5f);
    sf[rr * 193 + lane]       = (v0 - mean) * inv * w[lane]       + bb[lane];
    sf[rr * 193 + lane + 64]  = (v1 - mean) * inv * w[lane + 64]  + bb[lane + 64];
    sf[rr * 193 + lane + 128] = (v2 - mean) * inv * w[lane + 128] + bb[lane + 128];
  }
  __syncthreads();
  for (int j = threadIdx.x; j < 192 * 16; j += 256) {
    int m = j >> 4, t4 = j & 15;
    float4 o4;
    o4.x = sf[(t4 * 4 + 0) * 193 + m];
    o4.y = sf[(t4 * 4 + 1) * 193 + m];
    o4.z = sf[(t4 * 4 + 2) * 193 + m];
    o4.w = sf[(t4 * 4 + 3) * 193 + m];
    *(float4*)&out[((size_t)(b * 192 + m)) * 256 + t0 + t4 * 4] = o4;
  }
}

// ---------------------------------------------------------------------------
extern "C" void kernel_launch(void* const* d_in, const int* in_sizes, int n_in,
                              void* d_out, int out_size, void* d_ws, size_t ws_size,
                              hipStream_t stream) {
  (void)in_sizes; (void)n_in; (void)out_size; (void)ws_size;
  const float* x_p     = (const float*)d_in[0];
  const float* y_g     = (const float*)d_in[1];
  const float* conv1_w = (const float*)d_in[2];
  const float* conv1_b = (const float*)d_in[3];
  const float* gamma1  = (const float*)d_in[4];
  const float* beta1   = (const float*)d_in[5];
  const float* conv2_w = (const float*)d_in[6];
  const float* conv2_b = (const float*)d_in[7];
  const float* gamma2  = (const float*)d_in[8];
  const float* beta2   = (const float*)d_in[9];
  const float* conv3_w = (const float*)d_in[10];
  const float* conv3_b = (const float*)d_in[11];
  const float* ln_q_w  = (const float*)d_in[12];
  const float* ln_q_b  = (const float*)d_in[13];
  const float* ln_kv_w = (const float*)d_in[14];
  const float* ln_kv_b = (const float*)d_in[15];
  const float* ln_out_w= (const float*)d_in[16];
  const float* ln_out_b= (const float*)d_in[17];
  const float* Wq      = (const float*)d_in[18];
  const float* Wk      = (const float*)d_in[19];
  const float* v_w     = (const float*)d_in[20];
  const float* Wv      = (const float*)d_in[21];
  const float* out_w   = (const float*)d_in[22];
  const float* out_b   = (const float*)d_in[23];
  float* out = (float*)d_out;
  float* ws  = (float*)d_ws;

  float*   t1    = ws + OFF_T1;
  ushortT* x2bf  = (ushortT*)(ws + OFF_X2BF);
  float*   t2    = ws + OFF_T2;
  ushortT* x3bf  = (ushortT*)(ws + OFF_X3BF);
  float*   qraw  = ws + OFF_QRAW;
  float*   qln   = ws + OFF_QLN;
  ushortT* qlnb  = (ushortT*)(ws + OFF_QLNB);
  ushortT* kvb   = (ushortT*)(ws + OFF_KVB);
  float*   qproj = ws + OFF_QP;
  float*   kproj = ws + OFF_KP;
  float*   vproj = ws + OFF_VP;
  ushortT* wbq   = (ushortT*)(ws + OFF_WBQ);
  ushortT* wbk   = (ushortT*)(ws + OFF_WBK);
  ushortT* wbv   = (ushortT*)(ws + OFF_WBV);
  ushortT* wbo   = (ushortT*)(ws + OFF_WBO);
  ushortT* ctxb  = (ushortT*)(ws + OFF_CTXB);
  float*   ctx2  = ws + OFF_CTX2;
  ushortT* wt2   = (ushortT*)(ws + OFF_WT2);
  ushortT* wt3   = (ushortT*)(ws + OFF_WT3);

  convw2_kernel<<<1600, 256, 0, stream>>>(conv2_w, wt2, 2, 25, 409600);
  convw2_kernel<<<864, 256, 0, stream>>>(conv3_w, wt3, 3, 9, 221184);
  wcast_kernel<<<96, 256, 0, stream>>>(Wq, wbq, 24576);
  wcast_kernel<<<96, 256, 0, stream>>>(Wk, wbk, 24576);
  wcast_kernel<<<144, 256, 0, stream>>>(Wv, wbv, 36864);
  wcast_kernel<<<144, 256, 0, stream>>>(out_w, wbo, 36864);
  conv1_kernel<<<1024, 256, 0, stream>>>(x_p, conv1_w, conv1_b, t1);
  gdn_kernel<<<2048, 256, 0, stream>>>(t1, gamma1, beta1, x2bf, 1024, 16, 1);
  conv_mfma_kernel<0><<<256, 256, 0, stream>>>(x2bf, wt2, conv2_b, t2);
  gdn_kernel<<<512, 256, 0, stream>>>(t2, gamma2, beta2, x3bf, 256, 4, 0);
  conv_mfma_kernel<1><<<384, 256, 0, stream>>>(x3bf, wt3, conv3_b, qraw);
  ln_rows_kernel<<<4096, 256, 0, stream>>>(qraw, ln_q_w, ln_q_b, qln, qlnb, 16384);
  ln_kv_kernel<<<512, 256, 0, stream>>>(y_g, ln_kv_w, ln_kv_b, kvb);
  gemm_bf16_kernel<<<256, 256, 0, stream>>>(qlnb, wbq, nullptr, qproj, 128, 2);
  gemm_bf16_kernel<<<32, 256, 0, stream>>>(kvb, wbk, nullptr, kproj, 128, 2);
  gemm_bf16_kernel<<<48, 256, 0, stream>>>(kvb, wbv, nullptr, vproj, 192, 3);
  attn_kernel<<<1024, 256, 0, stream>>>(qproj, kproj, vproj, v_w, ctxb);
  gemm_bf16_kernel<<<384, 256, 0, stream>>>(ctxb, wbo, out_b, ctx2, 192, 3);
  lnout_kernel<<<256, 256, 0, stream>>>(qln, ctx2, ln_out_w, ln_out_b, out);
}

// Round 4
// 365.356 us; speedup vs baseline: 2.0672x; 1.0199x over previous
//
#include <hip/hip_runtime.h>
#include <cstddef>
#include <cstdint>

// ---------------------------------------------------------------------------
// Shapes: x (64,3,64,64) -> conv1 5x5s2 -> (64,128,32,32) -> GDN1
//   -> conv2 5x5s2 -> (64,128,16,16) -> GDN2 -> conv3 3x3s1 -> (64,192,16,16)
//   -> LN -> Bahdanau attention (D=128, Tk=32) -> out proj -> LN -> out.
// conv2/conv3: bf16 MFMA implicit GEMM (polyphase for stride-2). Weight slabs
// are pre-repacked into per-(phase,mt) STAGE ORDER so the K-loop is a pure
// pointer-stride; depth-8 circular register prefetch hides L2 latency
// (1 wave/SIMD -> no TLP; need ~8 stages x 39cyc of ILP cover).
// ---------------------------------------------------------------------------

typedef __bf16 bf16x8 __attribute__((ext_vector_type(8)));
typedef float floatx4 __attribute__((ext_vector_type(4)));
typedef unsigned short ushortT;
typedef unsigned short ushort8v __attribute__((ext_vector_type(8)));

__device__ __forceinline__ ushortT f2bf(float f) {
  unsigned u = __builtin_bit_cast(unsigned, f);
  unsigned r = (u + 0x7FFFu + ((u >> 16) & 1u)) >> 16;
  return (ushortT)r;
}

// ---- workspace layout (float-slot offsets); peak ~56 MB ----
static constexpr size_t OFF_T1   = 0;          // conv1 out fp32 (64,128,1024)
static constexpr size_t OFF_X2BF = 8388608;    // gdn1 out bf16 [b][4][256][128]
static constexpr size_t OFF_T2   = 0;          // conv2 out fp32 (64,128,256)
static constexpr size_t OFF_X3BF = 2097152;    // gdn2 out bf16 [b][256][128]
static constexpr size_t OFF_QRAW = 3145728;    // conv3 out fp32 (64,256,192)
static constexpr size_t OFF_QLN  = 6291456;    // fp32 (64,256,192)
static constexpr size_t OFF_QLNB = 9437184;    // bf16 (64,256,192)
static constexpr size_t OFF_KVB  = 11010048;   // bf16 (64,32,192)
static constexpr size_t OFF_QP   = 11206656;   // fp32 (64,256,128)
static constexpr size_t OFF_KP   = 13303808;   // fp32 (64,32,128)
static constexpr size_t OFF_VP   = 13565952;   // fp32 (64,32,192)
static constexpr size_t OFF_WBQ  = 13959168;   // bf16 128x192
static constexpr size_t OFF_WBK  = 13971456;   // bf16 128x192
static constexpr size_t OFF_WBV  = 13983744;   // bf16 192x192
static constexpr size_t OFF_WBO  = 14002176;   // bf16 192x192
static constexpr size_t OFF_CTXB = 0;          // bf16 (64,256,192)
static constexpr size_t OFF_CTX2 = 3145728;    // fp32 (64,256,192)
static constexpr size_t OFF_WT2  = 12582912;   // bf16 conv2 slabs [200][2048]
static constexpr size_t OFF_WT3  = 12787712;   // bf16 conv3 slabs [108][2048]

// conv2 polyphase stage tables (stage s: tap index t = s>>2, cc = s&3)
__device__ __constant__ int d_TWI2[4][9] = {{ 0, 2, 4,10,12,14,20,22,24},
                                            { 1, 3,11,13,21,23, 0, 0, 0},
                                            { 5, 7, 9,15,17,19, 0, 0, 0},
                                            { 6, 8,16,18, 0, 0, 0, 0, 0}};

// ---------------------------------------------------------------------------
// conv weight repack into stage-ordered slabs.
// slab layout: [slabIdx][kg(4)][om(64)][j(8)] shorts (2048/slab)
// MODE0 (conv2): slabIdx = phStart[ph] + mt*NS[ph] + s;  oc=mt*64+om,
//   tap = TWI2[ph][s>>2], cc = s&3, c = cc*32+kg*8+j, src w[(oc*128+c)*25+tap]
// MODE1 (conv3): slabIdx = mt*36 + s; tap = s>>2; src w[(oc*128+c)*9+tap]
// ---------------------------------------------------------------------------
__global__ __launch_bounds__(256) void convw3_kernel(
    const float* __restrict__ w, ushortT* __restrict__ wt,
    int mode, int total) {
  int idx = blockIdx.x * 256 + threadIdx.x;
  if (idx >= total) return;
  int j    = idx & 7;
  int om   = (idx >> 3) & 63;
  int kg   = (idx >> 9) & 3;
  int slab = idx >> 11;
  int mt, s, tap, T;
  if (mode == 0) {
    int ph;
    if (slab < 72) ph = 0; else if (slab < 120) ph = 1;
    else if (slab < 168) ph = 2; else ph = 3;
    const int st[4] = {0, 72, 120, 168};
    const int ns[4] = {36, 24, 24, 16};
    int rel = slab - st[ph];
    mt = rel / ns[ph]; s = rel % ns[ph];
    tap = d_TWI2[ph][s >> 2]; T = 25;
  } else {
    mt = slab / 36; s = slab % 36; tap = s >> 2; T = 9;
  }
  int cc = s & 3;
  int c  = cc * 32 + kg * 8 + j;
  int oc = mt * 64 + om;
  wt[idx] = f2bf(w[(size_t)(oc * 128 + c) * T + tap]);
}

// plain fp32 -> bf16 cast
__global__ __launch_bounds__(256) void wcast_kernel(
    const float* __restrict__ w, ushortT* __restrict__ wb, int total) {
  int idx = blockIdx.x * 256 + threadIdx.x;
  if (idx < total) wb[idx] = f2bf(w[idx]);
}

// ---------------------------------------------------------------------------
// conv1: (64,3,64,64) -> (64,128,32,32), 5x5 s2 p2. (fp32)
// ---------------------------------------------------------------------------
__global__ __launch_bounds__(256) void conv1_kernel(
    const float* __restrict__ x, const float* __restrict__ w,
    const float* __restrict__ bias, float* __restrict__ out) {
  int b  = blockIdx.x >> 4;
  int og = blockIdx.x & 15;
  int o0 = og * 8;
  __shared__ float sx[3][64][72];
  __shared__ float sw[8 * 75];
  int tid = threadIdx.x;
  const float* xb = x + (size_t)b * 3 * 4096;
  for (int j = tid; j < 3 * 64 * 16; j += 256) {
    int c = j / 1024, rem = j % 1024;
    int row = rem >> 4, col4 = rem & 15;
    float4 v = *(const float4*)&xb[c * 4096 + row * 64 + col4 * 4];
    *(float4*)&sx[c][row][4 + col4 * 4] = v;
  }
  for (int j = tid; j < 3 * 64; j += 256) {
    int c = j / 64, row = j % 64;
    sx[c][row][0] = sx[c][row][1] = sx[c][row][2] = sx[c][row][3] = 0.f;
    sx[c][row][68] = sx[c][row][69] = sx[c][row][70] = sx[c][row][71] = 0.f;
  }
  for (int j = tid; j < 600; j += 256) sw[j] = w[o0 * 75 + j];
  __syncthreads();

  int oh = tid >> 3, ow0 = (tid & 7) * 4;
  float acc[8][4];
  #pragma unroll
  for (int oo = 0; oo < 8; ++oo)
    #pragma unroll
    for (int j = 0; j < 4; ++j) acc[oo][j] = 0.f;

  for (int c = 0; c < 3; ++c) {
    #pragma unroll
    for (int kh = 0; kh < 5; ++kh) {
      int ih = oh * 2 - 2 + kh;
      if (ih < 0 || ih >= 64) continue;
      float rv[16];
      *(float4*)&rv[0]  = *(const float4*)&sx[c][ih][ow0 * 2];
      *(float4*)&rv[4]  = *(const float4*)&sx[c][ih][ow0 * 2 + 4];
      *(float4*)&rv[8]  = *(const float4*)&sx[c][ih][ow0 * 2 + 8];
      *(float4*)&rv[12] = *(const float4*)&sx[c][ih][ow0 * 2 + 12];
      #pragma unroll
      for (int kw = 0; kw < 5; ++kw) {
        float wv[8];
        #pragma unroll
        for (int oo = 0; oo < 8; ++oo) wv[oo] = sw[oo * 75 + c * 25 + kh * 5 + kw];
        #pragma unroll
        for (int oo = 0; oo < 8; ++oo)
          #pragma unroll
          for (int j = 0; j < 4; ++j)
            acc[oo][j] += wv[oo] * rv[2 + kw + 2 * j];
      }
    }
  }
  #pragma unroll
  for (int oo = 0; oo < 8; ++oo) {
    float bv = bias[o0 + oo];
    float4 o4 = {acc[oo][0] + bv, acc[oo][1] + bv, acc[oo][2] + bv, acc[oo][3] + bv};
    *(float4*)&out[((size_t)(b * 128 + o0 + oo)) * 1024 + oh * 32 + ow0] = o4;
  }
}

// ---------------------------------------------------------------------------
// GDN (fp32 GEMM math) -> bf16 output in [b][phase][pix][c] layout.
// ---------------------------------------------------------------------------
__global__ __launch_bounds__(256) void gdn_kernel(
    const float* __restrict__ x, const float* __restrict__ gamma,
    const float* __restrict__ beta, ushortT* __restrict__ ybf,
    int HW, int nPixTiles, int isSplit) {
  int dt = blockIdx.x & 1;
  int pt = (blockIdx.x >> 1) % nPixTiles;
  int b  = blockIdx.x / (2 * nPixTiles);
  int d0 = dt * 64, p0 = pt * 64;
  const float* xb = x + (size_t)b * 128 * HW;
  __shared__ float sA[64 * 68];
  __shared__ float sB[64 * 68];
  int tid = threadIdx.x;
  int rg = tid >> 4, ng = tid & 15;
  float acc[4][4];
  #pragma unroll
  for (int i = 0; i < 4; ++i)
    #pragma unroll
    for (int j = 0; j < 4; ++j) acc[i][j] = 0.f;

  for (int c0 = 0; c0 < 128; c0 += 64) {
    __syncthreads();
    for (int j = tid; j < 1024; j += 256) {
      int dd = j >> 4, k4 = j & 15;
      float4 v = *(const float4*)&gamma[(size_t)(d0 + dd) * 128 + c0 + k4 * 4];
      int kb = k4 * 4;
      sA[(kb + 0) * 68 + dd] = v.x; sA[(kb + 1) * 68 + dd] = v.y;
      sA[(kb + 2) * 68 + dd] = v.z; sA[(kb + 3) * 68 + dd] = v.w;
    }
    for (int j = tid; j < 1024; j += 256) {
      int kk = j >> 4, n4 = j & 15;
      float4 v = *(const float4*)&xb[(size_t)(c0 + kk) * HW + p0 + n4 * 4];
      v.x *= v.x; v.y *= v.y; v.z *= v.z; v.w *= v.w;
      *(float4*)&sB[kk * 68 + n4 * 4] = v;
    }
    __syncthreads();
    #pragma unroll 8
    for (int kk = 0; kk < 64; ++kk) {
      float4 a = *(const float4*)&sA[kk * 68 + rg * 4];
      float4 bb4 = *(const float4*)&sB[kk * 68 + ng * 4];
      acc[0][0] += a.x * bb4.x; acc[0][1] += a.x * bb4.y; acc[0][2] += a.x * bb4.z; acc[0][3] += a.x * bb4.w;
      acc[1][0] += a.y * bb4.x; acc[1][1] += a.y * bb4.y; acc[1][2] += a.y * bb4.z; acc[1][3] += a.y * bb4.w;
      acc[2][0] += a.z * bb4.x; acc[2][1] += a.z * bb4.y; acc[2][2] += a.z * bb4.z; acc[2][3] += a.z * bb4.w;
      acc[3][0] += a.w * bb4.x; acc[3][1] += a.w * bb4.y; acc[3][2] += a.w * bb4.z; acc[3][3] += a.w * bb4.w;
    }
  }
  float yv[4][4];
  #pragma unroll
  for (int i = 0; i < 4; ++i) {
    int d = d0 + rg * 4 + i;
    float bt = beta[d];
    float4 xv = *(const float4*)&xb[(size_t)d * HW + p0 + ng * 4];
    yv[i][0] = xv.x * rsqrtf(acc[i][0] + bt);
    yv[i][1] = xv.y * rsqrtf(acc[i][1] + bt);
    yv[i][2] = xv.z * rsqrtf(acc[i][2] + bt);
    yv[i][3] = xv.w * rsqrtf(acc[i][3] + bt);
  }
  __syncthreads();
  #pragma unroll
  for (int j = 0; j < 4; ++j) {
    float4 col = {yv[0][j], yv[1][j], yv[2][j], yv[3][j]};
    *(float4*)&sA[(ng * 4 + j) * 68 + rg * 4] = col;
  }
  __syncthreads();
  for (int idx = tid; idx < 512; idx += 256) {
    int px = idx >> 3, c8 = idx & 7;
    const float* src = &sA[px * 68 + c8 * 8];
    ushort8v uv;
    #pragma unroll
    for (int k = 0; k < 8; ++k) uv[k] = f2bf(src[k]);
    int p = p0 + px;
    size_t base;
    if (isSplit) {
      int h = p >> 5, w5 = p & 31;
      int ph = ((h & 1) << 1) | (w5 & 1);
      base = (((size_t)b * 4 + ph) * 256 + (h >> 1) * 16 + (w5 >> 1));
    } else {
      base = ((size_t)b * 256 + p);
    }
    *(ushort8v*)&ybf[base * 128 + d0 + c8 * 8] = uv;
  }
}

// ---------------------------------------------------------------------------
// bf16 MFMA implicit-GEMM conv, stage-ordered slabs + depth-8 reg prefetch.
// MODE 0: conv2 (4 phases, NS={36,24,24,16}, OC=128, out fp32 (b,m,16,16))
// MODE 1: conv3 (1 phase, NS=36, OC=192, out fp32 (b,t,OC))
// Block: (b, mt 64-oc tile, 8-row half). Wave w owns rows r0+2w, r0+2w+1.
// ---------------------------------------------------------------------------
template<int MODE>
__global__ __launch_bounds__(256, 1) void conv_mfma_kernel(
    const ushortT* __restrict__ X,   // [b][NPH][256][128] bf16
    const ushortT* __restrict__ Wt,  // stage-ordered slabs [..][2048] bf16
    const float* __restrict__ bias,
    float* __restrict__ out) {
  constexpr int OC  = (MODE == 0) ? 128 : 192;
  constexpr int NMT = OC / 64;
  constexpr int NPH = (MODE == 0) ? 4 : 1;

  int b   = blockIdx.x / (NMT * 2);
  int rem = blockIdx.x % (NMT * 2);
  int mt  = rem >> 1;
  int rs  = rem & 1;
  int r0  = rs * 8;

  int wave = threadIdx.x >> 6;
  int lane = threadIdx.x & 63;
  int ln15 = lane & 15;
  int kg   = lane >> 4;

  __shared__ ushortT simg[10 * 18 * 136];   // 49 KB

  floatx4 acc[4][2];
  #pragma unroll
  for (int m = 0; m < 4; ++m) { acc[m][0] = (floatx4)0.f; acc[m][1] = (floatx4)0.f; }

  constexpr int NS2[4]      = {36, 24, 24, 16};
  constexpr int PHSTART2[4] = {0, 72, 120, 168};   // slab starts per phase
  constexpr int TDR_2[4][9] = {{-1,-1,-1, 0, 0, 0, 1, 1, 1},
                               {-1,-1, 0, 0, 1, 1, 0, 0, 0},
                               {-1,-1,-1, 0, 0, 0, 0, 0, 0},
                               {-1,-1, 0, 0, 0, 0, 0, 0, 0}};
  constexpr int TDC_2[4][9] = {{-1, 0, 1,-1, 0, 1,-1, 0, 1},
                               {-1, 0,-1, 0,-1, 0, 0, 0, 0},
                               {-1, 0, 1,-1, 0, 1, 0, 0, 0},
                               {-1, 0,-1, 0, 0, 0, 0, 0, 0}};
  constexpr int TDR_3[9] = {-1,-1,-1, 0, 0, 0, 1, 1, 1};
  constexpr int TDC_3[9] = {-1, 0, 1,-1, 0, 1,-1, 0, 1};

  const int aoff = kg * 512 + ln15 * 8;   // + m*128 per m-tile

  uint4 apf[8][4];   // depth-8 circular prefetch, 128 VGPRs

  #pragma unroll
  for (int ph = 0; ph < NPH; ++ph) {
    const int NS = (MODE == 0) ? NS2[ph] : 36;
    const int slabBase = (MODE == 0) ? (PHSTART2[ph] + mt * NS2[ph]) : (mt * 36);
    const ushortT* wp0 = Wt + (size_t)slabBase * 2048 + aoff;

    __syncthreads();
    // stage phase image: rows r0-1..r0+8, cols -1..16, all 128 ch
    const ushortT* Xb = X + (((size_t)b * NPH + ph) * 256) * 128;
    for (int idx = threadIdx.x; idx < 2880; idx += 256) {
      int chunk = idx & 15;
      int pix = idx >> 4;
      int row = pix / 18, colm = pix - row * 18;
      int i = r0 - 1 + row, j = colm - 1;
      uint4 v = {0u, 0u, 0u, 0u};
      if (i >= 0 && i < 16 && j >= 0 && j < 16)
        v = *(const uint4*)(Xb + ((size_t)(i * 16 + j)) * 128 + chunk * 8);
      *(uint4*)&simg[(row * 18 + colm) * 136 + chunk * 8] = v;
    }
    // prime depth-8 weight prefetch (independent of LDS; drains with barrier)
    #pragma unroll
    for (int jj = 0; jj < 8; ++jj)
      if (jj < NS) {
        #pragma unroll
        for (int m = 0; m < 4; ++m)
          apf[jj][m] = *(const uint4*)(wp0 + (size_t)jj * 2048 + m * 128);
      }
    __syncthreads();

    #pragma unroll
    for (int s0 = 0; s0 < NS; s0 += 8) {
      #pragma unroll
      for (int jj = 0; jj < 8; ++jj) {
        int s = s0 + jj;
        if (s < NS) {
          bf16x8 acur[4];
          #pragma unroll
          for (int m = 0; m < 4; ++m) acur[m] = __builtin_bit_cast(bf16x8, apf[jj][m]);
          int sp = s + 8;
          if (sp < NS) {
            #pragma unroll
            for (int m = 0; m < 4; ++m)
              apf[jj][m] = *(const uint4*)(wp0 + (size_t)sp * 2048 + m * 128);
          }
          int t  = s >> 2;
          int c0 = (s & 3) * 32;
          int dr = (MODE == 0) ? TDR_2[ph][t] : TDR_3[t];
          int dc = (MODE == 0) ? TDC_2[ph][t] : TDC_3[t];
          #pragma unroll
          for (int rw = 0; rw < 2; ++rw) {
            int lrow = wave * 2 + rw + dr + 1;
            int lcol = ln15 + dc + 1;
            bf16x8 bfr = *(const bf16x8*)&simg[(lrow * 18 + lcol) * 136 + c0 + kg * 8];
            #pragma unroll
            for (int m = 0; m < 4; ++m)
              acc[m][rw] = __builtin_amdgcn_mfma_f32_16x16x32_bf16(acur[m], bfr, acc[m][rw], 0, 0, 0);
          }
        }
      }
    }
  }

  // epilogue
  #pragma unroll
  for (int m = 0; m < 4; ++m) {
    int mg = mt * 64 + m * 16 + kg * 4;
    float4 bv = *(const float4*)&bias[mg];
    #pragma unroll
    for (int rw = 0; rw < 2; ++rw) {
      int r = r0 + wave * 2 + rw;
      if (MODE == 0) {
        int p = r * 16 + ln15;
        float* op = out + ((size_t)b * 128 + mg) * 256 + p;
        op[0]   = acc[m][rw][0] + bv.x;
        op[256] = acc[m][rw][1] + bv.y;
        op[512] = acc[m][rw][2] + bv.z;
        op[768] = acc[m][rw][3] + bv.w;
      } else {
        int t = r * 16 + ln15;
        float4 o4 = {acc[m][rw][0] + bv.x, acc[m][rw][1] + bv.y,
                     acc[m][rw][2] + bv.z, acc[m][rw][3] + bv.w};
        *(float4*)&out[((size_t)b * 256 + t) * OC + mg] = o4;
      }
    }
  }
}

// ---------------------------------------------------------------------------
// bf16 MFMA GEMM: C[r][n] = sum_k A[r][k]*B[n][k] (+bias[n]); K=192.
// ---------------------------------------------------------------------------
__global__ __launch_bounds__(256) void gemm_bf16_kernel(
    const ushortT* __restrict__ A, const ushortT* __restrict__ Bm,
    const float* __restrict__ bias, float* __restrict__ C,
    int N, int nTilesN) {
  int rt = blockIdx.x / nTilesN, nt = blockIdx.x % nTilesN;
  int r0 = rt * 128, n0 = nt * 64;
  __shared__ ushortT sA[128 * 196];
  __shared__ ushortT sB[64 * 196];
  int tid = threadIdx.x;
  for (int j = tid; j < 3072; j += 256) {
    int row = j / 24, ch = j % 24;
    *(ushort8v*)&sA[row * 196 + ch * 8] = *(const ushort8v*)&A[(size_t)(r0 + row) * 192 + ch * 8];
  }
  for (int j = tid; j < 1536; j += 256) {
    int row = j / 24, ch = j % 24;
    *(ushort8v*)&sB[row * 196 + ch * 8] = *(const ushort8v*)&Bm[(size_t)(n0 + row) * 192 + ch * 8];
  }
  __syncthreads();
  int wave = tid >> 6, lane = tid & 63, ln15 = lane & 15, kg = lane >> 4;
  floatx4 acc[2][4];
  #pragma unroll
  for (int m = 0; m < 2; ++m)
    #pragma unroll
    for (int n = 0; n < 4; ++n) acc[m][n] = (floatx4)0.f;

  #pragma unroll
  for (int k0 = 0; k0 < 192; k0 += 32) {
    bf16x8 afr[2];
    #pragma unroll
    for (int m = 0; m < 2; ++m)
      afr[m] = *(const bf16x8*)&sA[(wave * 32 + m * 16 + ln15) * 196 + k0 + kg * 8];
    #pragma unroll
    for (int n = 0; n < 4; ++n) {
      bf16x8 bfr = *(const bf16x8*)&sB[(n * 16 + ln15) * 196 + k0 + kg * 8];
      acc[0][n] = __builtin_amdgcn_mfma_f32_16x16x32_bf16(afr[0], bfr, acc[0][n], 0, 0, 0);
      acc[1][n] = __builtin_amdgcn_mfma_f32_16x16x32_bf16(afr[1], bfr, acc[1][n], 0, 0, 0);
    }
  }
  #pragma unroll
  for (int n = 0; n < 4; ++n) {
    int col = n0 + n * 16 + ln15;
    float bv = bias ? bias[col] : 0.f;
    #pragma unroll
    for (int m = 0; m < 2; ++m) {
      int rowb = r0 + wave * 32 + m * 16 + kg * 4;
      #pragma unroll
      for (int r = 0; r < 4; ++r)
        C[(size_t)(rowb + r) * N + col] = acc[m][n][r] + bv;
    }
  }
}

// ---------------------------------------------------------------------------
// LayerNorm rows of 192: fp32 out + bf16 out.
// ---------------------------------------------------------------------------
__global__ __launch_bounds__(256) void ln_rows_kernel(
    const float* __restrict__ X, const float* __restrict__ w,
    const float* __restrict__ bb, float* __restrict__ Y,
    ushortT* __restrict__ Yb, int R) {
  int row = blockIdx.x * 4 + (threadIdx.x >> 6);
  int lane = threadIdx.x & 63;
  if (row >= R) return;
  const float* xr = X + (size_t)row * 192;
  float v0 = xr[lane], v1 = xr[lane + 64], v2 = xr[lane + 128];
  float s = v0 + v1 + v2;
  float s2 = v0 * v0 + v1 * v1 + v2 * v2;
  #pragma unroll
  for (int off = 32; off; off >>= 1) { s += __shfl_xor(s, off); s2 += __shfl_xor(s2, off); }
  float mean = s * (1.f / 192.f);
  float var = s2 * (1.f / 192.f) - mean * mean;
  float inv = rsqrtf(var + 1e-5f);
  float o0 = (v0 - mean) * inv * w[lane]       + bb[lane];
  float o1 = (v1 - mean) * inv * w[lane + 64]  + bb[lane + 64];
  float o2 = (v2 - mean) * inv * w[lane + 128] + bb[lane + 128];
  float* yr = Y + (size_t)row * 192;
  yr[lane] = o0; yr[lane + 64] = o1; yr[lane + 128] = o2;
  ushortT* ybr = Yb + (size_t)row * 192;
  ybr[lane] = f2bf(o0); ybr[lane + 64] = f2bf(o1); ybr[lane + 128] = f2bf(o2);
}

// ---------------------------------------------------------------------------
// kv LN: y_g (64,192,32) -> bf16 (64,32,192) with LN over 192.
// ---------------------------------------------------------------------------
__global__ __launch_bounds__(256) void ln_kv_kernel(
    const float* __restrict__ yg, const float* __restrict__ w,
    const float* __restrict__ bb, ushortT* __restrict__ Yb) {
  int row = blockIdx.x * 4 + (threadIdx.x >> 6);
  int lane = threadIdx.x & 63;
  int b = row >> 5, t = row & 31;
  const float* src = yg + (size_t)b * 6144 + t;
  float v0 = src[(size_t)lane * 32];
  float v1 = src[(size_t)(lane + 64) * 32];
  float v2 = src[(size_t)(lane + 128) * 32];
  float s = v0 + v1 + v2;
  float s2 = v0 * v0 + v1 * v1 + v2 * v2;
  #pragma unroll
  for (int off = 32; off; off >>= 1) { s += __shfl_xor(s, off); s2 += __shfl_xor(s2, off); }
  float mean = s * (1.f / 192.f);
  float var = s2 * (1.f / 192.f) - mean * mean;
  float inv = rsqrtf(var + 1e-5f);
  ushortT* yr = Yb + (size_t)row * 192;
  yr[lane]       = f2bf((v0 - mean) * inv * w[lane]       + bb[lane]);
  yr[lane + 64]  = f2bf((v1 - mean) * inv * w[lane + 64]  + bb[lane + 64]);
  yr[lane + 128] = f2bf((v2 - mean) * inv * w[lane + 128] + bb[lane + 128]);
}

// ---------------------------------------------------------------------------
// Fused Bahdanau attention; ctx out is bf16.
// ---------------------------------------------------------------------------
__global__ __launch_bounds__(256) void attn_kernel(
    const float* __restrict__ qp, const float* __restrict__ kp,
    const float* __restrict__ vp, const float* __restrict__ vw,
    ushortT* __restrict__ ctxb) {
  int b = blockIdx.x >> 4;
  int q0 = (blockIdx.x & 15) * 16;
  __shared__ float skp[32 * 132];
  __shared__ float sqp[16 * 132];
  __shared__ float svp[32 * 192];
  __shared__ float se[16][33];
  __shared__ float svw[128];
  int tid = threadIdx.x;

  const float4* kp4 = (const float4*)(kp + (size_t)b * 32 * 128);
  for (int j = tid; j < 32 * 32; j += 256) {
    int k = j >> 5, d4 = j & 31;
    float4 v = kp4[k * 32 + d4];
    int base = k * 132 + d4 * 4;
    skp[base] = v.x; skp[base + 1] = v.y; skp[base + 2] = v.z; skp[base + 3] = v.w;
  }
  const float4* qp4 = (const float4*)(qp + (size_t)(b * 256 + q0) * 128);
  for (int j = tid; j < 16 * 32; j += 256) {
    int qq = j >> 5, d4 = j & 31;
    float4 v = qp4[qq * 32 + d4];
    int base = qq * 132 + d4 * 4;
    sqp[base] = v.x; sqp[base + 1] = v.y; sqp[base + 2] = v.z; sqp[base + 3] = v.w;
  }
  const float4* vp4 = (const float4*)(vp + (size_t)b * 32 * 192);
  for (int j = tid; j < 32 * 48; j += 256) {
    int k = j / 48, m4 = j % 48;
    *(float4*)&svp[k * 192 + m4 * 4] = vp4[k * 48 + m4];
  }
  if (tid < 128) svw[tid] = vw[tid];
  __syncthreads();

  for (int idx = tid; idx < 512; idx += 256) {
    int kk = idx >> 4, qq = idx & 15;
    const float* qrow = sqp + qq * 132;
    const float* krow = skp + kk * 132;
    float e = 0.f;
    #pragma unroll 4
    for (int d = 0; d < 128; ++d) {
      float t = qrow[d] + krow[d];
      float ex = __expf(2.f * t);
      e += svw[d] * (1.f - 2.f / (ex + 1.f));
    }
    se[qq][kk] = e;
  }
  __syncthreads();
  if (tid < 16) {
    float mx = -1e30f;
    for (int k = 0; k < 32; ++k) mx = fmaxf(mx, se[tid][k]);
    float s = 0.f;
    for (int k = 0; k < 32; ++k) { float a = __expf(se[tid][k] - mx); se[tid][k] = a; s += a; }
    float invs = 1.f / s;
    for (int k = 0; k < 32; ++k) se[tid][k] *= invs;
  }
  __syncthreads();
  for (int j = tid; j < 768; j += 256) {
    int qq = j / 48, m4 = j % 48;
    const float* al = se[qq];
    float4 a = {0.f, 0.f, 0.f, 0.f};
    #pragma unroll 8
    for (int k = 0; k < 32; ++k) {
      float wk = al[k];
      float4 v = *(const float4*)&svp[k * 192 + m4 * 4];
      a.x += wk * v.x; a.y += wk * v.y; a.z += wk * v.z; a.w += wk * v.w;
    }
    ushort4 o4 = {f2bf(a.x), f2bf(a.y), f2bf(a.z), f2bf(a.w)};
    *(ushort4*)&ctxb[((size_t)(b * 256 + q0 + qq)) * 192 + m4 * 4] = o4;
  }
}

// ---------------------------------------------------------------------------
// Final LN(q_ln + ctx2) + transpose (b,t,m) -> (b,m,t)
// ---------------------------------------------------------------------------
__global__ __launch_bounds__(256) void lnout_kernel(
    const float* __restrict__ qln, const float* __restrict__ ctx2,
    const float* __restrict__ w, const float* __restrict__ bb,
    float* __restrict__ out) {
  int b = blockIdx.x >> 2;
  int t0 = (blockIdx.x & 3) * 64;
  __shared__ float sf[64 * 193];
  int wid = threadIdx.x >> 6, lane = threadIdx.x & 63;
  for (int rr = wid; rr < 64; rr += 4) {
    size_t base = ((size_t)(b * 256 + t0 + rr)) * 192;
    float v0 = qln[base + lane]       + ctx2[base + lane];
    float v1 = qln[base + lane + 64]  + ctx2[base + lane + 64];
    float v2 = qln[base + lane + 128] + ctx2[base + lane + 128];
    float s = v0 + v1 + v2;
    float s2 = v0 * v0 + v1 * v1 + v2 * v2;
    #pragma unroll
    for (int off = 32; off; off >>= 1) { s += __shfl_xor(s, off); s2 += __shfl_xor(s2, off); }
    float mean = s * (1.f / 192.f);
    float var = s2 * (1.f / 192.f) - mean * mean;
    float inv = rsqrtf(var + 1e-5f);
    sf[rr * 193 + lane]       = (v0 - mean) * inv * w[lane]       + bb[lane];
    sf[rr * 193 + lane + 64]  = (v1 - mean) * inv * w[lane + 64]  + bb[lane + 64];
    sf[rr * 193 + lane + 128] = (v2 - mean) * inv * w[lane + 128] + bb[lane + 128];
  }
  __syncthreads();
  for (int j = threadIdx.x; j < 192 * 16; j += 256) {
    int m = j >> 4, t4 = j & 15;
    float4 o4;
    o4.x = sf[(t4 * 4 + 0) * 193 + m];
    o4.y = sf[(t4 * 4 + 1) * 193 + m];
    o4.z = sf[(t4 * 4 + 2) * 193 + m];
    o4.w = sf[(t4 * 4 + 3) * 193 + m];
    *(float4*)&out[((size_t)(b * 192 + m)) * 256 + t0 + t4 * 4] = o4;
  }
}

// ---------------------------------------------------------------------------
extern "C" void kernel_launch(void* const* d_in, const int* in_sizes, int n_in,
                              void* d_out, int out_size, void* d_ws, size_t ws_size,
                              hipStream_t stream) {
  (void)in_sizes; (void)n_in; (void)out_size; (void)ws_size;
  const float* x_p     = (const float*)d_in[0];
  const float* y_g     = (const float*)d_in[1];
  const float* conv1_w = (const float*)d_in[2];
  const float* conv1_b = (const float*)d_in[3];
  const float* gamma1  = (const float*)d_in[4];
  const float* beta1   = (const float*)d_in[5];
  const float* conv2_w = (const float*)d_in[6];
  const float* conv2_b = (const float*)d_in[7];
  const float* gamma2  = (const float*)d_in[8];
  const float* beta2   = (const float*)d_in[9];
  const float* conv3_w = (const float*)d_in[10];
  const float* conv3_b = (const float*)d_in[11];
  const float* ln_q_w  = (const float*)d_in[12];
  const float* ln_q_b  = (const float*)d_in[13];
  const float* ln_kv_w = (const float*)d_in[14];
  const float* ln_kv_b = (const float*)d_in[15];
  const float* ln_out_w= (const float*)d_in[16];
  const float* ln_out_b= (const float*)d_in[17];
  const float* Wq      = (const float*)d_in[18];
  const float* Wk      = (const float*)d_in[19];
  const float* v_w     = (const float*)d_in[20];
  const float* Wv      = (const float*)d_in[21];
  const float* out_w   = (const float*)d_in[22];
  const float* out_b   = (const float*)d_in[23];
  float* out = (float*)d_out;
  float* ws  = (float*)d_ws;

  float*   t1    = ws + OFF_T1;
  ushortT* x2bf  = (ushortT*)(ws + OFF_X2BF);
  float*   t2    = ws + OFF_T2;
  ushortT* x3bf  = (ushortT*)(ws + OFF_X3BF);
  float*   qraw  = ws + OFF_QRAW;
  float*   qln   = ws + OFF_QLN;
  ushortT* qlnb  = (ushortT*)(ws + OFF_QLNB);
  ushortT* kvb   = (ushortT*)(ws + OFF_KVB);
  float*   qproj = ws + OFF_QP;
  float*   kproj = ws + OFF_KP;
  float*   vproj = ws + OFF_VP;
  ushortT* wbq   = (ushortT*)(ws + OFF_WBQ);
  ushortT* wbk   = (ushortT*)(ws + OFF_WBK);
  ushortT* wbv   = (ushortT*)(ws + OFF_WBV);
  ushortT* wbo   = (ushortT*)(ws + OFF_WBO);
  ushortT* ctxb  = (ushortT*)(ws + OFF_CTXB);
  float*   ctx2  = ws + OFF_CTX2;
  ushortT* wt2   = (ushortT*)(ws + OFF_WT2);
  ushortT* wt3   = (ushortT*)(ws + OFF_WT3);

  convw3_kernel<<<1600, 256, 0, stream>>>(conv2_w, wt2, 0, 409600);
  convw3_kernel<<<864, 256, 0, stream>>>(conv3_w, wt3, 1, 221184);
  wcast_kernel<<<96, 256, 0, stream>>>(Wq, wbq, 24576);
  wcast_kernel<<<96, 256, 0, stream>>>(Wk, wbk, 24576);
  wcast_kernel<<<144, 256, 0, stream>>>(Wv, wbv, 36864);
  wcast_kernel<<<144, 256, 0, stream>>>(out_w, wbo, 36864);
  conv1_kernel<<<1024, 256, 0, stream>>>(x_p, conv1_w, conv1_b, t1);
  gdn_kernel<<<2048, 256, 0, stream>>>(t1, gamma1, beta1, x2bf, 1024, 16, 1);
  conv_mfma_kernel<0><<<256, 256, 0, stream>>>(x2bf, wt2, conv2_b, t2);
  gdn_kernel<<<512, 256, 0, stream>>>(t2, gamma2, beta2, x3bf, 256, 4, 0);
  conv_mfma_kernel<1><<<384, 256, 0, stream>>>(x3bf, wt3, conv3_b, qraw);
  ln_rows_kernel<<<4096, 256, 0, stream>>>(qraw, ln_q_w, ln_q_b, qln, qlnb, 16384);
  ln_kv_kernel<<<512, 256, 0, stream>>>(y_g, ln_kv_w, ln_kv_b, kvb);
  gemm_bf16_kernel<<<256, 256, 0, stream>>>(qlnb, wbq, nullptr, qproj, 128, 2);
  gemm_bf16_kernel<<<32, 256, 0, stream>>>(kvb, wbk, nullptr, kproj, 128, 2);
  gemm_bf16_kernel<<<48, 256, 0, stream>>>(kvb, wbv, nullptr, vproj, 192, 3);
  attn_kernel<<<1024, 256, 0, stream>>>(qproj, kproj, vproj, v_w, ctxb);
  gemm_bf16_kernel<<<384, 256, 0, stream>>>(ctxb, wbo, out_b, ctx2, 192, 3);
  lnout_kernel<<<256, 256, 0, stream>>>(qln, ctx2, ln_out_w, ln_out_b, out);
}

// Round 5
// 343.141 us; speedup vs baseline: 2.2010x; 1.0647x over previous
//
#include <hip/hip_runtime.h>
#include <cstddef>
#include <cstdint>

// ---------------------------------------------------------------------------
// Shapes: x (64,3,64,64) -> conv1 5x5s2 -> (64,128,32,32) -> GDN1
//   -> conv2 5x5s2 -> (64,128,16,16) -> GDN2 -> conv3 3x3s1 -> (64,192,16,16)
//   -> LN -> Bahdanau attention (D=128, Tk=32) -> out proj -> LN -> out.
// conv2/conv3: bf16 MFMA implicit GEMM (polyphase), stage-ordered weight
// slabs + depth-8 circular register prefetch. Attention energy: minimal
// tanh form  e = S0 + sum( -2*v_d * rcp(exp2(c*(q+k))+1) ), c=2*log2(e)
// folded into Wq/Wk at cast time; native v_exp/v_rcp.
// ---------------------------------------------------------------------------

typedef __bf16 bf16x8 __attribute__((ext_vector_type(8)));
typedef float floatx4 __attribute__((ext_vector_type(4)));
typedef unsigned short ushortT;
typedef unsigned short ushort8v __attribute__((ext_vector_type(8)));

#if __has_builtin(__builtin_amdgcn_exp2f)
#define EXP2F(x) __builtin_amdgcn_exp2f(x)
#else
#define EXP2F(x) exp2f(x)
#endif
#if __has_builtin(__builtin_amdgcn_rcpf)
#define RCPF(x) __builtin_amdgcn_rcpf(x)
#else
#define RCPF(x) (1.f / (x))
#endif

__device__ __forceinline__ ushortT f2bf(float f) {
  unsigned u = __builtin_bit_cast(unsigned, f);
  unsigned r = (u + 0x7FFFu + ((u >> 16) & 1u)) >> 16;
  return (ushortT)r;
}

// ---- workspace layout (float-slot offsets); peak ~56 MB ----
static constexpr size_t OFF_T1   = 0;          // conv1 out fp32 (64,128,1024)
static constexpr size_t OFF_X2BF = 8388608;    // gdn1 out bf16 [b][4][256][128]
static constexpr size_t OFF_T2   = 0;          // conv2 out fp32 (64,128,256)
static constexpr size_t OFF_X3BF = 2097152;    // gdn2 out bf16 [b][256][128]
static constexpr size_t OFF_QRAW = 3145728;    // conv3 out fp32 (64,256,192)
static constexpr size_t OFF_QLN  = 6291456;    // fp32 (64,256,192)
static constexpr size_t OFF_QLNB = 9437184;    // bf16 (64,256,192)
static constexpr size_t OFF_KVB  = 11010048;   // bf16 (64,32,192)
static constexpr size_t OFF_QP   = 11206656;   // fp32 (64,256,128)
static constexpr size_t OFF_KP   = 13303808;   // fp32 (64,32,128)
static constexpr size_t OFF_VP   = 13565952;   // fp32 (64,32,192)
static constexpr size_t OFF_WBQ  = 13959168;   // bf16 128x192 (scaled by c)
static constexpr size_t OFF_WBK  = 13971456;   // bf16 128x192 (scaled by c)
static constexpr size_t OFF_WBV  = 13983744;   // bf16 192x192
static constexpr size_t OFF_WBO  = 14002176;   // bf16 192x192
static constexpr size_t OFF_CTXB = 0;          // bf16 (64,256,192)
static constexpr size_t OFF_CTX2 = 3145728;    // fp32 (64,256,192)
static constexpr size_t OFF_WT2  = 12582912;   // bf16 conv2 slabs [200][2048]
static constexpr size_t OFF_WT3  = 12787712;   // bf16 conv3 slabs [108][2048]

// conv2 polyphase stage tables (stage s: tap index t = s>>2, cc = s&3)
__device__ __constant__ int d_TWI2[4][9] = {{ 0, 2, 4,10,12,14,20,22,24},
                                            { 1, 3,11,13,21,23, 0, 0, 0},
                                            { 5, 7, 9,15,17,19, 0, 0, 0},
                                            { 6, 8,16,18, 0, 0, 0, 0, 0}};

// ---------------------------------------------------------------------------
// conv weight repack into stage-ordered slabs (see round-3 notes).
// ---------------------------------------------------------------------------
__global__ __launch_bounds__(256) void convw3_kernel(
    const float* __restrict__ w, ushortT* __restrict__ wt,
    int mode, int total) {
  int idx = blockIdx.x * 256 + threadIdx.x;
  if (idx >= total) return;
  int j    = idx & 7;
  int om   = (idx >> 3) & 63;
  int kg   = (idx >> 9) & 3;
  int slab = idx >> 11;
  int mt, s, tap, T;
  if (mode == 0) {
    int ph;
    if (slab < 72) ph = 0; else if (slab < 120) ph = 1;
    else if (slab < 168) ph = 2; else ph = 3;
    const int st[4] = {0, 72, 120, 168};
    const int ns[4] = {36, 24, 24, 16};
    int rel = slab - st[ph];
    mt = rel / ns[ph]; s = rel % ns[ph];
    tap = d_TWI2[ph][s >> 2]; T = 25;
  } else {
    mt = slab / 36; s = slab % 36; tap = s >> 2; T = 9;
  }
  int cc = s & 3;
  int c  = cc * 32 + kg * 8 + j;
  int oc = mt * 64 + om;
  wt[idx] = f2bf(w[(size_t)(oc * 128 + c) * T + tap]);
}

// fp32 -> bf16 cast with scale
__global__ __launch_bounds__(256) void wcast_kernel(
    const float* __restrict__ w, ushortT* __restrict__ wb, int total,
    float scale) {
  int idx = blockIdx.x * 256 + threadIdx.x;
  if (idx < total) wb[idx] = f2bf(w[idx] * scale);
}

// ---------------------------------------------------------------------------
// conv1: (64,3,64,64) -> (64,128,32,32), 5x5 s2 p2. (fp32)
// ---------------------------------------------------------------------------
__global__ __launch_bounds__(256) void conv1_kernel(
    const float* __restrict__ x, const float* __restrict__ w,
    const float* __restrict__ bias, float* __restrict__ out) {
  int b  = blockIdx.x >> 4;
  int og = blockIdx.x & 15;
  int o0 = og * 8;
  __shared__ float sx[3][64][72];
  __shared__ float sw[8 * 75];
  int tid = threadIdx.x;
  const float* xb = x + (size_t)b * 3 * 4096;
  for (int j = tid; j < 3 * 64 * 16; j += 256) {
    int c = j / 1024, rem = j % 1024;
    int row = rem >> 4, col4 = rem & 15;
    float4 v = *(const float4*)&xb[c * 4096 + row * 64 + col4 * 4];
    *(float4*)&sx[c][row][4 + col4 * 4] = v;
  }
  for (int j = tid; j < 3 * 64; j += 256) {
    int c = j / 64, row = j % 64;
    sx[c][row][0] = sx[c][row][1] = sx[c][row][2] = sx[c][row][3] = 0.f;
    sx[c][row][68] = sx[c][row][69] = sx[c][row][70] = sx[c][row][71] = 0.f;
  }
  for (int j = tid; j < 600; j += 256) sw[j] = w[o0 * 75 + j];
  __syncthreads();

  int oh = tid >> 3, ow0 = (tid & 7) * 4;
  float acc[8][4];
  #pragma unroll
  for (int oo = 0; oo < 8; ++oo)
    #pragma unroll
    for (int j = 0; j < 4; ++j) acc[oo][j] = 0.f;

  for (int c = 0; c < 3; ++c) {
    #pragma unroll
    for (int kh = 0; kh < 5; ++kh) {
      int ih = oh * 2 - 2 + kh;
      if (ih < 0 || ih >= 64) continue;
      float rv[16];
      *(float4*)&rv[0]  = *(const float4*)&sx[c][ih][ow0 * 2];
      *(float4*)&rv[4]  = *(const float4*)&sx[c][ih][ow0 * 2 + 4];
      *(float4*)&rv[8]  = *(const float4*)&sx[c][ih][ow0 * 2 + 8];
      *(float4*)&rv[12] = *(const float4*)&sx[c][ih][ow0 * 2 + 12];
      #pragma unroll
      for (int kw = 0; kw < 5; ++kw) {
        float wv[8];
        #pragma unroll
        for (int oo = 0; oo < 8; ++oo) wv[oo] = sw[oo * 75 + c * 25 + kh * 5 + kw];
        #pragma unroll
        for (int oo = 0; oo < 8; ++oo)
          #pragma unroll
          for (int j = 0; j < 4; ++j)
            acc[oo][j] += wv[oo] * rv[2 + kw + 2 * j];
      }
    }
  }
  #pragma unroll
  for (int oo = 0; oo < 8; ++oo) {
    float bv = bias[o0 + oo];
    float4 o4 = {acc[oo][0] + bv, acc[oo][1] + bv, acc[oo][2] + bv, acc[oo][3] + bv};
    *(float4*)&out[((size_t)(b * 128 + o0 + oo)) * 1024 + oh * 32 + ow0] = o4;
  }
}

// ---------------------------------------------------------------------------
// GDN (fp32 GEMM math) -> bf16 output in [b][phase][pix][c] layout.
// ---------------------------------------------------------------------------
__global__ __launch_bounds__(256) void gdn_kernel(
    const float* __restrict__ x, const float* __restrict__ gamma,
    const float* __restrict__ beta, ushortT* __restrict__ ybf,
    int HW, int nPixTiles, int isSplit) {
  int dt = blockIdx.x & 1;
  int pt = (blockIdx.x >> 1) % nPixTiles;
  int b  = blockIdx.x / (2 * nPixTiles);
  int d0 = dt * 64, p0 = pt * 64;
  const float* xb = x + (size_t)b * 128 * HW;
  __shared__ float sA[64 * 68];
  __shared__ float sB[64 * 68];
  int tid = threadIdx.x;
  int rg = tid >> 4, ng = tid & 15;
  float acc[4][4];
  #pragma unroll
  for (int i = 0; i < 4; ++i)
    #pragma unroll
    for (int j = 0; j < 4; ++j) acc[i][j] = 0.f;

  for (int c0 = 0; c0 < 128; c0 += 64) {
    __syncthreads();
    for (int j = tid; j < 1024; j += 256) {
      int dd = j >> 4, k4 = j & 15;
      float4 v = *(const float4*)&gamma[(size_t)(d0 + dd) * 128 + c0 + k4 * 4];
      int kb = k4 * 4;
      sA[(kb + 0) * 68 + dd] = v.x; sA[(kb + 1) * 68 + dd] = v.y;
      sA[(kb + 2) * 68 + dd] = v.z; sA[(kb + 3) * 68 + dd] = v.w;
    }
    for (int j = tid; j < 1024; j += 256) {
      int kk = j >> 4, n4 = j & 15;
      float4 v = *(const float4*)&xb[(size_t)(c0 + kk) * HW + p0 + n4 * 4];
      v.x *= v.x; v.y *= v.y; v.z *= v.z; v.w *= v.w;
      *(float4*)&sB[kk * 68 + n4 * 4] = v;
    }
    __syncthreads();
    #pragma unroll 8
    for (int kk = 0; kk < 64; ++kk) {
      float4 a = *(const float4*)&sA[kk * 68 + rg * 4];
      float4 bb4 = *(const float4*)&sB[kk * 68 + ng * 4];
      acc[0][0] += a.x * bb4.x; acc[0][1] += a.x * bb4.y; acc[0][2] += a.x * bb4.z; acc[0][3] += a.x * bb4.w;
      acc[1][0] += a.y * bb4.x; acc[1][1] += a.y * bb4.y; acc[1][2] += a.y * bb4.z; acc[1][3] += a.y * bb4.w;
      acc[2][0] += a.z * bb4.x; acc[2][1] += a.z * bb4.y; acc[2][2] += a.z * bb4.z; acc[2][3] += a.z * bb4.w;
      acc[3][0] += a.w * bb4.x; acc[3][1] += a.w * bb4.y; acc[3][2] += a.w * bb4.z; acc[3][3] += a.w * bb4.w;
    }
  }
  float yv[4][4];
  #pragma unroll
  for (int i = 0; i < 4; ++i) {
    int d = d0 + rg * 4 + i;
    float bt = beta[d];
    float4 xv = *(const float4*)&xb[(size_t)d * HW + p0 + ng * 4];
    yv[i][0] = xv.x * rsqrtf(acc[i][0] + bt);
    yv[i][1] = xv.y * rsqrtf(acc[i][1] + bt);
    yv[i][2] = xv.z * rsqrtf(acc[i][2] + bt);
    yv[i][3] = xv.w * rsqrtf(acc[i][3] + bt);
  }
  __syncthreads();
  #pragma unroll
  for (int j = 0; j < 4; ++j) {
    float4 col = {yv[0][j], yv[1][j], yv[2][j], yv[3][j]};
    *(float4*)&sA[(ng * 4 + j) * 68 + rg * 4] = col;
  }
  __syncthreads();
  for (int idx = tid; idx < 512; idx += 256) {
    int px = idx >> 3, c8 = idx & 7;
    const float* src = &sA[px * 68 + c8 * 8];
    ushort8v uv;
    #pragma unroll
    for (int k = 0; k < 8; ++k) uv[k] = f2bf(src[k]);
    int p = p0 + px;
    size_t base;
    if (isSplit) {
      int h = p >> 5, w5 = p & 31;
      int ph = ((h & 1) << 1) | (w5 & 1);
      base = (((size_t)b * 4 + ph) * 256 + (h >> 1) * 16 + (w5 >> 1));
    } else {
      base = ((size_t)b * 256 + p);
    }
    *(ushort8v*)&ybf[base * 128 + d0 + c8 * 8] = uv;
  }
}

// ---------------------------------------------------------------------------
// bf16 MFMA implicit-GEMM conv, stage-ordered slabs + depth-8 reg prefetch.
// ---------------------------------------------------------------------------
template<int MODE>
__global__ __launch_bounds__(256, 1) void conv_mfma_kernel(
    const ushortT* __restrict__ X,   // [b][NPH][256][128] bf16
    const ushortT* __restrict__ Wt,  // stage-ordered slabs [..][2048] bf16
    const float* __restrict__ bias,
    float* __restrict__ out) {
  constexpr int OC  = (MODE == 0) ? 128 : 192;
  constexpr int NMT = OC / 64;
  constexpr int NPH = (MODE == 0) ? 4 : 1;

  int b   = blockIdx.x / (NMT * 2);
  int rem = blockIdx.x % (NMT * 2);
  int mt  = rem >> 1;
  int rs  = rem & 1;
  int r0  = rs * 8;

  int wave = threadIdx.x >> 6;
  int lane = threadIdx.x & 63;
  int ln15 = lane & 15;
  int kg   = lane >> 4;

  __shared__ ushortT simg[10 * 18 * 136];   // 49 KB

  floatx4 acc[4][2];
  #pragma unroll
  for (int m = 0; m < 4; ++m) { acc[m][0] = (floatx4)0.f; acc[m][1] = (floatx4)0.f; }

  constexpr int NS2[4]      = {36, 24, 24, 16};
  constexpr int PHSTART2[4] = {0, 72, 120, 168};
  constexpr int TDR_2[4][9] = {{-1,-1,-1, 0, 0, 0, 1, 1, 1},
                               {-1,-1, 0, 0, 1, 1, 0, 0, 0},
                               {-1,-1,-1, 0, 0, 0, 0, 0, 0},
                               {-1,-1, 0, 0, 0, 0, 0, 0, 0}};
  constexpr int TDC_2[4][9] = {{-1, 0, 1,-1, 0, 1,-1, 0, 1},
                               {-1, 0,-1, 0,-1, 0, 0, 0, 0},
                               {-1, 0, 1,-1, 0, 1, 0, 0, 0},
                               {-1, 0,-1, 0, 0, 0, 0, 0, 0}};
  constexpr int TDR_3[9] = {-1,-1,-1, 0, 0, 0, 1, 1, 1};
  constexpr int TDC_3[9] = {-1, 0, 1,-1, 0, 1,-1, 0, 1};

  const int aoff = kg * 512 + ln15 * 8;

  uint4 apf[8][4];

  #pragma unroll
  for (int ph = 0; ph < NPH; ++ph) {
    const int NS = (MODE == 0) ? NS2[ph] : 36;
    const int slabBase = (MODE == 0) ? (PHSTART2[ph] + mt * NS2[ph]) : (mt * 36);
    const ushortT* wp0 = Wt + (size_t)slabBase * 2048 + aoff;

    __syncthreads();
    const ushortT* Xb = X + (((size_t)b * NPH + ph) * 256) * 128;
    for (int idx = threadIdx.x; idx < 2880; idx += 256) {
      int chunk = idx & 15;
      int pix = idx >> 4;
      int row = pix / 18, colm = pix - row * 18;
      int i = r0 - 1 + row, j = colm - 1;
      uint4 v = {0u, 0u, 0u, 0u};
      if (i >= 0 && i < 16 && j >= 0 && j < 16)
        v = *(const uint4*)(Xb + ((size_t)(i * 16 + j)) * 128 + chunk * 8);
      *(uint4*)&simg[(row * 18 + colm) * 136 + chunk * 8] = v;
    }
    #pragma unroll
    for (int jj = 0; jj < 8; ++jj)
      if (jj < NS) {
        #pragma unroll
        for (int m = 0; m < 4; ++m)
          apf[jj][m] = *(const uint4*)(wp0 + (size_t)jj * 2048 + m * 128);
      }
    __syncthreads();

    #pragma unroll
    for (int s0 = 0; s0 < NS; s0 += 8) {
      #pragma unroll
      for (int jj = 0; jj < 8; ++jj) {
        int s = s0 + jj;
        if (s < NS) {
          bf16x8 acur[4];
          #pragma unroll
          for (int m = 0; m < 4; ++m) acur[m] = __builtin_bit_cast(bf16x8, apf[jj][m]);
          int sp = s + 8;
          if (sp < NS) {
            #pragma unroll
            for (int m = 0; m < 4; ++m)
              apf[jj][m] = *(const uint4*)(wp0 + (size_t)sp * 2048 + m * 128);
          }
          int t  = s >> 2;
          int c0 = (s & 3) * 32;
          int dr = (MODE == 0) ? TDR_2[ph][t] : TDR_3[t];
          int dc = (MODE == 0) ? TDC_2[ph][t] : TDC_3[t];
          #pragma unroll
          for (int rw = 0; rw < 2; ++rw) {
            int lrow = wave * 2 + rw + dr + 1;
            int lcol = ln15 + dc + 1;
            bf16x8 bfr = *(const bf16x8*)&simg[(lrow * 18 + lcol) * 136 + c0 + kg * 8];
            #pragma unroll
            for (int m = 0; m < 4; ++m)
              acc[m][rw] = __builtin_amdgcn_mfma_f32_16x16x32_bf16(acur[m], bfr, acc[m][rw], 0, 0, 0);
          }
        }
      }
    }
  }

  #pragma unroll
  for (int m = 0; m < 4; ++m) {
    int mg = mt * 64 + m * 16 + kg * 4;
    float4 bv = *(const float4*)&bias[mg];
    #pragma unroll
    for (int rw = 0; rw < 2; ++rw) {
      int r = r0 + wave * 2 + rw;
      if (MODE == 0) {
        int p = r * 16 + ln15;
        float* op = out + ((size_t)b * 128 + mg) * 256 + p;
        op[0]   = acc[m][rw][0] + bv.x;
        op[256] = acc[m][rw][1] + bv.y;
        op[512] = acc[m][rw][2] + bv.z;
        op[768] = acc[m][rw][3] + bv.w;
      } else {
        int t = r * 16 + ln15;
        float4 o4 = {acc[m][rw][0] + bv.x, acc[m][rw][1] + bv.y,
                     acc[m][rw][2] + bv.z, acc[m][rw][3] + bv.w};
        *(float4*)&out[((size_t)b * 256 + t) * OC + mg] = o4;
      }
    }
  }
}

// ---------------------------------------------------------------------------
// bf16 MFMA GEMM: C[r][n] = sum_k A[r][k]*B[n][k] (+bias[n]); K=192.
// ---------------------------------------------------------------------------
__global__ __launch_bounds__(256) void gemm_bf16_kernel(
    const ushortT* __restrict__ A, const ushortT* __restrict__ Bm,
    const float* __restrict__ bias, float* __restrict__ C,
    int N, int nTilesN) {
  int rt = blockIdx.x / nTilesN, nt = blockIdx.x % nTilesN;
  int r0 = rt * 128, n0 = nt * 64;
  __shared__ ushortT sA[128 * 196];
  __shared__ ushortT sB[64 * 196];
  int tid = threadIdx.x;
  for (int j = tid; j < 3072; j += 256) {
    int row = j / 24, ch = j % 24;
    *(ushort8v*)&sA[row * 196 + ch * 8] = *(const ushort8v*)&A[(size_t)(r0 + row) * 192 + ch * 8];
  }
  for (int j = tid; j < 1536; j += 256) {
    int row = j / 24, ch = j % 24;
    *(ushort8v*)&sB[row * 196 + ch * 8] = *(const ushort8v*)&Bm[(size_t)(n0 + row) * 192 + ch * 8];
  }
  __syncthreads();
  int wave = tid >> 6, lane = tid & 63, ln15 = lane & 15, kg = lane >> 4;
  floatx4 acc[2][4];
  #pragma unroll
  for (int m = 0; m < 2; ++m)
    #pragma unroll
    for (int n = 0; n < 4; ++n) acc[m][n] = (floatx4)0.f;

  #pragma unroll
  for (int k0 = 0; k0 < 192; k0 += 32) {
    bf16x8 afr[2];
    #pragma unroll
    for (int m = 0; m < 2; ++m)
      afr[m] = *(const bf16x8*)&sA[(wave * 32 + m * 16 + ln15) * 196 + k0 + kg * 8];
    #pragma unroll
    for (int n = 0; n < 4; ++n) {
      bf16x8 bfr = *(const bf16x8*)&sB[(n * 16 + ln15) * 196 + k0 + kg * 8];
      acc[0][n] = __builtin_amdgcn_mfma_f32_16x16x32_bf16(afr[0], bfr, acc[0][n], 0, 0, 0);
      acc[1][n] = __builtin_amdgcn_mfma_f32_16x16x32_bf16(afr[1], bfr, acc[1][n], 0, 0, 0);
    }
  }
  #pragma unroll
  for (int n = 0; n < 4; ++n) {
    int col = n0 + n * 16 + ln15;
    float bv = bias ? bias[col] : 0.f;
    #pragma unroll
    for (int m = 0; m < 2; ++m) {
      int rowb = r0 + wave * 32 + m * 16 + kg * 4;
      #pragma unroll
      for (int r = 0; r < 4; ++r)
        C[(size_t)(rowb + r) * N + col] = acc[m][n][r] + bv;
    }
  }
}

// ---------------------------------------------------------------------------
// LayerNorm rows of 192: fp32 out + bf16 out.
// ---------------------------------------------------------------------------
__global__ __launch_bounds__(256) void ln_rows_kernel(
    const float* __restrict__ X, const float* __restrict__ w,
    const float* __restrict__ bb, float* __restrict__ Y,
    ushortT* __restrict__ Yb, int R) {
  int row = blockIdx.x * 4 + (threadIdx.x >> 6);
  int lane = threadIdx.x & 63;
  if (row >= R) return;
  const float* xr = X + (size_t)row * 192;
  float v0 = xr[lane], v1 = xr[lane + 64], v2 = xr[lane + 128];
  float s = v0 + v1 + v2;
  float s2 = v0 * v0 + v1 * v1 + v2 * v2;
  #pragma unroll
  for (int off = 32; off; off >>= 1) { s += __shfl_xor(s, off); s2 += __shfl_xor(s2, off); }
  float mean = s * (1.f / 192.f);
  float var = s2 * (1.f / 192.f) - mean * mean;
  float inv = rsqrtf(var + 1e-5f);
  float o0 = (v0 - mean) * inv * w[lane]       + bb[lane];
  float o1 = (v1 - mean) * inv * w[lane + 64]  + bb[lane + 64];
  float o2 = (v2 - mean) * inv * w[lane + 128] + bb[lane + 128];
  float* yr = Y + (size_t)row * 192;
  yr[lane] = o0; yr[lane + 64] = o1; yr[lane + 128] = o2;
  ushortT* ybr = Yb + (size_t)row * 192;
  ybr[lane] = f2bf(o0); ybr[lane + 64] = f2bf(o1); ybr[lane + 128] = f2bf(o2);
}

// ---------------------------------------------------------------------------
// kv LN: y_g (64,192,32) -> bf16 (64,32,192) with LN over 192.
// ---------------------------------------------------------------------------
__global__ __launch_bounds__(256) void ln_kv_kernel(
    const float* __restrict__ yg, const float* __restrict__ w,
    const float* __restrict__ bb, ushortT* __restrict__ Yb) {
  int row = blockIdx.x * 4 + (threadIdx.x >> 6);
  int lane = threadIdx.x & 63;
  int b = row >> 5, t = row & 31;
  const float* src = yg + (size_t)b * 6144 + t;
  float v0 = src[(size_t)lane * 32];
  float v1 = src[(size_t)(lane + 64) * 32];
  float v2 = src[(size_t)(lane + 128) * 32];
  float s = v0 + v1 + v2;
  float s2 = v0 * v0 + v1 * v1 + v2 * v2;
  #pragma unroll
  for (int off = 32; off; off >>= 1) { s += __shfl_xor(s, off); s2 += __shfl_xor(s2, off); }
  float mean = s * (1.f / 192.f);
  float var = s2 * (1.f / 192.f) - mean * mean;
  float inv = rsqrtf(var + 1e-5f);
  ushortT* yr = Yb + (size_t)row * 192;
  yr[lane]       = f2bf((v0 - mean) * inv * w[lane]       + bb[lane]);
  yr[lane + 64]  = f2bf((v1 - mean) * inv * w[lane + 64]  + bb[lane + 64]);
  yr[lane + 128] = f2bf((v2 - mean) * inv * w[lane + 128] + bb[lane + 128]);
}

// ---------------------------------------------------------------------------
// Fused Bahdanau attention v2. qp/kp are PRE-SCALED by c=2*log2(e).
// e(q,k) = S0 + sum_d (-2 v_d) * rcp(exp2(qp_d + kp_d) + 1)
// ---------------------------------------------------------------------------
__global__ __launch_bounds__(256) void attn_kernel(
    const float* __restrict__ qp, const float* __restrict__ kp,
    const float* __restrict__ vp, const float* __restrict__ vw,
    ushortT* __restrict__ ctxb) {
  int b = blockIdx.x >> 4;
  int q0 = (blockIdx.x & 15) * 16;
  __shared__ float skp[32 * 132];
  __shared__ float sqp[16 * 132];
  __shared__ float svp[32 * 192];
  __shared__ float se[16][33];
  __shared__ float swm[128];
  __shared__ float sS0;
  int tid = threadIdx.x;

  const float4* kp4 = (const float4*)(kp + (size_t)b * 32 * 128);
  for (int j = tid; j < 32 * 32; j += 256) {
    int k = j >> 5, d4 = j & 31;
    float4 v = kp4[k * 32 + d4];
    *(float4*)&skp[k * 132 + d4 * 4] = v;
  }
  const float4* qp4 = (const float4*)(qp + (size_t)(b * 256 + q0) * 128);
  for (int j = tid; j < 16 * 32; j += 256) {
    int qq = j >> 5, d4 = j & 31;
    float4 v = qp4[qq * 32 + d4];
    *(float4*)&sqp[qq * 132 + d4 * 4] = v;
  }
  const float4* vp4 = (const float4*)(vp + (size_t)b * 32 * 192);
  for (int j = tid; j < 32 * 48; j += 256) {
    int k = j / 48, m4 = j % 48;
    *(float4*)&svp[k * 192 + m4 * 4] = vp4[k * 48 + m4];
  }
  if (tid < 128) swm[tid] = -2.f * vw[tid];
  if (tid < 64) {
    float s = vw[tid] + vw[tid + 64];
    #pragma unroll
    for (int off = 32; off; off >>= 1) s += __shfl_xor(s, off);
    if (tid == 0) sS0 = s;
  }
  __syncthreads();

  // energy: thread owns (qq, kc) and (qq, kc+16)
  {
    int qq = tid >> 4, kc = tid & 15;
    const float4* q4 = (const float4*)&sqp[qq * 132];
    const float4* ka = (const float4*)&skp[kc * 132];
    const float4* kb = (const float4*)&skp[(kc + 16) * 132];
    const float4* w4 = (const float4*)swm;
    float S0 = sS0;
    float acc0 = S0, acc1 = S0;
    #pragma unroll 8
    for (int dj = 0; dj < 32; ++dj) {
      float4 qv = q4[dj], k0 = ka[dj], k1 = kb[dj], wv = w4[dj];
      acc0 += wv.x * RCPF(EXP2F(qv.x + k0.x) + 1.f);
      acc0 += wv.y * RCPF(EXP2F(qv.y + k0.y) + 1.f);
      acc0 += wv.z * RCPF(EXP2F(qv.z + k0.z) + 1.f);
      acc0 += wv.w * RCPF(EXP2F(qv.w + k0.w) + 1.f);
      acc1 += wv.x * RCPF(EXP2F(qv.x + k1.x) + 1.f);
      acc1 += wv.y * RCPF(EXP2F(qv.y + k1.y) + 1.f);
      acc1 += wv.z * RCPF(EXP2F(qv.z + k1.z) + 1.f);
      acc1 += wv.w * RCPF(EXP2F(qv.w + k1.w) + 1.f);
    }
    se[qq][kc] = acc0;
    se[qq][kc + 16] = acc1;
  }
  __syncthreads();
  if (tid < 16) {
    float mx = -1e30f;
    for (int k = 0; k < 32; ++k) mx = fmaxf(mx, se[tid][k]);
    float s = 0.f;
    for (int k = 0; k < 32; ++k) { float a = __expf(se[tid][k] - mx); se[tid][k] = a; s += a; }
    float invs = 1.f / s;
    for (int k = 0; k < 32; ++k) se[tid][k] *= invs;
  }
  __syncthreads();
  for (int j = tid; j < 768; j += 256) {
    int qq = j / 48, m4 = j % 48;
    const float* al = se[qq];
    float4 a = {0.f, 0.f, 0.f, 0.f};
    #pragma unroll 8
    for (int k = 0; k < 32; ++k) {
      float wk = al[k];
      float4 v = *(const float4*)&svp[k * 192 + m4 * 4];
      a.x += wk * v.x; a.y += wk * v.y; a.z += wk * v.z; a.w += wk * v.w;
    }
    ushort4 o4 = {f2bf(a.x), f2bf(a.y), f2bf(a.z), f2bf(a.w)};
    *(ushort4*)&ctxb[((size_t)(b * 256 + q0 + qq)) * 192 + m4 * 4] = o4;
  }
}

// ---------------------------------------------------------------------------
// Final LN(q_ln + ctx2) + transpose (b,t,m) -> (b,m,t)
// ---------------------------------------------------------------------------
__global__ __launch_bounds__(256) void lnout_kernel(
    const float* __restrict__ qln, const float* __restrict__ ctx2,
    const float* __restrict__ w, const float* __restrict__ bb,
    float* __restrict__ out) {
  int b = blockIdx.x >> 2;
  int t0 = (blockIdx.x & 3) * 64;
  __shared__ float sf[64 * 193];
  int wid = threadIdx.x >> 6, lane = threadIdx.x & 63;
  for (int rr = wid; rr < 64; rr += 4) {
    size_t base = ((size_t)(b * 256 + t0 + rr)) * 192;
    float v0 = qln[base + lane]       + ctx2[base + lane];
    float v1 = qln[base + lane + 64]  + ctx2[base + lane + 64];
    float v2 = qln[base + lane + 128] + ctx2[base + lane + 128];
    float s = v0 + v1 + v2;
    float s2 = v0 * v0 + v1 * v1 + v2 * v2;
    #pragma unroll
    for (int off = 32; off; off >>= 1) { s += __shfl_xor(s, off); s2 += __shfl_xor(s2, off); }
    float mean = s * (1.f / 192.f);
    float var = s2 * (1.f / 192.f) - mean * mean;
    float inv = rsqrtf(var + 1e-5f);
    sf[rr * 193 + lane]       = (v0 - mean) * inv * w[lane]       + bb[lane];
    sf[rr * 193 + lane + 64]  = (v1 - mean) * inv * w[lane + 64]  + bb[lane + 64];
    sf[rr * 193 + lane + 128] = (v2 - mean) * inv * w[lane + 128] + bb[lane + 128];
  }
  __syncthreads();
  for (int j = threadIdx.x; j < 192 * 16; j += 256) {
    int m = j >> 4, t4 = j & 15;
    float4 o4;
    o4.x = sf[(t4 * 4 + 0) * 193 + m];
    o4.y = sf[(t4 * 4 + 1) * 193 + m];
    o4.z = sf[(t4 * 4 + 2) * 193 + m];
    o4.w = sf[(t4 * 4 + 3) * 193 + m];
    *(float4*)&out[((size_t)(b * 192 + m)) * 256 + t0 + t4 * 4] = o4;
  }
}

// ---------------------------------------------------------------------------
extern "C" void kernel_launch(void* const* d_in, const int* in_sizes, int n_in,
                              void* d_out, int out_size, void* d_ws, size_t ws_size,
                              hipStream_t stream) {
  (void)in_sizes; (void)n_in; (void)out_size; (void)ws_size;
  const float* x_p     = (const float*)d_in[0];
  const float* y_g     = (const float*)d_in[1];
  const float* conv1_w = (const float*)d_in[2];
  const float* conv1_b = (const float*)d_in[3];
  const float* gamma1  = (const float*)d_in[4];
  const float* beta1   = (const float*)d_in[5];
  const float* conv2_w = (const float*)d_in[6];
  const float* conv2_b = (const float*)d_in[7];
  const float* gamma2  = (const float*)d_in[8];
  const float* beta2   = (const float*)d_in[9];
  const float* conv3_w = (const float*)d_in[10];
  const float* conv3_b = (const float*)d_in[11];
  const float* ln_q_w  = (const float*)d_in[12];
  const float* ln_q_b  = (const float*)d_in[13];
  const float* ln_kv_w = (const float*)d_in[14];
  const float* ln_kv_b = (const float*)d_in[15];
  const float* ln_out_w= (const float*)d_in[16];
  const float* ln_out_b= (const float*)d_in[17];
  const float* Wq      = (const float*)d_in[18];
  const float* Wk      = (const float*)d_in[19];
  const float* v_w     = (const float*)d_in[20];
  const float* Wv      = (const float*)d_in[21];
  const float* out_w   = (const float*)d_in[22];
  const float* out_b   = (const float*)d_in[23];
  float* out = (float*)d_out;
  float* ws  = (float*)d_ws;

  float*   t1    = ws + OFF_T1;
  ushortT* x2bf  = (ushortT*)(ws + OFF_X2BF);
  float*   t2    = ws + OFF_T2;
  ushortT* x3bf  = (ushortT*)(ws + OFF_X3BF);
  float*   qraw  = ws + OFF_QRAW;
  float*   qln   = ws + OFF_QLN;
  ushortT* qlnb  = (ushortT*)(ws + OFF_QLNB);
  ushortT* kvb   = (ushortT*)(ws + OFF_KVB);
  float*   qproj = ws + OFF_QP;
  float*   kproj = ws + OFF_KP;
  float*   vproj = ws + OFF_VP;
  ushortT* wbq   = (ushortT*)(ws + OFF_WBQ);
  ushortT* wbk   = (ushortT*)(ws + OFF_WBK);
  ushortT* wbv   = (ushortT*)(ws + OFF_WBV);
  ushortT* wbo   = (ushortT*)(ws + OFF_WBO);
  ushortT* ctxb  = (ushortT*)(ws + OFF_CTXB);
  float*   ctx2  = ws + OFF_CTX2;
  ushortT* wt2   = (ushortT*)(ws + OFF_WT2);
  ushortT* wt3   = (ushortT*)(ws + OFF_WT3);

  constexpr float C2LE = 2.88539008177792681f;   // 2*log2(e)

  convw3_kernel<<<1600, 256, 0, stream>>>(conv2_w, wt2, 0, 409600);
  convw3_kernel<<<864, 256, 0, stream>>>(conv3_w, wt3, 1, 221184);
  wcast_kernel<<<96, 256, 0, stream>>>(Wq, wbq, 24576, C2LE);
  wcast_kernel<<<96, 256, 0, stream>>>(Wk, wbk, 24576, C2LE);
  wcast_kernel<<<144, 256, 0, stream>>>(Wv, wbv, 36864, 1.0f);
  wcast_kernel<<<144, 256, 0, stream>>>(out_w, wbo, 36864, 1.0f);
  conv1_kernel<<<1024, 256, 0, stream>>>(x_p, conv1_w, conv1_b, t1);
  gdn_kernel<<<2048, 256, 0, stream>>>(t1, gamma1, beta1, x2bf, 1024, 16, 1);
  conv_mfma_kernel<0><<<256, 256, 0, stream>>>(x2bf, wt2, conv2_b, t2);
  gdn_kernel<<<512, 256, 0, stream>>>(t2, gamma2, beta2, x3bf, 256, 4, 0);
  conv_mfma_kernel<1><<<384, 256, 0, stream>>>(x3bf, wt3, conv3_b, qraw);
  ln_rows_kernel<<<4096, 256, 0, stream>>>(qraw, ln_q_w, ln_q_b, qln, qlnb, 16384);
  ln_kv_kernel<<<512, 256, 0, stream>>>(y_g, ln_kv_w, ln_kv_b, kvb);
  gemm_bf16_kernel<<<256, 256, 0, stream>>>(qlnb, wbq, nullptr, qproj, 128, 2);
  gemm_bf16_kernel<<<32, 256, 0, stream>>>(kvb, wbk, nullptr, kproj, 128, 2);
  gemm_bf16_kernel<<<48, 256, 0, stream>>>(kvb, wbv, nullptr, vproj, 192, 3);
  attn_kernel<<<1024, 256, 0, stream>>>(qproj, kproj, vproj, v_w, ctxb);
  gemm_bf16_kernel<<<384, 256, 0, stream>>>(ctxb, wbo, out_b, ctx2, 192, 3);
  lnout_kernel<<<256, 256, 0, stream>>>(qln, ctx2, ln_out_w, ln_out_b, out);
}

// Round 6
// 298.953 us; speedup vs baseline: 2.5264x; 1.1478x over previous
//
#include <hip/hip_runtime.h>
#include <cstddef>
#include <cstdint>

// ---------------------------------------------------------------------------
// Pipeline: x (64,3,64,64) -> conv1 5x5s2 (MFMA polyphase) -> GDN1 (MFMA)
//   -> conv2 5x5s2 (MFMA polyphase) -> GDN2 (MFMA) -> conv3 3x3 (MFMA)
//   -> LN -> Bahdanau attention -> out proj (MFMA) -> LN -> out.
// All heavy math on bf16 MFMA; intermediate activations bf16 (b,px,c).
// ---------------------------------------------------------------------------

typedef __bf16 bf16x8 __attribute__((ext_vector_type(8)));
typedef float floatx4 __attribute__((ext_vector_type(4)));
typedef unsigned short ushortT;
typedef unsigned short ushort8v __attribute__((ext_vector_type(8)));

#if __has_builtin(__builtin_amdgcn_exp2f)
#define EXP2F(x) __builtin_amdgcn_exp2f(x)
#else
#define EXP2F(x) exp2f(x)
#endif
#if __has_builtin(__builtin_amdgcn_rcpf)
#define RCPF(x) __builtin_amdgcn_rcpf(x)
#else
#define RCPF(x) (1.f / (x))
#endif

__device__ __forceinline__ ushortT f2bf(float f) {
  unsigned u = __builtin_bit_cast(unsigned, f);
  unsigned r = (u + 0x7FFFu + ((u >> 16) & 1u)) >> 16;
  return (ushortT)r;
}
__device__ __forceinline__ float bf2f(ushortT u) {
  return __builtin_bit_cast(float, ((unsigned)u) << 16);
}

// ---- workspace layout (float-slot offsets); ws >= 256 MB so no overlap ----
static constexpr size_t OFF_T1BF = 0;          // conv1 out bf16 (64,1024,128)
static constexpr size_t OFF_X2BF = 4194304;    // gdn1 out bf16 [b][4][256][128]
static constexpr size_t OFF_T2BF = 8388608;    // conv2 out bf16 (64,256,128)
static constexpr size_t OFF_X3BF = 9437184;    // gdn2 out bf16 (64,256,128)
static constexpr size_t OFF_QRAW = 10485760;   // conv3 out fp32 (64,256,192)
static constexpr size_t OFF_QLN  = 13631488;   // fp32 (64,256,192)
static constexpr size_t OFF_QLNB = 16777216;   // bf16 (64,256,192)
static constexpr size_t OFF_KVB  = 18350080;   // bf16 (64,32,192)
static constexpr size_t OFF_QP   = 18546688;   // fp32 (64,256,128)
static constexpr size_t OFF_KP   = 20643840;   // fp32 (64,32,128)
static constexpr size_t OFF_VP   = 20905984;   // fp32 (64,32,192)
static constexpr size_t OFF_WBQ  = 21299200;   // bf16 128x192 (scaled by c)
static constexpr size_t OFF_WBK  = 21311488;   // bf16 128x192 (scaled by c)
static constexpr size_t OFF_WBV  = 21323776;   // bf16 192x192
static constexpr size_t OFF_WBO  = 21342208;   // bf16 192x192
static constexpr size_t OFF_CTXB = 21360640;   // bf16 (64,256,192)
static constexpr size_t OFF_CTX2 = 22933504;   // fp32 (64,256,192)
static constexpr size_t OFF_WT2  = 26079232;   // bf16 conv2 slabs [200][2048]
static constexpr size_t OFF_WT3  = 26284032;   // bf16 conv3 slabs [108][2048]
static constexpr size_t OFF_WC1  = 26394624;   // bf16 conv1 slabs [5][128][32]
static constexpr size_t OFF_GB1  = 26406912;   // bf16 gamma1 128x128
static constexpr size_t OFF_GB2  = 26415104;   // bf16 gamma2 128x128

// 5x5 s2 p2 polyphase tap tables (tap id = kh*5+kw); verified via conv2.
__device__ __constant__ int d_TWI2[4][9] = {{ 0, 2, 4,10,12,14,20,22,24},
                                            { 1, 3,11,13,21,23, 0, 0, 0},
                                            { 5, 7, 9,15,17,19, 0, 0, 0},
                                            { 6, 8,16,18, 0, 0, 0, 0, 0}};
__device__ __constant__ int d_NT2[4] = {9, 6, 6, 4};

// ---------------------------------------------------------------------------
// conv2/conv3 weight repack into stage-ordered slabs (unchanged from r3).
// ---------------------------------------------------------------------------
__global__ __launch_bounds__(256) void convw3_kernel(
    const float* __restrict__ w, ushortT* __restrict__ wt,
    int mode, int total) {
  int idx = blockIdx.x * 256 + threadIdx.x;
  if (idx >= total) return;
  int j    = idx & 7;
  int om   = (idx >> 3) & 63;
  int kg   = (idx >> 9) & 3;
  int slab = idx >> 11;
  int mt, s, tap, T;
  if (mode == 0) {
    int ph;
    if (slab < 72) ph = 0; else if (slab < 120) ph = 1;
    else if (slab < 168) ph = 2; else ph = 3;
    const int st[4] = {0, 72, 120, 168};
    const int ns[4] = {36, 24, 24, 16};
    int rel = slab - st[ph];
    mt = rel / ns[ph]; s = rel % ns[ph];
    tap = d_TWI2[ph][s >> 2]; T = 25;
  } else {
    mt = slab / 36; s = slab % 36; tap = s >> 2; T = 9;
  }
  int cc = s & 3;
  int c  = cc * 32 + kg * 8 + j;
  int oc = mt * 64 + om;
  wt[idx] = f2bf(w[(size_t)(oc * 128 + c) * T + tap]);
}

// ---------------------------------------------------------------------------
// conv1 weight pack: 5 K-slabs; slab s covers (ph, i): {ph0:i0, ph0:i1,
// ph1, ph2, ph3}. slot k = kg*8 + j -> channel c = kg (<3), tap idx = i*8+j.
// layout wt[slab][oc(128)][k(32)] bf16, zero-padded.
// ---------------------------------------------------------------------------
__global__ __launch_bounds__(256) void convw1_kernel(
    const float* __restrict__ w, ushortT* __restrict__ wt) {
  int idx = blockIdx.x * 256 + threadIdx.x;
  if (idx >= 20480) return;
  int k    = idx & 31;
  int oc   = (idx >> 5) & 127;
  int slab = idx >> 12;
  int ph, i;
  if (slab < 2) { ph = 0; i = slab; } else { ph = slab - 1; i = 0; }
  int kg = k >> 3, jj = k & 7;
  int tidx = i * 8 + jj;
  float val = 0.f;
  if (kg < 3 && tidx < d_NT2[ph]) {
    int tap = d_TWI2[ph][tidx];
    val = w[(size_t)(oc * 3 + kg) * 25 + tap];
  }
  wt[idx] = f2bf(val);
}

// fp32 -> bf16 cast with scale
__global__ __launch_bounds__(256) void wcast_kernel(
    const float* __restrict__ w, ushortT* __restrict__ wb, int total,
    float scale) {
  int idx = blockIdx.x * 256 + threadIdx.x;
  if (idx < total) wb[idx] = f2bf(w[idx] * scale);
}

// ---------------------------------------------------------------------------
// conv1 MFMA polyphase: (64,3,64,64) fp32 -> (64,1024px,128c) bf16.
// Block: (b, 8-output-row group). LDS: phase images [ph][c][10][36] bf16
// (+c=3 garbage pad) and weights [5][128][40] bf16.
// B-frag build: base + kg*360 (runtime) + const tap offset (immediate).
// ---------------------------------------------------------------------------
__global__ __launch_bounds__(256, 1) void conv1_mfma_kernel(
    const float* __restrict__ x, const ushortT* __restrict__ wc1,
    const float* __restrict__ bias, ushortT* __restrict__ outb) {
  int b  = blockIdx.x >> 2;
  int yg = blockIdx.x & 3;
  int y0 = yg * 8;

  int wave = threadIdx.x >> 6;
  int lane = threadIdx.x & 63;
  int ln15 = lane & 15;
  int kg   = lane >> 4;
  int tid  = threadIdx.x;

  __shared__ ushortT simg[4680];         // [ph][c][lr(10)][col(36)] + pad
  __shared__ ushortT sA[5 * 128 * 40];   // [slab][oc][40]

  // zero image
  for (int j = tid; j < 2340; j += 256) ((unsigned*)simg)[j] = 0u;
  __syncthreads();

  // stage phase images: input rows ih in [2*y0-2, 2*y0+17]
  int ihBase = 2 * y0 - 2;
  const float* xb = x + (size_t)b * 3 * 4096;
  for (int j = tid; j < 960; j += 256) {
    int q = j & 15;            // col quad (iw = 4q..4q+3)
    int rr = j >> 4;
    int c = rr / 20, ihl = rr % 20;
    int ih = ihBase + ihl;
    if (ih >= 0 && ih < 64) {
      float4 v = *(const float4*)&xb[c * 4096 + ih * 64 + q * 4];
      int pr = ih & 1, u = ih >> 1;
      int lr = u - y0 + 1;     // 0..9
      int base0 = ((pr * 2 + 0) * 3 + c) * 360 + lr * 36;
      int base1 = ((pr * 2 + 1) * 3 + c) * 360 + lr * 36;
      simg[base0 + 2 * q + 1] = f2bf(v.x);   // iw=4q   -> pc0, v=2q
      simg[base1 + 2 * q + 1] = f2bf(v.y);   // iw=4q+1 -> pc1, v=2q
      simg[base0 + 2 * q + 2] = f2bf(v.z);   // iw=4q+2 -> pc0, v=2q+1
      simg[base1 + 2 * q + 2] = f2bf(v.w);   // iw=4q+3 -> pc1, v=2q+1
    }
  }
  // stage weights [slab][oc][32] -> [slab][oc][40]
  for (int j = tid; j < 2560; j += 256) {
    int chunk = j & 3, row = j >> 2;     // row = slab*128+oc, 0..639
    uint4 v = *(const uint4*)&wc1[row * 32 + chunk * 8];
    *(uint4*)&sA[row * 40 + chunk * 8] = v;
  }
  __syncthreads();

  constexpr int TDR[4][9] = {{-1,-1,-1, 0, 0, 0, 1, 1, 1},
                             {-1,-1, 0, 0, 1, 1, 0, 0, 0},
                             {-1,-1,-1, 0, 0, 0, 0, 0, 0},
                             {-1,-1, 0, 0, 0, 0, 0, 0, 0}};
  constexpr int TDC[4][9] = {{-1, 0, 1,-1, 0, 1,-1, 0, 1},
                             {-1, 0,-1, 0,-1, 0, 0, 0, 0},
                             {-1, 0, 1,-1, 0, 1, 0, 0, 0},
                             {-1, 0,-1, 0, 0, 0, 0, 0, 0}};
  constexpr int NT[4]  = {9, 6, 6, 4};
  constexpr int NM[4]  = {2, 1, 1, 1};
  constexpr int SB[4]  = {0, 2, 3, 4};

  // build B-frags for this wave's 4 n-tiles x 5 slabs
  ushort8v Bf[4][5];
  #pragma unroll
  for (int ntl = 0; ntl < 4; ++ntl) {
    int ntg = wave * 4 + ntl;
    int yloc = ntg >> 1;
    int xx = (ntg & 1) * 16 + ln15;
    int lbase = (yloc + 1) * 36 + xx + 1 + kg * 360;
    #pragma unroll
    for (int ph = 0; ph < 4; ++ph) {
      int pbase = ph * 1080 + lbase;
      #pragma unroll
      for (int i = 0; i < 2; ++i) {
        if (i < NM[ph]) {
          ushort8v bv;
          #pragma unroll
          for (int j = 0; j < 8; ++j) {
            int tidx = i * 8 + j;
            if (tidx >= NT[ph]) tidx = 0;   // A is zero there
            int off = TDR[ph][tidx] * 36 + TDC[ph][tidx];
            bv[j] = simg[pbase + off];
          }
          Bf[ntl][SB[ph] + i] = bv;
        }
      }
    }
  }

  // MFMA + epilogue
  #pragma unroll
  for (int m = 0; m < 8; ++m) {
    bf16x8 Af[5];
    #pragma unroll
    for (int s = 0; s < 5; ++s)
      Af[s] = *(const bf16x8*)&sA[(s * 128 + m * 16 + ln15) * 40 + kg * 8];
    int oc0 = m * 16 + kg * 4;
    float4 bv = *(const float4*)&bias[oc0];
    #pragma unroll
    for (int ntl = 0; ntl < 4; ++ntl) {
      floatx4 acc = (floatx4)0.f;
      #pragma unroll
      for (int s = 0; s < 5; ++s)
        acc = __builtin_amdgcn_mfma_f32_16x16x32_bf16(
            Af[s], __builtin_bit_cast(bf16x8, Bf[ntl][s]), acc, 0, 0, 0);
      int ntg = wave * 4 + ntl;
      int y = y0 + (ntg >> 1);
      int xx = (ntg & 1) * 16 + ln15;
      int p = y * 32 + xx;
      ushort4 o4 = {f2bf(acc[0] + bv.x), f2bf(acc[1] + bv.y),
                    f2bf(acc[2] + bv.z), f2bf(acc[3] + bv.w)};
      *(ushort4*)&outb[((size_t)b * 1024 + p) * 128 + oc0] = o4;
    }
  }
}

// ---------------------------------------------------------------------------
// GDN as bf16 MFMA GEMM: norm[px][d] = gamma[d][:] . xsq[px][:], K=128.
// y[px][d] = x * rsqrt(norm + beta[d]); output bf16, optional phase-split.
// Block: (b, 64-px tile). M=128 d, N=64 px.
// ---------------------------------------------------------------------------
__global__ __launch_bounds__(256) void gdn_mfma_kernel(
    const ushortT* __restrict__ xbf, const ushortT* __restrict__ gb,
    const float* __restrict__ beta, ushortT* __restrict__ ybf,
    int HW, int nPixTiles, int isSplit) {
  int pt = blockIdx.x % nPixTiles;
  int b  = blockIdx.x / nPixTiles;
  int px0 = pt * 64;
  int tid = threadIdx.x;
  int wave = tid >> 6, lane = tid & 63, ln15 = lane & 15, kg = lane >> 4;

  __shared__ ushortT sG[128 * 136];
  __shared__ ushortT sX[64 * 136];

  for (int j = tid; j < 2048; j += 256) {
    int row = j >> 4, ch = j & 15;
    *(uint4*)&sG[row * 136 + ch * 8] = *(const uint4*)&gb[row * 128 + ch * 8];
  }
  for (int j = tid; j < 1024; j += 256) {
    int row = j >> 4, ch = j & 15;
    ushort8v xv = *(const ushort8v*)&xbf[((size_t)(b * HW + px0 + row)) * 128 + ch * 8];
    ushort8v sq;
    #pragma unroll
    for (int r = 0; r < 8; ++r) {
      float f = bf2f(xv[r]);
      sq[r] = f2bf(f * f);
    }
    *(ushort8v*)&sX[row * 136 + ch * 8] = sq;
  }
  __syncthreads();

  floatx4 acc[2][4];
  #pragma unroll
  for (int mi = 0; mi < 2; ++mi)
    #pragma unroll
    for (int nt = 0; nt < 4; ++nt) acc[mi][nt] = (floatx4)0.f;

  #pragma unroll
  for (int k0 = 0; k0 < 128; k0 += 32) {
    bf16x8 a0 = *(const bf16x8*)&sG[(wave * 32 + ln15) * 136 + k0 + kg * 8];
    bf16x8 a1 = *(const bf16x8*)&sG[(wave * 32 + 16 + ln15) * 136 + k0 + kg * 8];
    #pragma unroll
    for (int nt = 0; nt < 4; ++nt) {
      bf16x8 bb = *(const bf16x8*)&sX[(nt * 16 + ln15) * 136 + k0 + kg * 8];
      acc[0][nt] = __builtin_amdgcn_mfma_f32_16x16x32_bf16(a0, bb, acc[0][nt], 0, 0, 0);
      acc[1][nt] = __builtin_amdgcn_mfma_f32_16x16x32_bf16(a1, bb, acc[1][nt], 0, 0, 0);
    }
  }

  #pragma unroll
  for (int mi = 0; mi < 2; ++mi) {
    int d0 = wave * 32 + mi * 16 + kg * 4;
    float4 bt = *(const float4*)&beta[d0];
    #pragma unroll
    for (int nt = 0; nt < 4; ++nt) {
      int p = px0 + nt * 16 + ln15;
      ushort4 x4 = *(const ushort4*)&xbf[((size_t)(b * HW + p)) * 128 + d0];
      ushort4 o4;
      o4.x = f2bf(bf2f(x4.x) * rsqrtf(acc[mi][nt][0] + bt.x));
      o4.y = f2bf(bf2f(x4.y) * rsqrtf(acc[mi][nt][1] + bt.y));
      o4.z = f2bf(bf2f(x4.z) * rsqrtf(acc[mi][nt][2] + bt.z));
      o4.w = f2bf(bf2f(x4.w) * rsqrtf(acc[mi][nt][3] + bt.w));
      size_t dst;
      if (isSplit) {
        int h = p >> 5, w5 = p & 31;
        int ph = ((h & 1) << 1) | (w5 & 1);
        dst = (((size_t)b * 4 + ph) * 256 + (h >> 1) * 16 + (w5 >> 1)) * 128 + d0;
      } else {
        dst = ((size_t)b * 256 + p) * 128 + d0;
      }
      *(ushort4*)&ybf[dst] = o4;
    }
  }
}

// ---------------------------------------------------------------------------
// conv2/conv3 MFMA implicit GEMM (stage-ordered slabs + depth-8 prefetch).
// MODE0: conv2, out bf16 (b,256px,128c). MODE1: conv3, out fp32 (b,t,192).
// ---------------------------------------------------------------------------
template<int MODE>
__global__ __launch_bounds__(256, 1) void conv_mfma_kernel(
    const ushortT* __restrict__ X,
    const ushortT* __restrict__ Wt,
    const float* __restrict__ bias,
    ushortT* __restrict__ outb, float* __restrict__ outf) {
  constexpr int OC  = (MODE == 0) ? 128 : 192;
  constexpr int NMT = OC / 64;
  constexpr int NPH = (MODE == 0) ? 4 : 1;

  int b   = blockIdx.x / (NMT * 2);
  int rem = blockIdx.x % (NMT * 2);
  int mt  = rem >> 1;
  int rs  = rem & 1;
  int r0  = rs * 8;

  int wave = threadIdx.x >> 6;
  int lane = threadIdx.x & 63;
  int ln15 = lane & 15;
  int kg   = lane >> 4;

  __shared__ ushortT simg[10 * 18 * 136];

  floatx4 acc[4][2];
  #pragma unroll
  for (int m = 0; m < 4; ++m) { acc[m][0] = (floatx4)0.f; acc[m][1] = (floatx4)0.f; }

  constexpr int NS2[4]      = {36, 24, 24, 16};
  constexpr int PHSTART2[4] = {0, 72, 120, 168};
  constexpr int TDR_2[4][9] = {{-1,-1,-1, 0, 0, 0, 1, 1, 1},
                               {-1,-1, 0, 0, 1, 1, 0, 0, 0},
                               {-1,-1,-1, 0, 0, 0, 0, 0, 0},
                               {-1,-1, 0, 0, 0, 0, 0, 0, 0}};
  constexpr int TDC_2[4][9] = {{-1, 0, 1,-1, 0, 1,-1, 0, 1},
                               {-1, 0,-1, 0,-1, 0, 0, 0, 0},
                               {-1, 0, 1,-1, 0, 1, 0, 0, 0},
                               {-1, 0,-1, 0, 0, 0, 0, 0, 0}};
  constexpr int TDR_3[9] = {-1,-1,-1, 0, 0, 0, 1, 1, 1};
  constexpr int TDC_3[9] = {-1, 0, 1,-1, 0, 1,-1, 0, 1};

  const int aoff = kg * 512 + ln15 * 8;
  uint4 apf[8][4];

  #pragma unroll
  for (int ph = 0; ph < NPH; ++ph) {
    const int NS = (MODE == 0) ? NS2[ph] : 36;
    const int slabBase = (MODE == 0) ? (PHSTART2[ph] + mt * NS2[ph]) : (mt * 36);
    const ushortT* wp0 = Wt + (size_t)slabBase * 2048 + aoff;

    __syncthreads();
    const ushortT* Xb = X + (((size_t)b * NPH + ph) * 256) * 128;
    for (int idx = threadIdx.x; idx < 2880; idx += 256) {
      int chunk = idx & 15;
      int pix = idx >> 4;
      int row = pix / 18, colm = pix - row * 18;
      int i = r0 - 1 + row, j = colm - 1;
      uint4 v = {0u, 0u, 0u, 0u};
      if (i >= 0 && i < 16 && j >= 0 && j < 16)
        v = *(const uint4*)(Xb + ((size_t)(i * 16 + j)) * 128 + chunk * 8);
      *(uint4*)&simg[(row * 18 + colm) * 136 + chunk * 8] = v;
    }
    #pragma unroll
    for (int jj = 0; jj < 8; ++jj)
      if (jj < NS) {
        #pragma unroll
        for (int m = 0; m < 4; ++m)
          apf[jj][m] = *(const uint4*)(wp0 + (size_t)jj * 2048 + m * 128);
      }
    __syncthreads();

    #pragma unroll
    for (int s0 = 0; s0 < NS; s0 += 8) {
      #pragma unroll
      for (int jj = 0; jj < 8; ++jj) {
        int s = s0 + jj;
        if (s < NS) {
          bf16x8 acur[4];
          #pragma unroll
          for (int m = 0; m < 4; ++m) acur[m] = __builtin_bit_cast(bf16x8, apf[jj][m]);
          int sp = s + 8;
          if (sp < NS) {
            #pragma unroll
            for (int m = 0; m < 4; ++m)
              apf[jj][m] = *(const uint4*)(wp0 + (size_t)sp * 2048 + m * 128);
          }
          int t  = s >> 2;
          int c0 = (s & 3) * 32;
          int dr = (MODE == 0) ? TDR_2[ph][t] : TDR_3[t];
          int dc = (MODE == 0) ? TDC_2[ph][t] : TDC_3[t];
          #pragma unroll
          for (int rw = 0; rw < 2; ++rw) {
            int lrow = wave * 2 + rw + dr + 1;
            int lcol = ln15 + dc + 1;
            bf16x8 bfr = *(const bf16x8*)&simg[(lrow * 18 + lcol) * 136 + c0 + kg * 8];
            #pragma unroll
            for (int m = 0; m < 4; ++m)
              acc[m][rw] = __builtin_amdgcn_mfma_f32_16x16x32_bf16(acur[m], bfr, acc[m][rw], 0, 0, 0);
          }
        }
      }
    }
  }

  #pragma unroll
  for (int m = 0; m < 4; ++m) {
    int mg = mt * 64 + m * 16 + kg * 4;
    float4 bv = *(const float4*)&bias[mg];
    #pragma unroll
    for (int rw = 0; rw < 2; ++rw) {
      int r = r0 + wave * 2 + rw;
      int p = r * 16 + ln15;
      if (MODE == 0) {
        ushort4 o4 = {f2bf(acc[m][rw][0] + bv.x), f2bf(acc[m][rw][1] + bv.y),
                      f2bf(acc[m][rw][2] + bv.z), f2bf(acc[m][rw][3] + bv.w)};
        *(ushort4*)&outb[((size_t)b * 256 + p) * 128 + mg] = o4;
      } else {
        float4 o4 = {acc[m][rw][0] + bv.x, acc[m][rw][1] + bv.y,
                     acc[m][rw][2] + bv.z, acc[m][rw][3] + bv.w};
        *(float4*)&outf[((size_t)b * 256 + p) * OC + mg] = o4;
      }
    }
  }
}

// ---------------------------------------------------------------------------
// bf16 MFMA GEMM: C[r][n] = sum_k A[r][k]*B[n][k] (+bias[n]); K=192.
// ---------------------------------------------------------------------------
__global__ __launch_bounds__(256) void gemm_bf16_kernel(
    const ushortT* __restrict__ A, const ushortT* __restrict__ Bm,
    const float* __restrict__ bias, float* __restrict__ C,
    int N, int nTilesN) {
  int rt = blockIdx.x / nTilesN, nt = blockIdx.x % nTilesN;
  int r0 = rt * 128, n0 = nt * 64;
  __shared__ ushortT sA[128 * 196];
  __shared__ ushortT sB[64 * 196];
  int tid = threadIdx.x;
  for (int j = tid; j < 3072; j += 256) {
    int row = j / 24, ch = j % 24;
    *(ushort8v*)&sA[row * 196 + ch * 8] = *(const ushort8v*)&A[(size_t)(r0 + row) * 192 + ch * 8];
  }
  for (int j = tid; j < 1536; j += 256) {
    int row = j / 24, ch = j % 24;
    *(ushort8v*)&sB[row * 196 + ch * 8] = *(const ushort8v*)&Bm[(size_t)(n0 + row) * 192 + ch * 8];
  }
  __syncthreads();
  int wave = tid >> 6, lane = tid & 63, ln15 = lane & 15, kg = lane >> 4;
  floatx4 acc[2][4];
  #pragma unroll
  for (int m = 0; m < 2; ++m)
    #pragma unroll
    for (int n = 0; n < 4; ++n) acc[m][n] = (floatx4)0.f;

  #pragma unroll
  for (int k0 = 0; k0 < 192; k0 += 32) {
    bf16x8 afr[2];
    #pragma unroll
    for (int m = 0; m < 2; ++m)
      afr[m] = *(const bf16x8*)&sA[(wave * 32 + m * 16 + ln15) * 196 + k0 + kg * 8];
    #pragma unroll
    for (int n = 0; n < 4; ++n) {
      bf16x8 bfr = *(const bf16x8*)&sB[(n * 16 + ln15) * 196 + k0 + kg * 8];
      acc[0][n] = __builtin_amdgcn_mfma_f32_16x16x32_bf16(afr[0], bfr, acc[0][n], 0, 0, 0);
      acc[1][n] = __builtin_amdgcn_mfma_f32_16x16x32_bf16(afr[1], bfr, acc[1][n], 0, 0, 0);
    }
  }
  #pragma unroll
  for (int n = 0; n < 4; ++n) {
    int col = n0 + n * 16 + ln15;
    float bv = bias ? bias[col] : 0.f;
    #pragma unroll
    for (int m = 0; m < 2; ++m) {
      int rowb = r0 + wave * 32 + m * 16 + kg * 4;
      #pragma unroll
      for (int r = 0; r < 4; ++r)
        C[(size_t)(rowb + r) * N + col] = acc[m][n][r] + bv;
    }
  }
}

// ---------------------------------------------------------------------------
// LayerNorm rows of 192: fp32 out + bf16 out.
// ---------------------------------------------------------------------------
__global__ __launch_bounds__(256) void ln_rows_kernel(
    const float* __restrict__ X, const float* __restrict__ w,
    const float* __restrict__ bb, float* __restrict__ Y,
    ushortT* __restrict__ Yb, int R) {
  int row = blockIdx.x * 4 + (threadIdx.x >> 6);
  int lane = threadIdx.x & 63;
  if (row >= R) return;
  const float* xr = X + (size_t)row * 192;
  float v0 = xr[lane], v1 = xr[lane + 64], v2 = xr[lane + 128];
  float s = v0 + v1 + v2;
  float s2 = v0 * v0 + v1 * v1 + v2 * v2;
  #pragma unroll
  for (int off = 32; off; off >>= 1) { s += __shfl_xor(s, off); s2 += __shfl_xor(s2, off); }
  float mean = s * (1.f / 192.f);
  float var = s2 * (1.f / 192.f) - mean * mean;
  float inv = rsqrtf(var + 1e-5f);
  float o0 = (v0 - mean) * inv * w[lane]       + bb[lane];
  float o1 = (v1 - mean) * inv * w[lane + 64]  + bb[lane + 64];
  float o2 = (v2 - mean) * inv * w[lane + 128] + bb[lane + 128];
  float* yr = Y + (size_t)row * 192;
  yr[lane] = o0; yr[lane + 64] = o1; yr[lane + 128] = o2;
  ushortT* ybr = Yb + (size_t)row * 192;
  ybr[lane] = f2bf(o0); ybr[lane + 64] = f2bf(o1); ybr[lane + 128] = f2bf(o2);
}

// ---------------------------------------------------------------------------
// kv LN: y_g (64,192,32) -> bf16 (64,32,192) with LN over 192.
// ---------------------------------------------------------------------------
__global__ __launch_bounds__(256) void ln_kv_kernel(
    const float* __restrict__ yg, const float* __restrict__ w,
    const float* __restrict__ bb, ushortT* __restrict__ Yb) {
  int row = blockIdx.x * 4 + (threadIdx.x >> 6);
  int lane = threadIdx.x & 63;
  int b = row >> 5, t = row & 31;
  const float* src = yg + (size_t)b * 6144 + t;
  float v0 = src[(size_t)lane * 32];
  float v1 = src[(size_t)(lane + 64) * 32];
  float v2 = src[(size_t)(lane + 128) * 32];
  float s = v0 + v1 + v2;
  float s2 = v0 * v0 + v1 * v1 + v2 * v2;
  #pragma unroll
  for (int off = 32; off; off >>= 1) { s += __shfl_xor(s, off); s2 += __shfl_xor(s2, off); }
  float mean = s * (1.f / 192.f);
  float var = s2 * (1.f / 192.f) - mean * mean;
  float inv = rsqrtf(var + 1e-5f);
  ushortT* yr = Yb + (size_t)row * 192;
  yr[lane]       = f2bf((v0 - mean) * inv * w[lane]       + bb[lane]);
  yr[lane + 64]  = f2bf((v1 - mean) * inv * w[lane + 64]  + bb[lane + 64]);
  yr[lane + 128] = f2bf((v2 - mean) * inv * w[lane + 128] + bb[lane + 128]);
}

// ---------------------------------------------------------------------------
// Fused Bahdanau attention. qp/kp PRE-SCALED by c=2*log2(e).
// e(q,k) = S0 + sum_d (-2 v_d) * rcp(exp2(qp_d + kp_d) + 1)
// ---------------------------------------------------------------------------
__global__ __launch_bounds__(256) void attn_kernel(
    const float* __restrict__ qp, const float* __restrict__ kp,
    const float* __restrict__ vp, const float* __restrict__ vw,
    ushortT* __restrict__ ctxb) {
  int b = blockIdx.x >> 4;
  int q0 = (blockIdx.x & 15) * 16;
  __shared__ float skp[32 * 132];
  __shared__ float sqp[16 * 132];
  __shared__ float svp[32 * 192];
  __shared__ float se[16][33];
  __shared__ float swm[128];
  __shared__ float sS0;
  int tid = threadIdx.x;

  const float4* kp4 = (const float4*)(kp + (size_t)b * 32 * 128);
  for (int j = tid; j < 32 * 32; j += 256) {
    int k = j >> 5, d4 = j & 31;
    float4 v = kp4[k * 32 + d4];
    *(float4*)&skp[k * 132 + d4 * 4] = v;
  }
  const float4* qp4 = (const float4*)(qp + (size_t)(b * 256 + q0) * 128);
  for (int j = tid; j < 16 * 32; j += 256) {
    int qq = j >> 5, d4 = j & 31;
    float4 v = qp4[qq * 32 + d4];
    *(float4*)&sqp[qq * 132 + d4 * 4] = v;
  }
  const float4* vp4 = (const float4*)(vp + (size_t)b * 32 * 192);
  for (int j = tid; j < 32 * 48; j += 256) {
    int k = j / 48, m4 = j % 48;
    *(float4*)&svp[k * 192 + m4 * 4] = vp4[k * 48 + m4];
  }
  if (tid < 128) swm[tid] = -2.f * vw[tid];
  if (tid < 64) {
    float s = vw[tid] + vw[tid + 64];
    #pragma unroll
    for (int off = 32; off; off >>= 1) s += __shfl_xor(s, off);
    if (tid == 0) sS0 = s;
  }
  __syncthreads();

  {
    int qq = tid >> 4, kc = tid & 15;
    const float4* q4 = (const float4*)&sqp[qq * 132];
    const float4* ka = (const float4*)&skp[kc * 132];
    const float4* kb = (const float4*)&skp[(kc + 16) * 132];
    const float4* w4 = (const float4*)swm;
    float S0 = sS0;
    float acc0 = S0, acc1 = S0;
    #pragma unroll 8
    for (int dj = 0; dj < 32; ++dj) {
      float4 qv = q4[dj], k0 = ka[dj], k1 = kb[dj], wv = w4[dj];
      acc0 += wv.x * RCPF(EXP2F(qv.x + k0.x) + 1.f);
      acc0 += wv.y * RCPF(EXP2F(qv.y + k0.y) + 1.f);
      acc0 += wv.z * RCPF(EXP2F(qv.z + k0.z) + 1.f);
      acc0 += wv.w * RCPF(EXP2F(qv.w + k0.w) + 1.f);
      acc1 += wv.x * RCPF(EXP2F(qv.x + k1.x) + 1.f);
      acc1 += wv.y * RCPF(EXP2F(qv.y + k1.y) + 1.f);
      acc1 += wv.z * RCPF(EXP2F(qv.z + k1.z) + 1.f);
      acc1 += wv.w * RCPF(EXP2F(qv.w + k1.w) + 1.f);
    }
    se[qq][kc] = acc0;
    se[qq][kc + 16] = acc1;
  }
  __syncthreads();
  if (tid < 16) {
    float mx = -1e30f;
    for (int k = 0; k < 32; ++k) mx = fmaxf(mx, se[tid][k]);
    float s = 0.f;
    for (int k = 0; k < 32; ++k) { float a = __expf(se[tid][k] - mx); se[tid][k] = a; s += a; }
    float invs = 1.f / s;
    for (int k = 0; k < 32; ++k) se[tid][k] *= invs;
  }
  __syncthreads();
  for (int j = tid; j < 768; j += 256) {
    int qq = j / 48, m4 = j % 48;
    const float* al = se[qq];
    float4 a = {0.f, 0.f, 0.f, 0.f};
    #pragma unroll 8
    for (int k = 0; k < 32; ++k) {
      float wk = al[k];
      float4 v = *(const float4*)&svp[k * 192 + m4 * 4];
      a.x += wk * v.x; a.y += wk * v.y; a.z += wk * v.z; a.w += wk * v.w;
    }
    ushort4 o4 = {f2bf(a.x), f2bf(a.y), f2bf(a.z), f2bf(a.w)};
    *(ushort4*)&ctxb[((size_t)(b * 256 + q0 + qq)) * 192 + m4 * 4] = o4;
  }
}

// ---------------------------------------------------------------------------
// Final LN(q_ln + ctx2) + transpose (b,t,m) -> (b,m,t)
// ---------------------------------------------------------------------------
__global__ __launch_bounds__(256) void lnout_kernel(
    const float* __restrict__ qln, const float* __restrict__ ctx2,
    const float* __restrict__ w, const float* __restrict__ bb,
    float* __restrict__ out) {
  int b = blockIdx.x >> 2;
  int t0 = (blockIdx.x & 3) * 64;
  __shared__ float sf[64 * 193];
  int wid = threadIdx.x >> 6, lane = threadIdx.x & 63;
  for (int rr = wid; rr < 64; rr += 4) {
    size_t base = ((size_t)(b * 256 + t0 + rr)) * 192;
    float v0 = qln[base + lane]       + ctx2[base + lane];
    float v1 = qln[base + lane + 64]  + ctx2[base + lane + 64];
    float v2 = qln[base + lane + 128] + ctx2[base + lane + 128];
    float s = v0 + v1 + v2;
    float s2 = v0 * v0 + v1 * v1 + v2 * v2;
    #pragma unroll
    for (int off = 32; off; off >>= 1) { s += __shfl_xor(s, off); s2 += __shfl_xor(s2, off); }
    float mean = s * (1.f / 192.f);
    float var = s2 * (1.f / 192.f) - mean * mean;
    float inv = rsqrtf(var + 1e-5f);
    sf[rr * 193 + lane]       = (v0 - mean) * inv * w[lane]       + bb[lane];
    sf[rr * 193 + lane + 64]  = (v1 - mean) * inv * w[lane + 64]  + bb[lane + 64];
    sf[rr * 193 + lane + 128] = (v2 - mean) * inv * w[lane + 128] + bb[lane + 128];
  }
  __syncthreads();
  for (int j = threadIdx.x; j < 192 * 16; j += 256) {
    int m = j >> 4, t4 = j & 15;
    float4 o4;
    o4.x = sf[(t4 * 4 + 0) * 193 + m];
    o4.y = sf[(t4 * 4 + 1) * 193 + m];
    o4.z = sf[(t4 * 4 + 2) * 193 + m];
    o4.w = sf[(t4 * 4 + 3) * 193 + m];
    *(float4*)&out[((size_t)(b * 192 + m)) * 256 + t0 + t4 * 4] = o4;
  }
}

// ---------------------------------------------------------------------------
extern "C" void kernel_launch(void* const* d_in, const int* in_sizes, int n_in,
                              void* d_out, int out_size, void* d_ws, size_t ws_size,
                              hipStream_t stream) {
  (void)in_sizes; (void)n_in; (void)out_size; (void)ws_size;
  const float* x_p     = (const float*)d_in[0];
  const float* y_g     = (const float*)d_in[1];
  const float* conv1_w = (const float*)d_in[2];
  const float* conv1_b = (const float*)d_in[3];
  const float* gamma1  = (const float*)d_in[4];
  const float* beta1   = (const float*)d_in[5];
  const float* conv2_w = (const float*)d_in[6];
  const float* conv2_b = (const float*)d_in[7];
  const float* gamma2  = (const float*)d_in[8];
  const float* beta2   = (const float*)d_in[9];
  const float* conv3_w = (const float*)d_in[10];
  const float* conv3_b = (const float*)d_in[11];
  const float* ln_q_w  = (const float*)d_in[12];
  const float* ln_q_b  = (const float*)d_in[13];
  const float* ln_kv_w = (const float*)d_in[14];
  const float* ln_kv_b = (const float*)d_in[15];
  const float* ln_out_w= (const float*)d_in[16];
  const float* ln_out_b= (const float*)d_in[17];
  const float* Wq      = (const float*)d_in[18];
  const float* Wk      = (const float*)d_in[19];
  const float* v_w     = (const float*)d_in[20];
  const float* Wv      = (const float*)d_in[21];
  const float* out_w   = (const float*)d_in[22];
  const float* out_b   = (const float*)d_in[23];
  float* out = (float*)d_out;
  float* ws  = (float*)d_ws;

  ushortT* t1bf  = (ushortT*)(ws + OFF_T1BF);
  ushortT* x2bf  = (ushortT*)(ws + OFF_X2BF);
  ushortT* t2bf  = (ushortT*)(ws + OFF_T2BF);
  ushortT* x3bf  = (ushortT*)(ws + OFF_X3BF);
  float*   qraw  = ws + OFF_QRAW;
  float*   qln   = ws + OFF_QLN;
  ushortT* qlnb  = (ushortT*)(ws + OFF_QLNB);
  ushortT* kvb   = (ushortT*)(ws + OFF_KVB);
  float*   qproj = ws + OFF_QP;
  float*   kproj = ws + OFF_KP;
  float*   vproj = ws + OFF_VP;
  ushortT* wbq   = (ushortT*)(ws + OFF_WBQ);
  ushortT* wbk   = (ushortT*)(ws + OFF_WBK);
  ushortT* wbv   = (ushortT*)(ws + OFF_WBV);
  ushortT* wbo   = (ushortT*)(ws + OFF_WBO);
  ushortT* ctxb  = (ushortT*)(ws + OFF_CTXB);
  float*   ctx2  = ws + OFF_CTX2;
  ushortT* wt2   = (ushortT*)(ws + OFF_WT2);
  ushortT* wt3   = (ushortT*)(ws + OFF_WT3);
  ushortT* wc1   = (ushortT*)(ws + OFF_WC1);
  ushortT* gb1   = (ushortT*)(ws + OFF_GB1);
  ushortT* gb2   = (ushortT*)(ws + OFF_GB2);

  constexpr float C2LE = 2.88539008177792681f;   // 2*log2(e)

  convw3_kernel<<<1600, 256, 0, stream>>>(conv2_w, wt2, 0, 409600);
  convw3_kernel<<<864, 256, 0, stream>>>(conv3_w, wt3, 1, 221184);
  convw1_kernel<<<80, 256, 0, stream>>>(conv1_w, wc1);
  wcast_kernel<<<96, 256, 0, stream>>>(Wq, wbq, 24576, C2LE);
  wcast_kernel<<<96, 256, 0, stream>>>(Wk, wbk, 24576, C2LE);
  wcast_kernel<<<144, 256, 0, stream>>>(Wv, wbv, 36864, 1.0f);
  wcast_kernel<<<144, 256, 0, stream>>>(out_w, wbo, 36864, 1.0f);
  wcast_kernel<<<64, 256, 0, stream>>>(gamma1, gb1, 16384, 1.0f);
  wcast_kernel<<<64, 256, 0, stream>>>(gamma2, gb2, 16384, 1.0f);

  conv1_mfma_kernel<<<256, 256, 0, stream>>>(x_p, wc1, conv1_b, t1bf);
  gdn_mfma_kernel<<<1024, 256, 0, stream>>>(t1bf, gb1, beta1, x2bf, 1024, 16, 1);
  conv_mfma_kernel<0><<<256, 256, 0, stream>>>(x2bf, wt2, conv2_b, t2bf, nullptr);
  gdn_mfma_kernel<<<256, 256, 0, stream>>>(t2bf, gb2, beta2, x3bf, 256, 4, 0);
  conv_mfma_kernel<1><<<384, 256, 0, stream>>>(x3bf, wt3, conv3_b, nullptr, qraw);
  ln_rows_kernel<<<4096, 256, 0, stream>>>(qraw, ln_q_w, ln_q_b, qln, qlnb, 16384);
  ln_kv_kernel<<<512, 256, 0, stream>>>(y_g, ln_kv_w, ln_kv_b, kvb);
  gemm_bf16_kernel<<<256, 256, 0, stream>>>(qlnb, wbq, nullptr, qproj, 128, 2);
  gemm_bf16_kernel<<<32, 256, 0, stream>>>(kvb, wbk, nullptr, kproj, 128, 2);
  gemm_bf16_kernel<<<48, 256, 0, stream>>>(kvb, wbv, nullptr, vproj, 192, 3);
  attn_kernel<<<1024, 256, 0, stream>>>(qproj, kproj, vproj, v_w, ctxb);
  gemm_bf16_kernel<<<384, 256, 0, stream>>>(ctxb, wbo, out_b, ctx2, 192, 3);
  lnout_kernel<<<256, 256, 0, stream>>>(qln, ctx2, ln_out_w, ln_out_b, out);
}

// Round 7
// 260.982 us; speedup vs baseline: 2.8939x; 1.1455x over previous
//
#include <hip/hip_runtime.h>
#include <cstddef>
#include <cstdint>

// ---------------------------------------------------------------------------
// Pipeline: x (64,3,64,64) -> conv1 5x5s2 (MFMA polyphase) -> GDN1 (MFMA)
//   -> conv2 5x5s2 (MFMA polyphase) -> GDN2 (MFMA) -> conv3 3x3 (MFMA)
//   -> LN -> Bahdanau attention -> out proj (MFMA) -> LN -> out.
// R7: single fused prep kernel (9->1), conv row-split x4 (2 blocks/CU),
// fused ln_all + gemm_qkv, qln kept bf16-only. 12 launches total.
// ---------------------------------------------------------------------------

typedef __bf16 bf16x8 __attribute__((ext_vector_type(8)));
typedef float floatx4 __attribute__((ext_vector_type(4)));
typedef unsigned short ushortT;
typedef unsigned short ushort8v __attribute__((ext_vector_type(8)));

#if __has_builtin(__builtin_amdgcn_exp2f)
#define EXP2F(x) __builtin_amdgcn_exp2f(x)
#else
#define EXP2F(x) exp2f(x)
#endif
#if __has_builtin(__builtin_amdgcn_rcpf)
#define RCPF(x) __builtin_amdgcn_rcpf(x)
#else
#define RCPF(x) (1.f / (x))
#endif

__device__ __forceinline__ ushortT f2bf(float f) {
  unsigned u = __builtin_bit_cast(unsigned, f);
  unsigned r = (u + 0x7FFFu + ((u >> 16) & 1u)) >> 16;
  return (ushortT)r;
}
__device__ __forceinline__ float bf2f(ushortT u) {
  return __builtin_bit_cast(float, ((unsigned)u) << 16);
}

// ---- workspace layout (float-slot offsets) ----
static constexpr size_t OFF_T1BF = 0;          // conv1 out bf16 (64,1024,128)
static constexpr size_t OFF_X2BF = 4194304;    // gdn1 out bf16 [b][4][256][128]
static constexpr size_t OFF_T2BF = 8388608;    // conv2 out bf16 (64,256,128)
static constexpr size_t OFF_X3BF = 9437184;    // gdn2 out bf16 (64,256,128)
static constexpr size_t OFF_QRAW = 10485760;   // conv3 out fp32 (64,256,192)
static constexpr size_t OFF_QLNB = 16777216;   // bf16 (64,256,192)
static constexpr size_t OFF_KVB  = 18350080;   // bf16 (64,32,192)
static constexpr size_t OFF_QP   = 18546688;   // fp32 (64,256,128)
static constexpr size_t OFF_KP   = 20643840;   // fp32 (64,32,128)
static constexpr size_t OFF_VP   = 20905984;   // fp32 (64,32,192)
static constexpr size_t OFF_WBQ  = 21299200;   // bf16 128x192 (scaled by c)
static constexpr size_t OFF_WBK  = 21311488;   // bf16 128x192 (scaled by c)
static constexpr size_t OFF_WBV  = 21323776;   // bf16 192x192
static constexpr size_t OFF_WBO  = 21342208;   // bf16 192x192
static constexpr size_t OFF_CTXB = 21360640;   // bf16 (64,256,192)
static constexpr size_t OFF_CTX2 = 22933504;   // fp32 (64,256,192)
static constexpr size_t OFF_WT2  = 26079232;   // bf16 conv2 slabs [200][2048]
static constexpr size_t OFF_WT3  = 26284032;   // bf16 conv3 slabs [108][2048]
static constexpr size_t OFF_WC1  = 26394624;   // bf16 conv1 slabs [5][128][32]
static constexpr size_t OFF_GB1  = 26406912;   // bf16 gamma1 128x128
static constexpr size_t OFF_GB2  = 26415104;   // bf16 gamma2 128x128

// 5x5 s2 p2 polyphase tap tables (tap id = kh*5+kw); HW-verified via conv2.
__device__ __constant__ int d_TWI2[4][9] = {{ 0, 2, 4,10,12,14,20,22,24},
                                            { 1, 3,11,13,21,23, 0, 0, 0},
                                            { 5, 7, 9,15,17,19, 0, 0, 0},
                                            { 6, 8,16,18, 0, 0, 0, 0, 0}};
__device__ __constant__ int d_NT2[4] = {9, 6, 6, 4};

// ---------------------------------------------------------------------------
// fused prep: all weight repacks/casts in one launch, block-range dispatch.
// ---------------------------------------------------------------------------
__device__ void dev_convw3(const float* w, ushortT* wt, int mode, int total,
                           int idx) {
  if (idx >= total) return;
  int j    = idx & 7;
  int om   = (idx >> 3) & 63;
  int kg   = (idx >> 9) & 3;
  int slab = idx >> 11;
  int mt, s, tap, T;
  if (mode == 0) {
    int ph;
    if (slab < 72) ph = 0; else if (slab < 120) ph = 1;
    else if (slab < 168) ph = 2; else ph = 3;
    const int st[4] = {0, 72, 120, 168};
    const int ns[4] = {36, 24, 24, 16};
    int rel = slab - st[ph];
    mt = rel / ns[ph]; s = rel % ns[ph];
    tap = d_TWI2[ph][s >> 2]; T = 25;
  } else {
    mt = slab / 36; s = slab % 36; tap = s >> 2; T = 9;
  }
  int cc = s & 3;
  int c  = cc * 32 + kg * 8 + j;
  int oc = mt * 64 + om;
  wt[idx] = f2bf(w[(size_t)(oc * 128 + c) * T + tap]);
}

__device__ void dev_convw1(const float* w, ushortT* wt, int idx) {
  if (idx >= 20480) return;
  int k    = idx & 31;
  int oc   = (idx >> 5) & 127;
  int slab = idx >> 12;
  int ph, i;
  if (slab < 2) { ph = 0; i = slab; } else { ph = slab - 1; i = 0; }
  int kg = k >> 3, jj = k & 7;
  int tidx = i * 8 + jj;
  float val = 0.f;
  if (kg < 3 && tidx < d_NT2[ph]) {
    int tap = d_TWI2[ph][tidx];
    val = w[(size_t)(oc * 3 + kg) * 25 + tap];
  }
  wt[idx] = f2bf(val);
}

__device__ void dev_wcast(const float* w, ushortT* wb, int total, float scale,
                          int idx) {
  if (idx < total) wb[idx] = f2bf(w[idx] * scale);
}

__global__ __launch_bounds__(256) void prep_kernel(
    const float* __restrict__ conv2_w, ushortT* __restrict__ wt2,
    const float* __restrict__ conv3_w, ushortT* __restrict__ wt3,
    const float* __restrict__ conv1_w, ushortT* __restrict__ wc1,
    const float* __restrict__ Wq, ushortT* __restrict__ wbq,
    const float* __restrict__ Wk, ushortT* __restrict__ wbk,
    const float* __restrict__ Wv, ushortT* __restrict__ wbv,
    const float* __restrict__ out_w, ushortT* __restrict__ wbo,
    const float* __restrict__ gamma1, ushortT* __restrict__ gb1,
    const float* __restrict__ gamma2, ushortT* __restrict__ gb2) {
  constexpr float C2LE = 2.88539008177792681f;   // 2*log2(e)
  int blk = blockIdx.x, tid = threadIdx.x;
  if (blk < 1600)      dev_convw3(conv2_w, wt2, 0, 409600, blk * 256 + tid);
  else if (blk < 2464) dev_convw3(conv3_w, wt3, 1, 221184, (blk - 1600) * 256 + tid);
  else if (blk < 2544) dev_convw1(conv1_w, wc1, (blk - 2464) * 256 + tid);
  else if (blk < 2640) dev_wcast(Wq, wbq, 24576, C2LE, (blk - 2544) * 256 + tid);
  else if (blk < 2736) dev_wcast(Wk, wbk, 24576, C2LE, (blk - 2640) * 256 + tid);
  else if (blk < 2880) dev_wcast(Wv, wbv, 36864, 1.f, (blk - 2736) * 256 + tid);
  else if (blk < 3024) dev_wcast(out_w, wbo, 36864, 1.f, (blk - 2880) * 256 + tid);
  else if (blk < 3088) dev_wcast(gamma1, gb1, 16384, 1.f, (blk - 3024) * 256 + tid);
  else                 dev_wcast(gamma2, gb2, 16384, 1.f, (blk - 3088) * 256 + tid);
}

// ---------------------------------------------------------------------------
// conv1 MFMA polyphase: (64,3,64,64) fp32 -> (64,1024px,128c) bf16.
// ---------------------------------------------------------------------------
__global__ __launch_bounds__(256, 1) void conv1_mfma_kernel(
    const float* __restrict__ x, const ushortT* __restrict__ wc1,
    const float* __restrict__ bias, ushortT* __restrict__ outb) {
  int b  = blockIdx.x >> 2;
  int yg = blockIdx.x & 3;
  int y0 = yg * 8;

  int wave = threadIdx.x >> 6;
  int lane = threadIdx.x & 63;
  int ln15 = lane & 15;
  int kg   = lane >> 4;
  int tid  = threadIdx.x;

  __shared__ ushortT simg[4680];         // [ph][c][lr(10)][col(36)] + pad
  __shared__ ushortT sA[5 * 128 * 40];   // [slab][oc][40]

  for (int j = tid; j < 2340; j += 256) ((unsigned*)simg)[j] = 0u;
  __syncthreads();

  int ihBase = 2 * y0 - 2;
  const float* xb = x + (size_t)b * 3 * 4096;
  for (int j = tid; j < 960; j += 256) {
    int q = j & 15;
    int rr = j >> 4;
    int c = rr / 20, ihl = rr % 20;
    int ih = ihBase + ihl;
    if (ih >= 0 && ih < 64) {
      float4 v = *(const float4*)&xb[c * 4096 + ih * 64 + q * 4];
      int pr = ih & 1, u = ih >> 1;
      int lr = u - y0 + 1;
      int base0 = ((pr * 2 + 0) * 3 + c) * 360 + lr * 36;
      int base1 = ((pr * 2 + 1) * 3 + c) * 360 + lr * 36;
      simg[base0 + 2 * q + 1] = f2bf(v.x);
      simg[base1 + 2 * q + 1] = f2bf(v.y);
      simg[base0 + 2 * q + 2] = f2bf(v.z);
      simg[base1 + 2 * q + 2] = f2bf(v.w);
    }
  }
  for (int j = tid; j < 2560; j += 256) {
    int chunk = j & 3, row = j >> 2;
    uint4 v = *(const uint4*)&wc1[row * 32 + chunk * 8];
    *(uint4*)&sA[row * 40 + chunk * 8] = v;
  }
  __syncthreads();

  constexpr int TDR[4][9] = {{-1,-1,-1, 0, 0, 0, 1, 1, 1},
                             {-1,-1, 0, 0, 1, 1, 0, 0, 0},
                             {-1,-1,-1, 0, 0, 0, 0, 0, 0},
                             {-1,-1, 0, 0, 0, 0, 0, 0, 0}};
  constexpr int TDC[4][9] = {{-1, 0, 1,-1, 0, 1,-1, 0, 1},
                             {-1, 0,-1, 0,-1, 0, 0, 0, 0},
                             {-1, 0, 1,-1, 0, 1, 0, 0, 0},
                             {-1, 0,-1, 0, 0, 0, 0, 0, 0}};
  constexpr int NT[4]  = {9, 6, 6, 4};
  constexpr int NM[4]  = {2, 1, 1, 1};
  constexpr int SB[4]  = {0, 2, 3, 4};

  ushort8v Bf[4][5];
  #pragma unroll
  for (int ntl = 0; ntl < 4; ++ntl) {
    int ntg = wave * 4 + ntl;
    int yloc = ntg >> 1;
    int xx = (ntg & 1) * 16 + ln15;
    int lbase = (yloc + 1) * 36 + xx + 1 + kg * 360;
    #pragma unroll
    for (int ph = 0; ph < 4; ++ph) {
      int pbase = ph * 1080 + lbase;
      #pragma unroll
      for (int i = 0; i < 2; ++i) {
        if (i < NM[ph]) {
          ushort8v bv;
          #pragma unroll
          for (int j = 0; j < 8; ++j) {
            int tidx = i * 8 + j;
            if (tidx >= NT[ph]) tidx = 0;
            int off = TDR[ph][tidx] * 36 + TDC[ph][tidx];
            bv[j] = simg[pbase + off];
          }
          Bf[ntl][SB[ph] + i] = bv;
        }
      }
    }
  }

  #pragma unroll
  for (int m = 0; m < 8; ++m) {
    bf16x8 Af[5];
    #pragma unroll
    for (int s = 0; s < 5; ++s)
      Af[s] = *(const bf16x8*)&sA[(s * 128 + m * 16 + ln15) * 40 + kg * 8];
    int oc0 = m * 16 + kg * 4;
    float4 bv = *(const float4*)&bias[oc0];
    #pragma unroll
    for (int ntl = 0; ntl < 4; ++ntl) {
      floatx4 acc = (floatx4)0.f;
      #pragma unroll
      for (int s = 0; s < 5; ++s)
        acc = __builtin_amdgcn_mfma_f32_16x16x32_bf16(
            Af[s], __builtin_bit_cast(bf16x8, Bf[ntl][s]), acc, 0, 0, 0);
      int ntg = wave * 4 + ntl;
      int y = y0 + (ntg >> 1);
      int xx = (ntg & 1) * 16 + ln15;
      int p = y * 32 + xx;
      ushort4 o4 = {f2bf(acc[0] + bv.x), f2bf(acc[1] + bv.y),
                    f2bf(acc[2] + bv.z), f2bf(acc[3] + bv.w)};
      *(ushort4*)&outb[((size_t)b * 1024 + p) * 128 + oc0] = o4;
    }
  }
}

// ---------------------------------------------------------------------------
// GDN as bf16 MFMA GEMM (unchanged from r6).
// ---------------------------------------------------------------------------
__global__ __launch_bounds__(256) void gdn_mfma_kernel(
    const ushortT* __restrict__ xbf, const ushortT* __restrict__ gb,
    const float* __restrict__ beta, ushortT* __restrict__ ybf,
    int HW, int nPixTiles, int isSplit) {
  int pt = blockIdx.x % nPixTiles;
  int b  = blockIdx.x / nPixTiles;
  int px0 = pt * 64;
  int tid = threadIdx.x;
  int wave = tid >> 6, lane = tid & 63, ln15 = lane & 15, kg = lane >> 4;

  __shared__ ushortT sG[128 * 136];
  __shared__ ushortT sX[64 * 136];

  for (int j = tid; j < 2048; j += 256) {
    int row = j >> 4, ch = j & 15;
    *(uint4*)&sG[row * 136 + ch * 8] = *(const uint4*)&gb[row * 128 + ch * 8];
  }
  for (int j = tid; j < 1024; j += 256) {
    int row = j >> 4, ch = j & 15;
    ushort8v xv = *(const ushort8v*)&xbf[((size_t)(b * HW + px0 + row)) * 128 + ch * 8];
    ushort8v sq;
    #pragma unroll
    for (int r = 0; r < 8; ++r) {
      float f = bf2f(xv[r]);
      sq[r] = f2bf(f * f);
    }
    *(ushort8v*)&sX[row * 136 + ch * 8] = sq;
  }
  __syncthreads();

  floatx4 acc[2][4];
  #pragma unroll
  for (int mi = 0; mi < 2; ++mi)
    #pragma unroll
    for (int nt = 0; nt < 4; ++nt) acc[mi][nt] = (floatx4)0.f;

  #pragma unroll
  for (int k0 = 0; k0 < 128; k0 += 32) {
    bf16x8 a0 = *(const bf16x8*)&sG[(wave * 32 + ln15) * 136 + k0 + kg * 8];
    bf16x8 a1 = *(const bf16x8*)&sG[(wave * 32 + 16 + ln15) * 136 + k0 + kg * 8];
    #pragma unroll
    for (int nt = 0; nt < 4; ++nt) {
      bf16x8 bb = *(const bf16x8*)&sX[(nt * 16 + ln15) * 136 + k0 + kg * 8];
      acc[0][nt] = __builtin_amdgcn_mfma_f32_16x16x32_bf16(a0, bb, acc[0][nt], 0, 0, 0);
      acc[1][nt] = __builtin_amdgcn_mfma_f32_16x16x32_bf16(a1, bb, acc[1][nt], 0, 0, 0);
    }
  }

  #pragma unroll
  for (int mi = 0; mi < 2; ++mi) {
    int d0 = wave * 32 + mi * 16 + kg * 4;
    float4 bt = *(const float4*)&beta[d0];
    #pragma unroll
    for (int nt = 0; nt < 4; ++nt) {
      int p = px0 + nt * 16 + ln15;
      ushort4 x4 = *(const ushort4*)&xbf[((size_t)(b * HW + p)) * 128 + d0];
      ushort4 o4;
      o4.x = f2bf(bf2f(x4.x) * rsqrtf(acc[mi][nt][0] + bt.x));
      o4.y = f2bf(bf2f(x4.y) * rsqrtf(acc[mi][nt][1] + bt.y));
      o4.z = f2bf(bf2f(x4.z) * rsqrtf(acc[mi][nt][2] + bt.z));
      o4.w = f2bf(bf2f(x4.w) * rsqrtf(acc[mi][nt][3] + bt.w));
      size_t dst;
      if (isSplit) {
        int h = p >> 5, w5 = p & 31;
        int ph = ((h & 1) << 1) | (w5 & 1);
        dst = (((size_t)b * 4 + ph) * 256 + (h >> 1) * 16 + (w5 >> 1)) * 128 + d0;
      } else {
        dst = ((size_t)b * 256 + p) * 128 + d0;
      }
      *(ushort4*)&ybf[dst] = o4;
    }
  }
}

// ---------------------------------------------------------------------------
// conv2/conv3 MFMA implicit GEMM; r7: 4-row split -> 2 blocks/CU.
// Block: (b, mt 64-oc tile, rs in 0..3 -> rows rs*4..rs*4+3).
// Wave w owns output row r0 + w.
// ---------------------------------------------------------------------------
template<int MODE>
__global__ __launch_bounds__(256, 2) void conv_mfma_kernel(
    const ushortT* __restrict__ X,
    const ushortT* __restrict__ Wt,
    const float* __restrict__ bias,
    ushortT* __restrict__ outb, float* __restrict__ outf) {
  constexpr int OC  = (MODE == 0) ? 128 : 192;
  constexpr int NMT = OC / 64;
  constexpr int NPH = (MODE == 0) ? 4 : 1;

  int b   = blockIdx.x / (NMT * 4);
  int rem = blockIdx.x % (NMT * 4);
  int mt  = rem >> 2;
  int rs  = rem & 3;
  int r0  = rs * 4;

  int wave = threadIdx.x >> 6;
  int lane = threadIdx.x & 63;
  int ln15 = lane & 15;
  int kg   = lane >> 4;

  __shared__ ushortT simg[6 * 18 * 136];   // 29.4 KB

  floatx4 acc[4];
  #pragma unroll
  for (int m = 0; m < 4; ++m) acc[m] = (floatx4)0.f;

  constexpr int NS2[4]      = {36, 24, 24, 16};
  constexpr int PHSTART2[4] = {0, 72, 120, 168};
  constexpr int TDR_2[4][9] = {{-1,-1,-1, 0, 0, 0, 1, 1, 1},
                               {-1,-1, 0, 0, 1, 1, 0, 0, 0},
                               {-1,-1,-1, 0, 0, 0, 0, 0, 0},
                               {-1,-1, 0, 0, 0, 0, 0, 0, 0}};
  constexpr int TDC_2[4][9] = {{-1, 0, 1,-1, 0, 1,-1, 0, 1},
                               {-1, 0,-1, 0,-1, 0, 0, 0, 0},
                               {-1, 0, 1,-1, 0, 1, 0, 0, 0},
                               {-1, 0,-1, 0, 0, 0, 0, 0, 0}};
  constexpr int TDR_3[9] = {-1,-1,-1, 0, 0, 0, 1, 1, 1};
  constexpr int TDC_3[9] = {-1, 0, 1,-1, 0, 1,-1, 0, 1};

  const int aoff = kg * 512 + ln15 * 8;
  uint4 apf[8][4];

  #pragma unroll
  for (int ph = 0; ph < NPH; ++ph) {
    const int NS = (MODE == 0) ? NS2[ph] : 36;
    const int slabBase = (MODE == 0) ? (PHSTART2[ph] + mt * NS2[ph]) : (mt * 36);
    const ushortT* wp0 = Wt + (size_t)slabBase * 2048 + aoff;

    __syncthreads();
    const ushortT* Xb = X + (((size_t)b * NPH + ph) * 256) * 128;
    for (int idx = threadIdx.x; idx < 1728; idx += 256) {
      int chunk = idx & 15;
      int pix = idx >> 4;
      int row = pix / 18, colm = pix - row * 18;
      int i = r0 - 1 + row, j = colm - 1;
      uint4 v = {0u, 0u, 0u, 0u};
      if (i >= 0 && i < 16 && j >= 0 && j < 16)
        v = *(const uint4*)(Xb + ((size_t)(i * 16 + j)) * 128 + chunk * 8);
      *(uint4*)&simg[(row * 18 + colm) * 136 + chunk * 8] = v;
    }
    #pragma unroll
    for (int jj = 0; jj < 8; ++jj)
      if (jj < NS) {
        #pragma unroll
        for (int m = 0; m < 4; ++m)
          apf[jj][m] = *(const uint4*)(wp0 + (size_t)jj * 2048 + m * 128);
      }
    __syncthreads();

    #pragma unroll
    for (int s0 = 0; s0 < NS; s0 += 8) {
      #pragma unroll
      for (int jj = 0; jj < 8; ++jj) {
        int s = s0 + jj;
        if (s < NS) {
          bf16x8 acur[4];
          #pragma unroll
          for (int m = 0; m < 4; ++m) acur[m] = __builtin_bit_cast(bf16x8, apf[jj][m]);
          int sp = s + 8;
          if (sp < NS) {
            #pragma unroll
            for (int m = 0; m < 4; ++m)
              apf[jj][m] = *(const uint4*)(wp0 + (size_t)sp * 2048 + m * 128);
          }
          int t  = s >> 2;
          int c0 = (s & 3) * 32;
          int dr = (MODE == 0) ? TDR_2[ph][t] : TDR_3[t];
          int dc = (MODE == 0) ? TDC_2[ph][t] : TDC_3[t];
          int lrow = wave + dr + 1;
          int lcol = ln15 + dc + 1;
          bf16x8 bfr = *(const bf16x8*)&simg[(lrow * 18 + lcol) * 136 + c0 + kg * 8];
          #pragma unroll
          for (int m = 0; m < 4; ++m)
            acc[m] = __builtin_amdgcn_mfma_f32_16x16x32_bf16(acur[m], bfr, acc[m], 0, 0, 0);
        }
      }
    }
  }

  #pragma unroll
  for (int m = 0; m < 4; ++m) {
    int mg = mt * 64 + m * 16 + kg * 4;
    float4 bv = *(const float4*)&bias[mg];
    int r = r0 + wave;
    int p = r * 16 + ln15;
    if (MODE == 0) {
      ushort4 o4 = {f2bf(acc[m][0] + bv.x), f2bf(acc[m][1] + bv.y),
                    f2bf(acc[m][2] + bv.z), f2bf(acc[m][3] + bv.w)};
      *(ushort4*)&outb[((size_t)b * 256 + p) * 128 + mg] = o4;
    } else {
      float4 o4 = {acc[m][0] + bv.x, acc[m][1] + bv.y,
                   acc[m][2] + bv.z, acc[m][3] + bv.w};
      *(float4*)&outf[((size_t)b * 256 + p) * OC + mg] = o4;
    }
  }
}

// ---------------------------------------------------------------------------
// bf16 MFMA GEMM body: C[r][n] = sum_k A[r][k]*B[n][k] (+bias); K=192.
// ---------------------------------------------------------------------------
__device__ __forceinline__ void gemm_body(
    const ushortT* A, const ushortT* Bm, const float* bias, float* C,
    int N, int r0, int n0, int tid) {
  __shared__ ushortT sA[128 * 196];
  __shared__ ushortT sB[64 * 196];
  for (int j = tid; j < 3072; j += 256) {
    int row = j / 24, ch = j % 24;
    *(ushort8v*)&sA[row * 196 + ch * 8] = *(const ushort8v*)&A[(size_t)(r0 + row) * 192 + ch * 8];
  }
  for (int j = tid; j < 1536; j += 256) {
    int row = j / 24, ch = j % 24;
    *(ushort8v*)&sB[row * 196 + ch * 8] = *(const ushort8v*)&Bm[(size_t)(n0 + row) * 192 + ch * 8];
  }
  __syncthreads();
  int wave = tid >> 6, lane = tid & 63, ln15 = lane & 15, kg = lane >> 4;
  floatx4 acc[2][4];
  #pragma unroll
  for (int m = 0; m < 2; ++m)
    #pragma unroll
    for (int n = 0; n < 4; ++n) acc[m][n] = (floatx4)0.f;

  #pragma unroll
  for (int k0 = 0; k0 < 192; k0 += 32) {
    bf16x8 afr[2];
    #pragma unroll
    for (int m = 0; m < 2; ++m)
      afr[m] = *(const bf16x8*)&sA[(wave * 32 + m * 16 + ln15) * 196 + k0 + kg * 8];
    #pragma unroll
    for (int n = 0; n < 4; ++n) {
      bf16x8 bfr = *(const bf16x8*)&sB[(n * 16 + ln15) * 196 + k0 + kg * 8];
      acc[0][n] = __builtin_amdgcn_mfma_f32_16x16x32_bf16(afr[0], bfr, acc[0][n], 0, 0, 0);
      acc[1][n] = __builtin_amdgcn_mfma_f32_16x16x32_bf16(afr[1], bfr, acc[1][n], 0, 0, 0);
    }
  }
  #pragma unroll
  for (int n = 0; n < 4; ++n) {
    int col = n0 + n * 16 + ln15;
    float bv = bias ? bias[col] : 0.f;
    #pragma unroll
    for (int m = 0; m < 2; ++m) {
      int rowb = r0 + wave * 32 + m * 16 + kg * 4;
      #pragma unroll
      for (int r = 0; r < 4; ++r)
        C[(size_t)(rowb + r) * N + col] = acc[m][n][r] + bv;
    }
  }
}

// fused Q/K/V projection GEMMs in one launch (336 blocks).
__global__ __launch_bounds__(256) void gemm_qkv_kernel(
    const ushortT* __restrict__ qlnb, const ushortT* __restrict__ kvb,
    const ushortT* __restrict__ wbq, const ushortT* __restrict__ wbk,
    const ushortT* __restrict__ wbv,
    float* __restrict__ qproj, float* __restrict__ kproj,
    float* __restrict__ vproj) {
  int blk = blockIdx.x, tid = threadIdx.x;
  if (blk < 256) {
    gemm_body(qlnb, wbq, nullptr, qproj, 128, (blk >> 1) * 128, (blk & 1) * 64, tid);
  } else if (blk < 288) {
    int k = blk - 256;
    gemm_body(kvb, wbk, nullptr, kproj, 128, (k >> 1) * 128, (k & 1) * 64, tid);
  } else {
    int k = blk - 288;
    gemm_body(kvb, wbv, nullptr, vproj, 192, (k / 3) * 128, (k % 3) * 64, tid);
  }
}

// out-projection GEMM.
__global__ __launch_bounds__(256) void gemm_out_kernel(
    const ushortT* __restrict__ A, const ushortT* __restrict__ Bm,
    const float* __restrict__ bias, float* __restrict__ C) {
  gemm_body(A, Bm, bias, C, 192, (blockIdx.x / 3) * 128, (blockIdx.x % 3) * 64,
            threadIdx.x);
}

// ---------------------------------------------------------------------------
// fused LN: blocks [0,4096) -> LN(qraw) -> qlnb bf16;
//           blocks [4096,4608) -> LN(y_g gather) -> kvb bf16.
// ---------------------------------------------------------------------------
__global__ __launch_bounds__(256) void ln_all_kernel(
    const float* __restrict__ qraw, const float* __restrict__ qw,
    const float* __restrict__ qb, ushortT* __restrict__ qlnb,
    const float* __restrict__ yg, const float* __restrict__ kw,
    const float* __restrict__ kb, ushortT* __restrict__ kvb) {
  int lane = threadIdx.x & 63;
  if (blockIdx.x < 4096) {
    int row = blockIdx.x * 4 + (threadIdx.x >> 6);
    const float* xr = qraw + (size_t)row * 192;
    float v0 = xr[lane], v1 = xr[lane + 64], v2 = xr[lane + 128];
    float s = v0 + v1 + v2;
    float s2 = v0 * v0 + v1 * v1 + v2 * v2;
    #pragma unroll
    for (int off = 32; off; off >>= 1) { s += __shfl_xor(s, off); s2 += __shfl_xor(s2, off); }
    float mean = s * (1.f / 192.f);
    float var = s2 * (1.f / 192.f) - mean * mean;
    float inv = rsqrtf(var + 1e-5f);
    ushortT* ybr = qlnb + (size_t)row * 192;
    ybr[lane]       = f2bf((v0 - mean) * inv * qw[lane]       + qb[lane]);
    ybr[lane + 64]  = f2bf((v1 - mean) * inv * qw[lane + 64]  + qb[lane + 64]);
    ybr[lane + 128] = f2bf((v2 - mean) * inv * qw[lane + 128] + qb[lane + 128]);
  } else {
    int row = (blockIdx.x - 4096) * 4 + (threadIdx.x >> 6);
    int b = row >> 5, t = row & 31;
    const float* src = yg + (size_t)b * 6144 + t;
    float v0 = src[(size_t)lane * 32];
    float v1 = src[(size_t)(lane + 64) * 32];
    float v2 = src[(size_t)(lane + 128) * 32];
    float s = v0 + v1 + v2;
    float s2 = v0 * v0 + v1 * v1 + v2 * v2;
    #pragma unroll
    for (int off = 32; off; off >>= 1) { s += __shfl_xor(s, off); s2 += __shfl_xor(s2, off); }
    float mean = s * (1.f / 192.f);
    float var = s2 * (1.f / 192.f) - mean * mean;
    float inv = rsqrtf(var + 1e-5f);
    ushortT* yr = kvb + (size_t)row * 192;
    yr[lane]       = f2bf((v0 - mean) * inv * kw[lane]       + kb[lane]);
    yr[lane + 64]  = f2bf((v1 - mean) * inv * kw[lane + 64]  + kb[lane + 64]);
    yr[lane + 128] = f2bf((v2 - mean) * inv * kw[lane + 128] + kb[lane + 128]);
  }
}

// ---------------------------------------------------------------------------
// Fused Bahdanau attention (unchanged from r6). qp/kp PRE-SCALED by 2*log2(e).
// ---------------------------------------------------------------------------
__global__ __launch_bounds__(256) void attn_kernel(
    const float* __restrict__ qp, const float* __restrict__ kp,
    const float* __restrict__ vp, const float* __restrict__ vw,
    ushortT* __restrict__ ctxb) {
  int b = blockIdx.x >> 4;
  int q0 = (blockIdx.x & 15) * 16;
  __shared__ float skp[32 * 132];
  __shared__ float sqp[16 * 132];
  __shared__ float svp[32 * 192];
  __shared__ float se[16][33];
  __shared__ float swm[128];
  __shared__ float sS0;
  int tid = threadIdx.x;

  const float4* kp4 = (const float4*)(kp + (size_t)b * 32 * 128);
  for (int j = tid; j < 32 * 32; j += 256) {
    int k = j >> 5, d4 = j & 31;
    float4 v = kp4[k * 32 + d4];
    *(float4*)&skp[k * 132 + d4 * 4] = v;
  }
  const float4* qp4 = (const float4*)(qp + (size_t)(b * 256 + q0) * 128);
  for (int j = tid; j < 16 * 32; j += 256) {
    int qq = j >> 5, d4 = j & 31;
    float4 v = qp4[qq * 32 + d4];
    *(float4*)&sqp[qq * 132 + d4 * 4] = v;
  }
  const float4* vp4 = (const float4*)(vp + (size_t)b * 32 * 192);
  for (int j = tid; j < 32 * 48; j += 256) {
    int k = j / 48, m4 = j % 48;
    *(float4*)&svp[k * 192 + m4 * 4] = vp4[k * 48 + m4];
  }
  if (tid < 128) swm[tid] = -2.f * vw[tid];
  if (tid < 64) {
    float s = vw[tid] + vw[tid + 64];
    #pragma unroll
    for (int off = 32; off; off >>= 1) s += __shfl_xor(s, off);
    if (tid == 0) sS0 = s;
  }
  __syncthreads();

  {
    int qq = tid >> 4, kc = tid & 15;
    const float4* q4 = (const float4*)&sqp[qq * 132];
    const float4* ka = (const float4*)&skp[kc * 132];
    const float4* kb = (const float4*)&skp[(kc + 16) * 132];
    const float4* w4 = (const float4*)swm;
    float S0 = sS0;
    float acc0 = S0, acc1 = S0;
    #pragma unroll 8
    for (int dj = 0; dj < 32; ++dj) {
      float4 qv = q4[dj], k0 = ka[dj], k1 = kb[dj], wv = w4[dj];
      acc0 += wv.x * RCPF(EXP2F(qv.x + k0.x) + 1.f);
      acc0 += wv.y * RCPF(EXP2F(qv.y + k0.y) + 1.f);
      acc0 += wv.z * RCPF(EXP2F(qv.z + k0.z) + 1.f);
      acc0 += wv.w * RCPF(EXP2F(qv.w + k0.w) + 1.f);
      acc1 += wv.x * RCPF(EXP2F(qv.x + k1.x) + 1.f);
      acc1 += wv.y * RCPF(EXP2F(qv.y + k1.y) + 1.f);
      acc1 += wv.z * RCPF(EXP2F(qv.z + k1.z) + 1.f);
      acc1 += wv.w * RCPF(EXP2F(qv.w + k1.w) + 1.f);
    }
    se[qq][kc] = acc0;
    se[qq][kc + 16] = acc1;
  }
  __syncthreads();
  if (tid < 16) {
    float mx = -1e30f;
    for (int k = 0; k < 32; ++k) mx = fmaxf(mx, se[tid][k]);
    float s = 0.f;
    for (int k = 0; k < 32; ++k) { float a = __expf(se[tid][k] - mx); se[tid][k] = a; s += a; }
    float invs = 1.f / s;
    for (int k = 0; k < 32; ++k) se[tid][k] *= invs;
  }
  __syncthreads();
  for (int j = tid; j < 768; j += 256) {
    int qq = j / 48, m4 = j % 48;
    const float* al = se[qq];
    float4 a = {0.f, 0.f, 0.f, 0.f};
    #pragma unroll 8
    for (int k = 0; k < 32; ++k) {
      float wk = al[k];
      float4 v = *(const float4*)&svp[k * 192 + m4 * 4];
      a.x += wk * v.x; a.y += wk * v.y; a.z += wk * v.z; a.w += wk * v.w;
    }
    ushort4 o4 = {f2bf(a.x), f2bf(a.y), f2bf(a.z), f2bf(a.w)};
    *(ushort4*)&ctxb[((size_t)(b * 256 + q0 + qq)) * 192 + m4 * 4] = o4;
  }
}

// ---------------------------------------------------------------------------
// Final LN(qlnb + ctx2) + transpose (b,t,m) -> (b,m,t); qlnb is bf16.
// ---------------------------------------------------------------------------
__global__ __launch_bounds__(256) void lnout_kernel(
    const ushortT* __restrict__ qlnb, const float* __restrict__ ctx2,
    const float* __restrict__ w, const float* __restrict__ bb,
    float* __restrict__ out) {
  int b = blockIdx.x >> 2;
  int t0 = (blockIdx.x & 3) * 64;
  __shared__ float sf[64 * 193];
  int wid = threadIdx.x >> 6, lane = threadIdx.x & 63;
  for (int rr = wid; rr < 64; rr += 4) {
    size_t base = ((size_t)(b * 256 + t0 + rr)) * 192;
    float v0 = bf2f(qlnb[base + lane])       + ctx2[base + lane];
    float v1 = bf2f(qlnb[base + lane + 64])  + ctx2[base + lane + 64];
    float v2 = bf2f(qlnb[base + lane + 128]) + ctx2[base + lane + 128];
    float s = v0 + v1 + v2;
    float s2 = v0 * v0 + v1 * v1 + v2 * v2;
    #pragma unroll
    for (int off = 32; off; off >>= 1) { s += __shfl_xor(s, off); s2 += __shfl_xor(s2, off); }
    float mean = s * (1.f / 192.f);
    float var = s2 * (1.f / 192.f) - mean * mean;
    float inv = rsqrtf(var + 1e-5f);
    sf[rr * 193 + lane]       = (v0 - mean) * inv * w[lane]       + bb[lane];
    sf[rr * 193 + lane + 64]  = (v1 - mean) * inv * w[lane + 64]  + bb[lane + 64];
    sf[rr * 193 + lane + 128] = (v2 - mean) * inv * w[lane + 128] + bb[lane + 128];
  }
  __syncthreads();
  for (int j = threadIdx.x; j < 192 * 16; j += 256) {
    int m = j >> 4, t4 = j & 15;
    float4 o4;
    o4.x = sf[(t4 * 4 + 0) * 193 + m];
    o4.y = sf[(t4 * 4 + 1) * 193 + m];
    o4.z = sf[(t4 * 4 + 2) * 193 + m];
    o4.w = sf[(t4 * 4 + 3) * 193 + m];
    *(float4*)&out[((size_t)(b * 192 + m)) * 256 + t0 + t4 * 4] = o4;
  }
}

// ---------------------------------------------------------------------------
extern "C" void kernel_launch(void* const* d_in, const int* in_sizes, int n_in,
                              void* d_out, int out_size, void* d_ws, size_t ws_size,
                              hipStream_t stream) {
  (void)in_sizes; (void)n_in; (void)out_size; (void)ws_size;
  const float* x_p     = (const float*)d_in[0];
  const float* y_g     = (const float*)d_in[1];
  const float* conv1_w = (const float*)d_in[2];
  const float* conv1_b = (const float*)d_in[3];
  const float* gamma1  = (const float*)d_in[4];
  const float* beta1   = (const float*)d_in[5];
  const float* conv2_w = (const float*)d_in[6];
  const float* conv2_b = (const float*)d_in[7];
  const float* gamma2  = (const float*)d_in[8];
  const float* beta2   = (const float*)d_in[9];
  const float* conv3_w = (const float*)d_in[10];
  const float* conv3_b = (const float*)d_in[11];
  const float* ln_q_w  = (const float*)d_in[12];
  const float* ln_q_b  = (const float*)d_in[13];
  const float* ln_kv_w = (const float*)d_in[14];
  const float* ln_kv_b = (const float*)d_in[15];
  const float* ln_out_w= (const float*)d_in[16];
  const float* ln_out_b= (const float*)d_in[17];
  const float* Wq      = (const float*)d_in[18];
  const float* Wk      = (const float*)d_in[19];
  const float* v_w     = (const float*)d_in[20];
  const float* Wv      = (const float*)d_in[21];
  const float* out_w   = (const float*)d_in[22];
  const float* out_b   = (const float*)d_in[23];
  float* out = (float*)d_out;
  float* ws  = (float*)d_ws;

  ushortT* t1bf  = (ushortT*)(ws + OFF_T1BF);
  ushortT* x2bf  = (ushortT*)(ws + OFF_X2BF);
  ushortT* t2bf  = (ushortT*)(ws + OFF_T2BF);
  ushortT* x3bf  = (ushortT*)(ws + OFF_X3BF);
  float*   qraw  = ws + OFF_QRAW;
  ushortT* qlnb  = (ushortT*)(ws + OFF_QLNB);
  ushortT* kvb   = (ushortT*)(ws + OFF_KVB);
  float*   qproj = ws + OFF_QP;
  float*   kproj = ws + OFF_KP;
  float*   vproj = ws + OFF_VP;
  ushortT* wbq   = (ushortT*)(ws + OFF_WBQ);
  ushortT* wbk   = (ushortT*)(ws + OFF_WBK);
  ushortT* wbv   = (ushortT*)(ws + OFF_WBV);
  ushortT* wbo   = (ushortT*)(ws + OFF_WBO);
  ushortT* ctxb  = (ushortT*)(ws + OFF_CTXB);
  float*   ctx2  = ws + OFF_CTX2;
  ushortT* wt2   = (ushortT*)(ws + OFF_WT2);
  ushortT* wt3   = (ushortT*)(ws + OFF_WT3);
  ushortT* wc1   = (ushortT*)(ws + OFF_WC1);
  ushortT* gb1   = (ushortT*)(ws + OFF_GB1);
  ushortT* gb2   = (ushortT*)(ws + OFF_GB2);

  prep_kernel<<<3152, 256, 0, stream>>>(conv2_w, wt2, conv3_w, wt3, conv1_w, wc1,
                                        Wq, wbq, Wk, wbk, Wv, wbv, out_w, wbo,
                                        gamma1, gb1, gamma2, gb2);
  conv1_mfma_kernel<<<256, 256, 0, stream>>>(x_p, wc1, conv1_b, t1bf);
  gdn_mfma_kernel<<<1024, 256, 0, stream>>>(t1bf, gb1, beta1, x2bf, 1024, 16, 1);
  conv_mfma_kernel<0><<<512, 256, 0, stream>>>(x2bf, wt2, conv2_b, t2bf, nullptr);
  gdn_mfma_kernel<<<256, 256, 0, stream>>>(t2bf, gb2, beta2, x3bf, 256, 4, 0);
  conv_mfma_kernel<1><<<768, 256, 0, stream>>>(x3bf, wt3, conv3_b, nullptr, qraw);
  ln_all_kernel<<<4608, 256, 0, stream>>>(qraw, ln_q_w, ln_q_b, qlnb,
                                          y_g, ln_kv_w, ln_kv_b, kvb);
  gemm_qkv_kernel<<<336, 256, 0, stream>>>(qlnb, kvb, wbq, wbk, wbv,
                                           qproj, kproj, vproj);
  attn_kernel<<<1024, 256, 0, stream>>>(qproj, kproj, vproj, v_w, ctxb);
  gemm_out_kernel<<<384, 256, 0, stream>>>(ctxb, wbo, out_b, ctx2);
  lnout_kernel<<<256, 256, 0, stream>>>(qlnb, ctx2, ln_out_w, ln_out_b, out);
}